// Round 3
// baseline (619.773 us; speedup 1.0000x reference)
//
#include <hip/hip_runtime.h>
#include <math.h>

constexpr int cB  = 16;
constexpr int cN  = 64;
constexpr int EMB = 32;
constexpr int NL  = 3;
constexpr int CDIM = 24;
constexpr int LOD = NL * CDIM;      // 72
constexpr int NB  = 10;
constexpr int H   = 150;
constexpr int CR  = 219;
constexpr int C2  = 438;
constexpr int HD  = 128;
constexpr int NSP = 6;              // species count
constexpr int TBL = 4096;
constexpr float RADIUS = 2.0f;

__device__ __forceinline__ float sp5(float x) {
    return fmaxf(x, 0.0f) + 0.2f * log1pf(expf(-5.0f * fabsf(x)));
}
__device__ __forceinline__ float sp1(float x) {
    return fmaxf(x, 0.0f) + log1pf(expf(-fabsf(x)));
}

// per species z: Wpz[z][h][lo] = sum_i rW3[h][lo*32+i]*emb[z][i]; Pbz[z][lo] likewise from rb3
__global__ void __launch_bounds__(256) k_wz(const float* __restrict__ emb_W,
                                            const float* __restrict__ rW3,
                                            const float* __restrict__ rb3,
                                            float* __restrict__ Wpz,
                                            float* __restrict__ Pbz) {
    int z = blockIdx.x;
    __shared__ float e[EMB];
    int t = threadIdx.x;
    if (t < EMB) e[t] = emb_W[z * EMB + t];
    __syncthreads();
    for (int o = t; o < H * LOD; o += 256) {
        int h = o / LOD, lo = o - h * LOD;
        const float* wr = &rW3[(size_t)h * (LOD * EMB) + lo * EMB];
        float s = 0.0f;
        #pragma unroll
        for (int i = 0; i < EMB; ++i) s = fmaf(wr[i], e[i], s);
        Wpz[(size_t)z * (H * LOD) + o] = s;
    }
    if (t < LOD) {
        float s = 0.0f;
        #pragma unroll
        for (int i = 0; i < EMB; ++i) s = fmaf(rb3[t * EMB + i], e[i], s);
        Pbz[z * LOD + t] = s;
    }
}

// table layer 0: basis(r_t) @ rW0 + rb0 -> sp5 -> tab[TBL][150]; 32 rows/block
__global__ void __launch_bounds__(320) k_tab0(const float* __restrict__ rW0,
                                              const float* __restrict__ rb0,
                                              float* __restrict__ tab) {
    int row0 = blockIdx.x * 32;
    __shared__ float bas[32][NB];
    __shared__ float Ws[NB][160];
    __shared__ float bs[160];
    int t = threadIdx.x;
    if (t < 32) {
        float r = (float)(row0 + t) * (RADIUS / (float)(TBL - 1));
        #pragma unroll
        for (int k = 0; k < NB; ++k) {
            float d = r * 4.5f - (float)k;
            float v = 0.0f;
            if (fabsf(d) < 1.0f) { float cc = cosf(1.57079632679489662f * d); v = cc * cc; }
            bas[t][k] = v;
        }
    }
    for (int i = t; i < NB * 160; i += 320) {
        unsigned k = (unsigned)i / 160, j = (unsigned)i % 160;
        Ws[k][j] = (j < H) ? rW0[k * H + j] : 0.0f;
    }
    if (t < 160) bs[t] = (t < H) ? rb0[t] : 0.0f;
    __syncthreads();
    int jt = t % 10, a2 = t / 10, j0 = jt * 16;
    float acc[16];
    #pragma unroll
    for (int q = 0; q < 16; ++q) acc[q] = 0.0f;
    for (int k = 0; k < NB; ++k) {
        float x = bas[a2][k];
        const float4* wr = reinterpret_cast<const float4*>(&Ws[k][j0]);
        #pragma unroll
        for (int q = 0; q < 4; ++q) {
            float4 w = wr[q];
            acc[4*q+0] = fmaf(x, w.x, acc[4*q+0]);
            acc[4*q+1] = fmaf(x, w.y, acc[4*q+1]);
            acc[4*q+2] = fmaf(x, w.z, acc[4*q+2]);
            acc[4*q+3] = fmaf(x, w.w, acc[4*q+3]);
        }
    }
    #pragma unroll
    for (int q = 0; q < 16; ++q) {
        int j = j0 + q;
        if (j < H) tab[(size_t)(row0 + a2) * H + j] = sp5(acc[q] + bs[j]);
    }
}

// C = sp5(A[32rows x150] @ W[150x150] + bias); 32 rows/block
__global__ void __launch_bounds__(320) k_lx(const float* __restrict__ A,
                                            const float* __restrict__ W,
                                            const float* __restrict__ bias,
                                            float* __restrict__ C) {
    int row0 = blockIdx.x * 32;
    __shared__ float As[32][152];
    __shared__ float Ws[32][160];
    __shared__ float bs[160];
    int t = threadIdx.x;
    for (int i = t; i < 32 * H; i += 320) {
        unsigned r = (unsigned)i / H, c = (unsigned)i % H;
        As[r][c] = A[(size_t)(row0 + r) * H + c];
    }
    if (t < 160) bs[t] = (t < H) ? bias[t] : 0.0f;
    int jt = t % 10, a2 = t / 10, j0 = jt * 16;
    float acc[16];
    #pragma unroll
    for (int q = 0; q < 16; ++q) acc[q] = 0.0f;
    for (int kk = 0; kk < H; kk += 32) {
        int kend = min(32, H - kk);
        __syncthreads();
        for (int i = t; i < kend * 160; i += 320) {
            unsigned kr = (unsigned)i / 160, j = (unsigned)i % 160;
            Ws[kr][j] = (j < H) ? W[(size_t)(kk + kr) * H + j] : 0.0f;
        }
        __syncthreads();
        for (int kr = 0; kr < kend; ++kr) {
            float x = As[a2][kk + kr];
            const float4* wr = reinterpret_cast<const float4*>(&Ws[kr][j0]);
            #pragma unroll
            for (int q = 0; q < 4; ++q) {
                float4 w = wr[q];
                acc[4*q+0] = fmaf(x, w.x, acc[4*q+0]);
                acc[4*q+1] = fmaf(x, w.y, acc[4*q+1]);
                acc[4*q+2] = fmaf(x, w.z, acc[4*q+2]);
                acc[4*q+3] = fmaf(x, w.w, acc[4*q+3]);
            }
        }
    }
    #pragma unroll
    for (int q = 0; q < 16; ++q) {
        int j = j0 + q;
        if (j < H) C[(size_t)(row0 + a2) * H + j] = sp5(acc[q] + bs[j]);
    }
}

// G[t][z][lo] = sum_h tab[t][h]*Wpz[z][h][lo] + Pbz[z][lo]; block = 64 t-rows x one z
__global__ void __launch_bounds__(256) k_G(const float* __restrict__ tab,
                                           const float* __restrict__ Wpz,
                                           const float* __restrict__ Pbz,
                                           float* __restrict__ G) {
    int row0 = blockIdx.x * 64;
    int z = blockIdx.y;
    int t = threadIdx.x;
    __shared__ float hs[64][152];
    __shared__ float wps[32][76];
    __shared__ float pbz[LOD];
    for (int i = t; i < 64 * H; i += 256) {
        unsigned r = (unsigned)i / H, c = (unsigned)i % H;
        hs[r][c] = tab[(size_t)(row0 + r) * H + c];
    }
    if (t < LOD) pbz[t] = Pbz[z * LOD + t];
    int lot = t & 7, c2 = t >> 3;
    int lo0 = lot * 9;
    float acc0[9], acc1[9];
    #pragma unroll
    for (int q = 0; q < 9; ++q) { acc0[q] = 0.0f; acc1[q] = 0.0f; }
    for (int kk = 0; kk < H; kk += 32) {
        int kend = min(32, H - kk);
        __syncthreads();
        for (int i = t; i < kend * LOD; i += 256) {
            unsigned kr = (unsigned)i / LOD, lo = (unsigned)i % LOD;
            wps[kr][lo] = Wpz[(size_t)z * (H * LOD) + (size_t)(kk + kr) * LOD + lo];
        }
        __syncthreads();
        for (int kr = 0; kr < kend; ++kr) {
            float x0 = hs[c2][kk + kr];
            float x1 = hs[c2 + 32][kk + kr];
            #pragma unroll
            for (int q = 0; q < 9; ++q) {
                float wv = wps[kr][lo0 + q];
                acc0[q] = fmaf(x0, wv, acc0[q]);
                acc1[q] = fmaf(x1, wv, acc1[q]);
            }
        }
    }
    float* d0 = &G[((size_t)(row0 + c2) * NSP + z) * LOD + lo0];
    float* d1 = &G[((size_t)(row0 + c2 + 32) * NSP + z) * LOD + lo0];
    #pragma unroll
    for (int q = 0; q < 9; ++q) {
        d0[q] = acc0[q] + pbz[lo0 + q];
        d1[q] = acc1[q] + pbz[lo0 + q];
    }
}

// fused per (b,a): pair mask + G-lerp -> p[n][72] in LDS; Y-reduce; body23 concat; residual
__global__ void __launch_bounds__(256) k_red(const float* __restrict__ xyz,
                                             const int* __restrict__ Z,
                                             const float* __restrict__ body23,
                                             const float* __restrict__ G,
                                             const float* __restrict__ res_W,
                                             const float* __restrict__ res_b,
                                             float* __restrict__ feats) {
    int ba = blockIdx.x;
    int b = ba >> 6, a = ba & 63;
    int t = threadIdx.x;
    __shared__ float ym[64][12];
    __shared__ float ps[64][76];
    __shared__ float xr[CR];
    __shared__ int t0s[64];
    __shared__ float wls[64];
    __shared__ int zs[64];
    __shared__ int msks[64];
    if (t < 64) {
        int n = t;
        float ax = xyz[((size_t)b * cN + a) * 3 + 0];
        float ay = xyz[((size_t)b * cN + a) * 3 + 1];
        float az = xyz[((size_t)b * cN + a) * 3 + 2];
        float d0 = ax - xyz[((size_t)b * cN + n) * 3 + 0];
        float d1 = ay - xyz[((size_t)b * cN + n) * 3 + 1];
        float d2 = az - xyz[((size_t)b * cN + n) * 3 + 2];
        float s = d0 * d0 + d1 * d1 + d2 * d2;
        float r = sqrtf(s + 1e-12f);
        msks[n] = (r < RADIUS) && (r > 1e-6f);
        float u = r * ((float)(TBL - 1) / RADIUS);
        int t0 = (int)u;
        if (t0 > TBL - 2) t0 = TBL - 2;
        t0s[n] = t0;
        wls[n] = u - (float)t0;
        zs[n] = Z[b * cN + n];
        float inv = 1.0f / r;
        float x = d0 * inv, y = d1 * inv, z = d2 * inv;
        ym[n][0] = 0.28209479177387814f;
        ym[n][1] = 0.4886025119029199f * y;
        ym[n][2] = 0.4886025119029199f * z;
        ym[n][3] = 0.4886025119029199f * x;
        ym[n][4] = 1.0925484305920792f * x * y;
        ym[n][5] = 1.0925484305920792f * y * z;
        ym[n][6] = 0.31539156525252005f * (3.0f * z * z - 1.0f);
        ym[n][7] = 1.0925484305920792f * x * z;
        ym[n][8] = 0.5462742152960396f * (x * x - y * y);
    }
    __syncthreads();
    for (int i = t; i < 64 * LOD; i += 256) {
        int n = i / LOD, lo = i - n * LOD;
        float v = 0.0f;
        if (msks[n]) {
            const float* g = &G[((size_t)t0s[n] * NSP + zs[n]) * LOD + lo];
            float g0 = g[0], g1 = g[NSP * LOD];
            v = g0 + wls[n] * (g1 - g0);
        }
        ps[n][lo] = v;
    }
    __syncthreads();
    if (t < 216) {
        int lo, yi;
        if (t < 24) { lo = t; yi = 0; }
        else if (t < 96) { int q = t - 24; int o = q / 3; lo = 24 + o; yi = 1 + (q - o * 3); }
        else { int q = t - 96; int o = q / 5; lo = 48 + o; yi = 4 + (q - o * 5); }
        float acc = 0.0f;
        #pragma unroll 4
        for (int n = 0; n < cN; ++n)
            acc = fmaf(ps[n][lo], ym[n][yi], acc);
        xr[3 + t] = acc * 0.125f;
    } else if (t < 219) {
        xr[t - 216] = body23[(size_t)ba * 3 + (t - 216)];
    }
    __syncthreads();
    if (t < CR) {
        float xv = xr[t];
        feats[(size_t)ba * C2 + t] = xv;
        float racc = res_b[t];
        for (int k = 0; k < CR; ++k)
            racc = fmaf(xr[k], res_W[k * CR + t], racc);
        feats[(size_t)ba * C2 + CR + t] = xv + sp5(racc);
    }
}

__global__ void __launch_bounds__(448) k_pool(const float* __restrict__ feats,
                                              float* __restrict__ pooled) {
    int b = blockIdx.x;
    int t = threadIdx.x;
    if (t < C2) {
        float s = 0.0f;
        for (int a = 0; a < cN; ++a) {
            float v = feats[(size_t)(b * cN + a) * C2 + t];
            s = fmaf(v, v, s);
        }
        pooled[b * C2 + t] = sqrtf(s);
    }
}

__global__ void __launch_bounds__(256) k_head(const float* __restrict__ pooled,
                                              const float* __restrict__ c_W,
                                              const float* __restrict__ c_b,
                                              const float* __restrict__ bn_g,
                                              const float* __restrict__ bn_b,
                                              const float* __restrict__ o_W,
                                              const float* __restrict__ o_b,
                                              float* __restrict__ out) {
    __shared__ float psm[cB][C2];
    __shared__ float hh[cB][HD];
    __shared__ float hh2[cB][HD];
    int t = threadIdx.x;
    for (int i = t; i < cB * C2; i += 256) psm[(unsigned)i / C2][(unsigned)i % C2] = pooled[i];
    __syncthreads();
    for (int o = t; o < cB * HD; o += 256) {
        int b = o >> 7, j = o & 127;
        float s0 = 0, s1 = 0, s2 = 0, s3 = 0;
        for (int ch = 0; ch < 436; ch += 4) {
            s0 = fmaf(psm[b][ch + 0], c_W[(ch + 0) * HD + j], s0);
            s1 = fmaf(psm[b][ch + 1], c_W[(ch + 1) * HD + j], s1);
            s2 = fmaf(psm[b][ch + 2], c_W[(ch + 2) * HD + j], s2);
            s3 = fmaf(psm[b][ch + 3], c_W[(ch + 3) * HD + j], s3);
        }
        s0 = fmaf(psm[b][436], c_W[436 * HD + j], s0);
        s1 = fmaf(psm[b][437], c_W[437 * HD + j], s1);
        hh[b][j] = sp1(((s0 + s1) + (s2 + s3)) + c_b[j]);
    }
    __syncthreads();
    if (t < HD) {
        int j = t;
        float mu = 0.0f;
        for (int bb = 0; bb < cB; ++bb) mu += hh[bb][j];
        mu *= (1.0f / cB);
        float var = 0.0f;
        for (int bb = 0; bb < cB; ++bb) { float d = hh[bb][j] - mu; var = fmaf(d, d, var); }
        var *= (1.0f / cB);
        float sc = bn_g[j] / sqrtf(var + 1e-5f);
        float bnb = bn_b[j];
        for (int bb = 0; bb < cB; ++bb)
            hh2[bb][j] = sp1((hh[bb][j] - mu) * sc + bnb);
    }
    __syncthreads();
    if (t < cB) {
        float s = o_b[0];
        for (int j = 0; j < HD; ++j) s = fmaf(hh2[t][j], o_W[j], s);
        out[t] = 1.0f / (1.0f + expf(-s));
    }
}

extern "C" void kernel_launch(void* const* d_in, const int* in_sizes, int n_in,
                              void* d_out, int out_size, void* d_ws, size_t ws_size,
                              hipStream_t stream) {
    const float* xyz    = (const float*)d_in[0];
    const int*   Z      = (const int*)d_in[1];
    const float* body23 = (const float*)d_in[2];
    const float* emb_W  = (const float*)d_in[3];
    const float* rW0    = (const float*)d_in[4];
    const float* rb0    = (const float*)d_in[5];
    const float* rW1    = (const float*)d_in[6];
    const float* rb1    = (const float*)d_in[7];
    const float* rW2    = (const float*)d_in[8];
    const float* rb2    = (const float*)d_in[9];
    const float* rW3    = (const float*)d_in[10];
    const float* rb3    = (const float*)d_in[11];
    const float* res_W  = (const float*)d_in[12];
    const float* res_b  = (const float*)d_in[13];
    const float* c_W    = (const float*)d_in[14];
    const float* c_b    = (const float*)d_in[15];
    const float* bn_g   = (const float*)d_in[16];
    const float* bn_b   = (const float*)d_in[17];
    const float* o_W    = (const float*)d_in[18];
    const float* o_b    = (const float*)d_in[19];

    float* w      = (float*)d_ws;
    float* Wpz    = w;                        // 6*150*72   = 64800
    float* Pbz    = Wpz + 64800;              // 6*72       = 432
    float* tabA   = Pbz + 432;                // 4096*150   = 614400
    float* tabB   = tabA + 614400;            // 4096*150
    float* G      = tabB + 614400;            // 4096*6*72  = 1769472
    float* feats  = G + 1769472;              // 1024*438   = 448512
    float* pooled = feats + 448512;           // 16*438
    (void)in_sizes; (void)n_in; (void)out_size; (void)ws_size;

    k_wz  <<<NSP, 256, 0, stream>>>(emb_W, rW3, rb3, Wpz, Pbz);
    k_tab0<<<TBL / 32, 320, 0, stream>>>(rW0, rb0, tabA);
    k_lx  <<<TBL / 32, 320, 0, stream>>>(tabA, rW1, rb1, tabB);
    k_lx  <<<TBL / 32, 320, 0, stream>>>(tabB, rW2, rb2, tabA);
    k_G   <<<dim3(TBL / 64, NSP), 256, 0, stream>>>(tabA, Wpz, Pbz, G);
    k_red <<<cB * cN, 256, 0, stream>>>(xyz, Z, body23, G, res_W, res_b, feats);
    k_pool<<<cB, 448, 0, stream>>>(feats, pooled);
    k_head<<<1, 256, 0, stream>>>(pooled, c_W, c_b, bn_g, bn_b, o_W, o_b, (float*)d_out);
}

// Round 6
// 372.056 us; speedup vs baseline: 1.6658x; 1.6658x over previous
//
#include <hip/hip_runtime.h>
#include <math.h>

constexpr int cB  = 16;
constexpr int cN  = 64;
constexpr int EMB = 32;
constexpr int NL  = 3;
constexpr int CDIM = 24;
constexpr int LOD = NL * CDIM;      // 72
constexpr int NB  = 10;
constexpr int H   = 150;
constexpr int CR  = 219;
constexpr int C2  = 438;
constexpr int HD  = 128;
constexpr int NSP = 6;              // species count
constexpr int TBL = 8192;
constexpr float RADIUS = 2.0f;

__device__ __forceinline__ float sp5(float x) {
    return fmaxf(x, 0.0f) + 0.2f * log1pf(expf(-5.0f * fabsf(x)));
}
__device__ __forceinline__ float sp1(float x) {
    return fmaxf(x, 0.0f) + log1pf(expf(-fabsf(x)));
}

// per species z: Wpz[z][h][lo] = sum_i rW3[h][lo*32+i]*emb[z][i]; Pbz[z][lo] from rb3
__global__ void __launch_bounds__(256) k_wz(const float* __restrict__ emb_W,
                                            const float* __restrict__ rW3,
                                            const float* __restrict__ rb3,
                                            float* __restrict__ Wpz,
                                            float* __restrict__ Pbz) {
    int z = blockIdx.x;
    __shared__ float e[EMB];
    int t = threadIdx.x;
    if (t < EMB) e[t] = emb_W[z * EMB + t];
    __syncthreads();
    for (int o = t; o < H * LOD; o += 256) {
        int h = o / LOD, lo = o - h * LOD;
        const float* wr = &rW3[(size_t)h * (LOD * EMB) + lo * EMB];
        float s = 0.0f;
        #pragma unroll
        for (int i = 0; i < EMB; ++i) s = fmaf(wr[i], e[i], s);
        Wpz[(size_t)z * (H * LOD) + o] = s;
    }
    if (t < LOD) {
        float s = 0.0f;
        #pragma unroll
        for (int i = 0; i < EMB; ++i) s = fmaf(rb3[t * EMB + i], e[i], s);
        Pbz[z * LOD + t] = s;
    }
}

// Fused table chain: per block = 32 table rows.
// basis -> L0(10->150) -> L1(150->150) -> L2(150->150) -> G (150 -> 6*72), all staged in LDS.
// G[t][z][lo] = sum_h h2[t][h]*Wpz[z][h][lo] + Pbz[z][lo]
__global__ void __launch_bounds__(256) k_chain(const float* __restrict__ rW0,
                                               const float* __restrict__ rb0,
                                               const float* __restrict__ rW1,
                                               const float* __restrict__ rb1,
                                               const float* __restrict__ rW2,
                                               const float* __restrict__ rb2,
                                               const float* __restrict__ Wpz,
                                               const float* __restrict__ Pbz,
                                               float* __restrict__ G) {
    int row0 = blockIdx.x * 32;
    int t = threadIdx.x;
    __shared__ float bas[32][12];
    __shared__ float hA[32][152];
    __shared__ float hB[32][152];
    __shared__ float Wt[16][160];
    __shared__ float bs[160];
    __shared__ float pz[NSP * LOD];

    // basis rows
    if (t < 32) {
        float r = (float)(row0 + t) * (RADIUS / (float)(TBL - 1));
        #pragma unroll
        for (int k = 0; k < NB; ++k) {
            float d = r * 4.5f - (float)k;
            float v = 0.0f;
            if (fabsf(d) < 1.0f) { float cc = cosf(1.57079632679489662f * d); v = cc * cc; }
            bas[t][k] = v;
        }
    }
    for (int i = t; i < NSP * LOD; i += 256) pz[i] = Pbz[i];

    int a2 = t >> 3, jt = t & 7, j0 = jt * 19;   // 32 rows x 8 col-groups x 19 cols

    // ---- L0: stage all of rW0 [10][150] + rb0 ----
    for (int i = t; i < NB * 160; i += 256) {
        int k = i / 160, j = i - k * 160;
        Wt[k][j] = (j < H) ? rW0[k * H + j] : 0.0f;
    }
    if (t < 160) bs[t] = (t < H) ? rb0[t] : 0.0f;
    __syncthreads();
    {
        float acc[19];
        #pragma unroll
        for (int q = 0; q < 19; ++q) acc[q] = 0.0f;
        #pragma unroll
        for (int k = 0; k < NB; ++k) {
            float x = bas[a2][k];
            #pragma unroll
            for (int q = 0; q < 19; ++q) acc[q] = fmaf(x, Wt[k][j0 + q], acc[q]);
        }
        #pragma unroll
        for (int q = 0; q < 19; ++q) {
            int j = j0 + q;
            if (j < H) hA[a2][j] = sp5(acc[q] + bs[j]);
        }
    }

    // ---- L1: hA -> hB,  L2: hB -> hA ----
    for (int layer = 0; layer < 2; ++layer) {
        const float* W  = layer ? rW2 : rW1;
        const float* bb = layer ? rb2 : rb1;
        const float (*src)[152] = layer ? hB : hA;
        float (*dst)[152] = layer ? hA : hB;
        float acc[19];
        #pragma unroll
        for (int q = 0; q < 19; ++q) acc[q] = 0.0f;
        for (int kk = 0; kk < H; kk += 16) {
            int kend = min(16, H - kk);
            __syncthreads();
            for (int i = t; i < kend * 160; i += 256) {
                int kr = i / 160, j = i - kr * 160;
                Wt[kr][j] = (j < H) ? W[(size_t)(kk + kr) * H + j] : 0.0f;
            }
            if (kk == 0 && t < 160) bs[t] = (t < H) ? bb[t] : 0.0f;
            __syncthreads();
            #pragma unroll 4
            for (int kr = 0; kr < kend; ++kr) {
                float x = src[a2][kk + kr];
                #pragma unroll
                for (int q = 0; q < 19; ++q) acc[q] = fmaf(x, Wt[kr][j0 + q], acc[q]);
            }
        }
        __syncthreads();
        #pragma unroll
        for (int q = 0; q < 19; ++q) {
            int j = j0 + q;
            if (j < H) dst[a2][j] = sp5(acc[q] + bs[j]);
        }
    }

    // ---- G phase: for each z, [32x150] @ Wpz[z][150x72] + Pbz[z] ----
    int lo0 = jt * 9;     // 8 groups x 9 = 72
    for (int z = 0; z < NSP; ++z) {
        float ac[9];
        #pragma unroll
        for (int q = 0; q < 9; ++q) ac[q] = 0.0f;
        for (int kk = 0; kk < H; kk += 16) {
            int kend = min(16, H - kk);
            __syncthreads();
            for (int i = t; i < kend * LOD; i += 256) {
                int kr = i / LOD, lo = i - kr * LOD;
                Wt[kr][lo] = Wpz[(size_t)z * (H * LOD) + (size_t)(kk + kr) * LOD + lo];
            }
            __syncthreads();
            #pragma unroll 4
            for (int kr = 0; kr < kend; ++kr) {
                float x = hA[a2][kk + kr];
                #pragma unroll
                for (int q = 0; q < 9; ++q) ac[q] = fmaf(x, Wt[kr][lo0 + q], ac[q]);
            }
        }
        float* gp = &G[((size_t)(row0 + a2) * NSP + z) * LOD + lo0];
        #pragma unroll
        for (int q = 0; q < 9; ++q) gp[q] = ac[q] + pz[z * LOD + lo0 + q];
    }
}

// fused per (b,a): pair mask + G-lerp -> ps[n][72] in LDS; Y-reduce; body23 concat; residual
__global__ void __launch_bounds__(256) k_red(const float* __restrict__ xyz,
                                             const int* __restrict__ Z,
                                             const float* __restrict__ body23,
                                             const float* __restrict__ G,
                                             const float* __restrict__ res_W,
                                             const float* __restrict__ res_b,
                                             float* __restrict__ feats) {
    int ba = blockIdx.x;
    int b = ba >> 6, a = ba & 63;
    int t = threadIdx.x;
    __shared__ float ym[64][12];
    __shared__ float ps[64][76];
    __shared__ float xr[CR];
    __shared__ int t0s[64];
    __shared__ float wls[64];
    __shared__ int zs[64];
    __shared__ int msks[64];
    if (t < 64) {
        int n = t;
        float ax = xyz[((size_t)b * cN + a) * 3 + 0];
        float ay = xyz[((size_t)b * cN + a) * 3 + 1];
        float az = xyz[((size_t)b * cN + a) * 3 + 2];
        float d0 = ax - xyz[((size_t)b * cN + n) * 3 + 0];
        float d1 = ay - xyz[((size_t)b * cN + n) * 3 + 1];
        float d2 = az - xyz[((size_t)b * cN + n) * 3 + 2];
        float s = d0 * d0 + d1 * d1 + d2 * d2;
        float r = sqrtf(s + 1e-12f);
        msks[n] = (r < RADIUS) && (r > 1e-6f);
        float u = r * ((float)(TBL - 1) / RADIUS);
        int t0 = (int)u;
        if (t0 > TBL - 2) t0 = TBL - 2;
        t0s[n] = t0;
        wls[n] = u - (float)t0;
        zs[n] = Z[b * cN + n];
        float inv = 1.0f / r;
        float x = d0 * inv, y = d1 * inv, z = d2 * inv;
        ym[n][0] = 0.28209479177387814f;
        ym[n][1] = 0.4886025119029199f * y;
        ym[n][2] = 0.4886025119029199f * z;
        ym[n][3] = 0.4886025119029199f * x;
        ym[n][4] = 1.0925484305920792f * x * y;
        ym[n][5] = 1.0925484305920792f * y * z;
        ym[n][6] = 0.31539156525252005f * (3.0f * z * z - 1.0f);
        ym[n][7] = 1.0925484305920792f * x * z;
        ym[n][8] = 0.5462742152960396f * (x * x - y * y);
    }
    __syncthreads();
    for (int i = t; i < 64 * LOD; i += 256) {
        int n = i / LOD, lo = i - n * LOD;
        float v = 0.0f;
        if (msks[n]) {
            const float* g = &G[((size_t)t0s[n] * NSP + zs[n]) * LOD + lo];
            float g0 = g[0], g1 = g[NSP * LOD];
            v = g0 + wls[n] * (g1 - g0);
        }
        ps[n][lo] = v;
    }
    __syncthreads();
    if (t < 216) {
        int lo, yi;
        if (t < 24) { lo = t; yi = 0; }
        else if (t < 96) { int q = t - 24; int o = q / 3; lo = 24 + o; yi = 1 + (q - o * 3); }
        else { int q = t - 96; int o = q / 5; lo = 48 + o; yi = 4 + (q - o * 5); }
        float acc = 0.0f;
        #pragma unroll 4
        for (int n = 0; n < cN; ++n)
            acc = fmaf(ps[n][lo], ym[n][yi], acc);
        xr[3 + t] = acc * 0.125f;
    } else if (t < 219) {
        xr[t - 216] = body23[(size_t)ba * 3 + (t - 216)];
    }
    __syncthreads();
    if (t < CR) {
        float xv = xr[t];
        feats[(size_t)ba * C2 + t] = xv;
        float racc = res_b[t];
        for (int k = 0; k < CR; ++k)
            racc = fmaf(xr[k], res_W[k * CR + t], racc);
        feats[(size_t)ba * C2 + CR + t] = xv + sp5(racc);
    }
}

__global__ void __launch_bounds__(448) k_pool(const float* __restrict__ feats,
                                              float* __restrict__ pooled) {
    int b = blockIdx.x;
    int t = threadIdx.x;
    if (t < C2) {
        float s = 0.0f;
        for (int a = 0; a < cN; ++a) {
            float v = feats[(size_t)(b * cN + a) * C2 + t];
            s = fmaf(v, v, s);
        }
        pooled[b * C2 + t] = sqrtf(s);
    }
}

__global__ void __launch_bounds__(256) k_head(const float* __restrict__ pooled,
                                              const float* __restrict__ c_W,
                                              const float* __restrict__ c_b,
                                              const float* __restrict__ bn_g,
                                              const float* __restrict__ bn_b,
                                              const float* __restrict__ o_W,
                                              const float* __restrict__ o_b,
                                              float* __restrict__ out) {
    __shared__ float psm[cB][C2];
    __shared__ float hh[cB][HD];
    __shared__ float hh2[cB][HD];
    int t = threadIdx.x;
    for (int i = t; i < cB * C2; i += 256) psm[(unsigned)i / C2][(unsigned)i % C2] = pooled[i];
    __syncthreads();
    for (int o = t; o < cB * HD; o += 256) {
        int b = o >> 7, j = o & 127;
        float s0 = 0, s1 = 0, s2 = 0, s3 = 0;
        for (int ch = 0; ch < 436; ch += 4) {
            s0 = fmaf(psm[b][ch + 0], c_W[(ch + 0) * HD + j], s0);
            s1 = fmaf(psm[b][ch + 1], c_W[(ch + 1) * HD + j], s1);
            s2 = fmaf(psm[b][ch + 2], c_W[(ch + 2) * HD + j], s2);
            s3 = fmaf(psm[b][ch + 3], c_W[(ch + 3) * HD + j], s3);
        }
        s0 = fmaf(psm[b][436], c_W[436 * HD + j], s0);
        s1 = fmaf(psm[b][437], c_W[437 * HD + j], s1);
        hh[b][j] = sp1(((s0 + s1) + (s2 + s3)) + c_b[j]);
    }
    __syncthreads();
    if (t < HD) {
        int j = t;
        float mu = 0.0f;
        for (int bb = 0; bb < cB; ++bb) mu += hh[bb][j];
        mu *= (1.0f / cB);
        float var = 0.0f;
        for (int bb = 0; bb < cB; ++bb) { float d = hh[bb][j] - mu; var = fmaf(d, d, var); }
        var *= (1.0f / cB);
        float sc = bn_g[j] / sqrtf(var + 1e-5f);
        float bnb = bn_b[j];
        for (int bb = 0; bb < cB; ++bb)
            hh2[bb][j] = sp1((hh[bb][j] - mu) * sc + bnb);
    }
    __syncthreads();
    if (t < cB) {
        float s = o_b[0];
        for (int j = 0; j < HD; ++j) s = fmaf(hh2[t][j], o_W[j], s);
        out[t] = 1.0f / (1.0f + expf(-s));
    }
}

extern "C" void kernel_launch(void* const* d_in, const int* in_sizes, int n_in,
                              void* d_out, int out_size, void* d_ws, size_t ws_size,
                              hipStream_t stream) {
    const float* xyz    = (const float*)d_in[0];
    const int*   Z      = (const int*)d_in[1];
    const float* body23 = (const float*)d_in[2];
    const float* emb_W  = (const float*)d_in[3];
    const float* rW0    = (const float*)d_in[4];
    const float* rb0    = (const float*)d_in[5];
    const float* rW1    = (const float*)d_in[6];
    const float* rb1    = (const float*)d_in[7];
    const float* rW2    = (const float*)d_in[8];
    const float* rb2    = (const float*)d_in[9];
    const float* rW3    = (const float*)d_in[10];
    const float* rb3    = (const float*)d_in[11];
    const float* res_W  = (const float*)d_in[12];
    const float* res_b  = (const float*)d_in[13];
    const float* c_W    = (const float*)d_in[14];
    const float* c_b    = (const float*)d_in[15];
    const float* bn_g   = (const float*)d_in[16];
    const float* bn_b   = (const float*)d_in[17];
    const float* o_W    = (const float*)d_in[18];
    const float* o_b    = (const float*)d_in[19];

    float* w      = (float*)d_ws;
    float* Wpz    = w;                        // 6*150*72   = 64800
    float* Pbz    = Wpz + 64800;              // 6*72       = 432
    float* G      = Pbz + 432;                // 8192*6*72  = 3538944
    float* feats  = G + 3538944;              // 1024*438   = 448512
    float* pooled = feats + 448512;           // 16*438
    (void)in_sizes; (void)n_in; (void)out_size; (void)ws_size;

    k_wz   <<<NSP, 256, 0, stream>>>(emb_W, rW3, rb3, Wpz, Pbz);
    k_chain<<<TBL / 32, 256, 0, stream>>>(rW0, rb0, rW1, rb1, rW2, rb2, Wpz, Pbz, G);
    k_red  <<<cB * cN, 256, 0, stream>>>(xyz, Z, body23, G, res_W, res_b, feats);
    k_pool <<<cB, 448, 0, stream>>>(feats, pooled);
    k_head <<<1, 256, 0, stream>>>(pooled, c_W, c_b, bn_g, bn_b, o_W, o_b, (float*)d_out);
}

// Round 9
// 354.939 us; speedup vs baseline: 1.7461x; 1.0482x over previous
//
#include <hip/hip_runtime.h>
#include <math.h>

constexpr int cB  = 16;
constexpr int cN  = 64;
constexpr int EMB = 32;
constexpr int NL  = 3;
constexpr int CDIM = 24;
constexpr int LOD = NL * CDIM;      // 72
constexpr int NB  = 10;
constexpr int H   = 150;
constexpr int CR  = 219;
constexpr int C2  = 438;
constexpr int HD  = 128;
constexpr int NSP = 6;              // species count
constexpr int TBL = 8192;
constexpr float RADIUS = 2.0f;

__device__ __forceinline__ float sp5(float x) {
    return fmaxf(x, 0.0f) + 0.2f * log1pf(expf(-5.0f * fabsf(x)));
}
__device__ __forceinline__ float sp1(float x) {
    return fmaxf(x, 0.0f) + log1pf(expf(-fabsf(x)));
}

// per species z: Wpz[z][h][lo] = sum_i rW3[h][lo*32+i]*emb[z][i]; Pbz[z][lo] from rb3
__global__ void __launch_bounds__(256) k_wz(const float* __restrict__ emb_W,
                                            const float* __restrict__ rW3,
                                            const float* __restrict__ rb3,
                                            float* __restrict__ Wpz,
                                            float* __restrict__ Pbz) {
    int z = blockIdx.x;
    __shared__ float e[EMB];
    int t = threadIdx.x;
    if (t < EMB) e[t] = emb_W[z * EMB + t];
    __syncthreads();
    for (int o = t; o < H * LOD; o += 256) {
        int h = o / LOD, lo = o - h * LOD;
        const float* wr = &rW3[(size_t)h * (LOD * EMB) + lo * EMB];
        float s = 0.0f;
        #pragma unroll
        for (int i = 0; i < EMB; ++i) s = fmaf(wr[i], e[i], s);
        Wpz[(size_t)z * (H * LOD) + o] = s;
    }
    if (t < LOD) {
        float s = 0.0f;
        #pragma unroll
        for (int i = 0; i < EMB; ++i) s = fmaf(rb3[t * EMB + i], e[i], s);
        Pbz[z * LOD + t] = s;
    }
}

// Fused table chain, double-buffered staging.
// Per block: 32 table rows. basis -> L0 -> L1 -> L2 -> G (6 species), ~31 barrier-pairs,
// every stage prefetched into the idle LDS buffer while the current tile computes.
__global__ void __launch_bounds__(256) k_chain(const float* __restrict__ rW0,
                                               const float* __restrict__ rb0,
                                               const float* __restrict__ rW1,
                                               const float* __restrict__ rb1,
                                               const float* __restrict__ rW2,
                                               const float* __restrict__ rb2,
                                               const float* __restrict__ Wpz,
                                               const float* __restrict__ Pbz,
                                               float* __restrict__ G) {
    int row0 = blockIdx.x * 32;
    int t = threadIdx.x;
    __shared__ float bas[32][10];
    __shared__ float hA[32 * 150];
    __shared__ float bs[152];
    __shared__ float pz[NSP * LOD];
    __shared__ float S[9600];                 // union scratch
    float* hBf = S;                           // [32*150] in L-phases
    float (*Wt)[15][160] = reinterpret_cast<float (*)[15][160]>(S + 4800);  // 2x15x160
    float (*Wz)[50][72]  = reinterpret_cast<float (*)[50][72]>(S);          // 2x50x72 in G-phase

    int a2 = t >> 3, jt = t & 7;
    int j0 = jt * 19;      // L-phase: 8 col-groups x 19 (covers 150 with guard)
    int lo0 = jt * 9;      // G-phase: 8 col-groups x 9 = 72

    // ---- prologue: basis, pz, L0 weights + bias ----
    if (t < 32) {
        float r = (float)(row0 + t) * (RADIUS / (float)(TBL - 1));
        #pragma unroll
        for (int k = 0; k < NB; ++k) {
            float d = r * 4.5f - (float)k;
            float v = 0.0f;
            if (fabsf(d) < 1.0f) { float cc = cosf(1.57079632679489662f * d); v = cc * cc; }
            bas[t][k] = v;
        }
    }
    for (int i = t; i < NSP * LOD; i += 256) pz[i] = Pbz[i];
    for (int i = t; i < NB * 160; i += 256) {
        int kr = (unsigned)i / 160, j = i - kr * 160;
        Wt[0][kr][j] = (j < H) ? rW0[(size_t)kr * H + j] : 0.0f;
    }
    if (t < 152) bs[t] = (t < H) ? rb0[t] : 0.0f;
    __syncthreads();

    // ---- L0: bas[32][10] @ rW0 ----
    {
        float acc[19];
        #pragma unroll
        for (int q = 0; q < 19; ++q) acc[q] = 0.0f;
        #pragma unroll
        for (int k = 0; k < NB; ++k) {
            float x = bas[a2][k];
            #pragma unroll
            for (int q = 0; q < 19; ++q) acc[q] = fmaf(x, Wt[0][k][j0 + q], acc[q]);
        }
        #pragma unroll
        for (int q = 0; q < 19; ++q) {
            int j = j0 + q;
            if (j < H) hA[a2 * 150 + j] = sp5(acc[q] + bs[j]);
        }
    }
    __syncthreads();   // hA ready; Wt/bs reads done

    // ---- L1 (hA->hB), L2 (hB->hA): 10 tiles of 15 rows, double-buffered ----
    for (int layer = 0; layer < 2; ++layer) {
        const float* W   = layer ? rW2 : rW1;
        const float* bb  = layer ? rb2 : rb1;
        const float* src = layer ? hBf : hA;
        float*       dst = layer ? hA  : hBf;
        // stage tile 0 + bias
        for (int i = t; i < 15 * 160; i += 256) {
            int kr = (unsigned)i / 160, j = i - kr * 160;
            Wt[0][kr][j] = (j < H) ? W[(size_t)kr * H + j] : 0.0f;
        }
        if (t < 152) bs[t] = (t < H) ? bb[t] : 0.0f;
        __syncthreads();
        float acc[19];
        #pragma unroll
        for (int q = 0; q < 19; ++q) acc[q] = 0.0f;
        int buf = 0;
        for (int tile = 0; tile < 10; ++tile) {
            if (tile < 9) {      // prefetch next tile into the idle buffer
                int kk2 = (tile + 1) * 15;
                for (int i = t; i < 15 * 160; i += 256) {
                    int kr = (unsigned)i / 160, j = i - kr * 160;
                    Wt[buf ^ 1][kr][j] = (j < H) ? W[(size_t)(kk2 + kr) * H + j] : 0.0f;
                }
            }
            int kk = tile * 15;
            #pragma unroll 5
            for (int kr = 0; kr < 15; ++kr) {
                float x = src[a2 * 150 + kk + kr];
                #pragma unroll
                for (int q = 0; q < 19; ++q) acc[q] = fmaf(x, Wt[buf][kr][j0 + q], acc[q]);
            }
            __syncthreads();
            buf ^= 1;
        }
        #pragma unroll
        for (int q = 0; q < 19; ++q) {
            int j = j0 + q;
            if (j < H) dst[a2 * 150 + j] = sp5(acc[q] + bs[j]);
        }
        __syncthreads();
    }

    // ---- G: 18 segments (6 species x 3 chunks of 50 rows), double-buffered ----
    {
        float ac[9];
        #pragma unroll
        for (int q = 0; q < 9; ++q) ac[q] = 0.0f;
        for (int i = t; i < 50 * 72; i += 256) {         // stage seg 0 (z=0, rows 0..49)
            int kr = (unsigned)i / 72, lo = i - kr * 72;
            Wz[0][kr][lo] = Wpz[(size_t)kr * LOD + lo];
        }
        __syncthreads();
        int gbuf = 0;
        for (int s = 0; s < 18; ++s) {
            if (s < 17) {
                int s2 = s + 1, z2 = s2 / 3, base2 = (s2 - z2 * 3) * 50;
                for (int i = t; i < 50 * 72; i += 256) {
                    int kr = (unsigned)i / 72, lo = i - kr * 72;
                    Wz[gbuf ^ 1][kr][lo] =
                        Wpz[(size_t)z2 * (H * LOD) + (size_t)(base2 + kr) * LOD + lo];
                }
            }
            int z = s / 3, base = (s - z * 3) * 50;
            #pragma unroll 5
            for (int kr = 0; kr < 50; ++kr) {
                float x = hA[a2 * 150 + base + kr];
                #pragma unroll
                for (int q = 0; q < 9; ++q) ac[q] = fmaf(x, Wz[gbuf][kr][lo0 + q], ac[q]);
            }
            if ((s - z * 3) == 2) {                      // last chunk of this z
                float* gp = &G[((size_t)(row0 + a2) * NSP + z) * LOD + lo0];
                #pragma unroll
                for (int q = 0; q < 9; ++q) { gp[q] = ac[q] + pz[z * LOD + lo0 + q]; ac[q] = 0.0f; }
            }
            __syncthreads();
            gbuf ^= 1;
        }
    }
}

// fused per (b,a): pair mask + G-lerp -> ps[n][72] in LDS; Y-reduce; body23 concat; residual
__global__ void __launch_bounds__(256) k_red(const float* __restrict__ xyz,
                                             const int* __restrict__ Z,
                                             const float* __restrict__ body23,
                                             const float* __restrict__ G,
                                             const float* __restrict__ res_W,
                                             const float* __restrict__ res_b,
                                             float* __restrict__ feats) {
    int ba = blockIdx.x;
    int b = ba >> 6, a = ba & 63;
    int t = threadIdx.x;
    __shared__ float ym[64][12];
    __shared__ float ps[64][76];
    __shared__ float xr[CR];
    __shared__ int t0s[64];
    __shared__ float wls[64];
    __shared__ int zs[64];
    __shared__ int msks[64];
    if (t < 64) {
        int n = t;
        float ax = xyz[((size_t)b * cN + a) * 3 + 0];
        float ay = xyz[((size_t)b * cN + a) * 3 + 1];
        float az = xyz[((size_t)b * cN + a) * 3 + 2];
        float d0 = ax - xyz[((size_t)b * cN + n) * 3 + 0];
        float d1 = ay - xyz[((size_t)b * cN + n) * 3 + 1];
        float d2 = az - xyz[((size_t)b * cN + n) * 3 + 2];
        float s = d0 * d0 + d1 * d1 + d2 * d2;
        float r = sqrtf(s + 1e-12f);
        msks[n] = (r < RADIUS) && (r > 1e-6f);
        float u = r * ((float)(TBL - 1) / RADIUS);
        int t0 = (int)u;
        if (t0 > TBL - 2) t0 = TBL - 2;
        t0s[n] = t0;
        wls[n] = u - (float)t0;
        zs[n] = Z[b * cN + n];
        float inv = 1.0f / r;
        float x = d0 * inv, y = d1 * inv, z = d2 * inv;
        ym[n][0] = 0.28209479177387814f;
        ym[n][1] = 0.4886025119029199f * y;
        ym[n][2] = 0.4886025119029199f * z;
        ym[n][3] = 0.4886025119029199f * x;
        ym[n][4] = 1.0925484305920792f * x * y;
        ym[n][5] = 1.0925484305920792f * y * z;
        ym[n][6] = 0.31539156525252005f * (3.0f * z * z - 1.0f);
        ym[n][7] = 1.0925484305920792f * x * z;
        ym[n][8] = 0.5462742152960396f * (x * x - y * y);
    }
    __syncthreads();
    for (int i = t; i < 64 * LOD; i += 256) {
        int n = i / LOD, lo = i - n * LOD;
        float v = 0.0f;
        if (msks[n]) {
            const float* g = &G[((size_t)t0s[n] * NSP + zs[n]) * LOD + lo];
            float g0 = g[0], g1 = g[NSP * LOD];
            v = g0 + wls[n] * (g1 - g0);
        }
        ps[n][lo] = v;
    }
    __syncthreads();
    if (t < 216) {
        int lo, yi;
        if (t < 24) { lo = t; yi = 0; }
        else if (t < 96) { int q = t - 24; int o = q / 3; lo = 24 + o; yi = 1 + (q - o * 3); }
        else { int q = t - 96; int o = q / 5; lo = 48 + o; yi = 4 + (q - o * 5); }
        float acc = 0.0f;
        #pragma unroll 4
        for (int n = 0; n < cN; ++n)
            acc = fmaf(ps[n][lo], ym[n][yi], acc);
        xr[3 + t] = acc * 0.125f;
    } else if (t < 219) {
        xr[t - 216] = body23[(size_t)ba * 3 + (t - 216)];
    }
    __syncthreads();
    if (t < CR) {
        float xv = xr[t];
        feats[(size_t)ba * C2 + t] = xv;
        float racc = res_b[t];
        for (int k = 0; k < CR; ++k)
            racc = fmaf(xr[k], res_W[k * CR + t], racc);
        feats[(size_t)ba * C2 + CR + t] = xv + sp5(racc);
    }
}

__global__ void __launch_bounds__(448) k_pool(const float* __restrict__ feats,
                                              float* __restrict__ pooled) {
    int b = blockIdx.x;
    int t = threadIdx.x;
    if (t < C2) {
        float s = 0.0f;
        for (int a = 0; a < cN; ++a) {
            float v = feats[(size_t)(b * cN + a) * C2 + t];
            s = fmaf(v, v, s);
        }
        pooled[b * C2 + t] = sqrtf(s);
    }
}

__global__ void __launch_bounds__(256) k_head(const float* __restrict__ pooled,
                                              const float* __restrict__ c_W,
                                              const float* __restrict__ c_b,
                                              const float* __restrict__ bn_g,
                                              const float* __restrict__ bn_b,
                                              const float* __restrict__ o_W,
                                              const float* __restrict__ o_b,
                                              float* __restrict__ out) {
    __shared__ float psm[cB][C2];
    __shared__ float hh[cB][HD];
    __shared__ float hh2[cB][HD];
    int t = threadIdx.x;
    for (int i = t; i < cB * C2; i += 256) psm[(unsigned)i / C2][(unsigned)i % C2] = pooled[i];
    __syncthreads();
    for (int o = t; o < cB * HD; o += 256) {
        int b = o >> 7, j = o & 127;
        float s0 = 0, s1 = 0, s2 = 0, s3 = 0;
        for (int ch = 0; ch < 436; ch += 4) {
            s0 = fmaf(psm[b][ch + 0], c_W[(ch + 0) * HD + j], s0);
            s1 = fmaf(psm[b][ch + 1], c_W[(ch + 1) * HD + j], s1);
            s2 = fmaf(psm[b][ch + 2], c_W[(ch + 2) * HD + j], s2);
            s3 = fmaf(psm[b][ch + 3], c_W[(ch + 3) * HD + j], s3);
        }
        s0 = fmaf(psm[b][436], c_W[436 * HD + j], s0);
        s1 = fmaf(psm[b][437], c_W[437 * HD + j], s1);
        hh[b][j] = sp1(((s0 + s1) + (s2 + s3)) + c_b[j]);
    }
    __syncthreads();
    if (t < HD) {
        int j = t;
        float mu = 0.0f;
        for (int bb = 0; bb < cB; ++bb) mu += hh[bb][j];
        mu *= (1.0f / cB);
        float var = 0.0f;
        for (int bb = 0; bb < cB; ++bb) { float d = hh[bb][j] - mu; var = fmaf(d, d, var); }
        var *= (1.0f / cB);
        float sc = bn_g[j] / sqrtf(var + 1e-5f);
        float bnb = bn_b[j];
        for (int bb = 0; bb < cB; ++bb)
            hh2[bb][j] = sp1((hh[bb][j] - mu) * sc + bnb);
    }
    __syncthreads();
    if (t < cB) {
        float s = o_b[0];
        for (int j = 0; j < HD; ++j) s = fmaf(hh2[t][j], o_W[j], s);
        out[t] = 1.0f / (1.0f + expf(-s));
    }
}

extern "C" void kernel_launch(void* const* d_in, const int* in_sizes, int n_in,
                              void* d_out, int out_size, void* d_ws, size_t ws_size,
                              hipStream_t stream) {
    const float* xyz    = (const float*)d_in[0];
    const int*   Z      = (const int*)d_in[1];
    const float* body23 = (const float*)d_in[2];
    const float* emb_W  = (const float*)d_in[3];
    const float* rW0    = (const float*)d_in[4];
    const float* rb0    = (const float*)d_in[5];
    const float* rW1    = (const float*)d_in[6];
    const float* rb1    = (const float*)d_in[7];
    const float* rW2    = (const float*)d_in[8];
    const float* rb2    = (const float*)d_in[9];
    const float* rW3    = (const float*)d_in[10];
    const float* rb3    = (const float*)d_in[11];
    const float* res_W  = (const float*)d_in[12];
    const float* res_b  = (const float*)d_in[13];
    const float* c_W    = (const float*)d_in[14];
    const float* c_b    = (const float*)d_in[15];
    const float* bn_g   = (const float*)d_in[16];
    const float* bn_b   = (const float*)d_in[17];
    const float* o_W    = (const float*)d_in[18];
    const float* o_b    = (const float*)d_in[19];

    float* w      = (float*)d_ws;
    float* Wpz    = w;                        // 6*150*72   = 64800
    float* Pbz    = Wpz + 64800;              // 6*72       = 432
    float* G      = Pbz + 432;                // 8192*6*72  = 3538944
    float* feats  = G + 3538944;              // 1024*438   = 448512
    float* pooled = feats + 448512;           // 16*438
    (void)in_sizes; (void)n_in; (void)out_size; (void)ws_size;

    k_wz   <<<NSP, 256, 0, stream>>>(emb_W, rW3, rb3, Wpz, Pbz);
    k_chain<<<TBL / 32, 256, 0, stream>>>(rW0, rb0, rW1, rb1, rW2, rb2, Wpz, Pbz, G);
    k_red  <<<cB * cN, 256, 0, stream>>>(xyz, Z, body23, G, res_W, res_b, feats);
    k_pool <<<cB, 448, 0, stream>>>(feats, pooled);
    k_head <<<1, 256, 0, stream>>>(pooled, c_W, c_b, bn_g, bn_b, o_W, o_b, (float*)d_out);
}

// Round 10
// 331.168 us; speedup vs baseline: 1.8715x; 1.0718x over previous
//
#include <hip/hip_runtime.h>
#include <math.h>

constexpr int cB  = 16;
constexpr int cN  = 64;
constexpr int EMB = 32;
constexpr int NL  = 3;
constexpr int CDIM = 24;
constexpr int LOD = NL * CDIM;      // 72
constexpr int NB  = 10;
constexpr int H   = 150;
constexpr int CR  = 219;
constexpr int C2  = 438;
constexpr int HD  = 128;
constexpr int NSP = 6;              // species count
constexpr int TBL = 8192;
constexpr float RADIUS = 2.0f;

__device__ __forceinline__ float sp5(float x) {
    return fmaxf(x, 0.0f) + 0.2f * log1pf(expf(-5.0f * fabsf(x)));
}
__device__ __forceinline__ float sp1(float x) {
    return fmaxf(x, 0.0f) + log1pf(expf(-fabsf(x)));
}

// per species z: Wpz[z][h][lo] = sum_i rW3[h][lo*32+i]*emb[z][i]; Pbz[z][lo] from rb3
__global__ void __launch_bounds__(256) k_wz(const float* __restrict__ emb_W,
                                            const float* __restrict__ rW3,
                                            const float* __restrict__ rb3,
                                            float* __restrict__ Wpz,
                                            float* __restrict__ Pbz) {
    int z = blockIdx.x;
    __shared__ float e[EMB];
    int t = threadIdx.x;
    if (t < EMB) e[t] = emb_W[z * EMB + t];
    __syncthreads();
    for (int o = t; o < H * LOD; o += 256) {
        int h = o / LOD, lo = o - h * LOD;
        const float* wr = &rW3[(size_t)h * (LOD * EMB) + lo * EMB];
        float s = 0.0f;
        #pragma unroll
        for (int i = 0; i < EMB; ++i) s = fmaf(wr[i], e[i], s);
        Wpz[(size_t)z * (H * LOD) + o] = s;
    }
    if (t < LOD) {
        float s = 0.0f;
        #pragma unroll
        for (int i = 0; i < EMB; ++i) s = fmaf(rb3[t * EMB + i], e[i], s);
        Pbz[z * LOD + t] = s;
    }
}

// Fused table chain. Per block: 8 table rows, 1024 blocks -> 4 blocks/CU (16 waves/CU)
// so cross-block waves hide LDS/stage latency. 256 thr = 8 rows x 32 col-groups.
// basis -> L0 -> L1 -> L2 -> G (6 species x 6 chunks of 25 rows), double-buffered.
__global__ void __launch_bounds__(256) k_chain(const float* __restrict__ rW0,
                                               const float* __restrict__ rb0,
                                               const float* __restrict__ rW1,
                                               const float* __restrict__ rb1,
                                               const float* __restrict__ rW2,
                                               const float* __restrict__ rb2,
                                               const float* __restrict__ Wpz,
                                               const float* __restrict__ Pbz,
                                               float* __restrict__ G) {
    int row0 = blockIdx.x * 8;
    int t = threadIdx.x;
    __shared__ float bas[8][10];
    __shared__ float hA[8 * 150];
    __shared__ float bs[160];
    __shared__ float pz[NSP * LOD];
    __shared__ float S[6000];                 // union scratch (24 KB)
    float* hBf = S;                           // [8*150] in L-phases
    float (*Wt)[15][160] = reinterpret_cast<float (*)[15][160]>(S + 1200);  // 2x15x160
    float (*Wz)[25][72]  = reinterpret_cast<float (*)[25][72]>(S);          // 2x25x72 in G-phase

    int a2 = t >> 5, jt = t & 31;
    int j0 = jt * 5;       // L-phase: 32 col-groups x 5 (150 covered, guard at 150)
    int lo0 = jt * 3;      // G-phase: 24 active groups x 3 = 72 (jt>=24 idle)

    // ---- prologue: basis, pz, L0 weights + bias ----
    if (t < 8) {
        float r = (float)(row0 + t) * (RADIUS / (float)(TBL - 1));
        #pragma unroll
        for (int k = 0; k < NB; ++k) {
            float d = r * 4.5f - (float)k;
            float v = 0.0f;
            if (fabsf(d) < 1.0f) { float cc = cosf(1.57079632679489662f * d); v = cc * cc; }
            bas[t][k] = v;
        }
    }
    for (int i = t; i < NSP * LOD; i += 256) pz[i] = Pbz[i];
    for (int i = t; i < NB * 160; i += 256) {
        int kr = (unsigned)i / 160, j = i - kr * 160;
        Wt[0][kr][j] = (j < H) ? rW0[(size_t)kr * H + j] : 0.0f;
    }
    if (t < 160) bs[t] = (t < H) ? rb0[t] : 0.0f;
    __syncthreads();

    // ---- L0: bas[8][10] @ rW0 ----
    {
        float acc[5];
        #pragma unroll
        for (int q = 0; q < 5; ++q) acc[q] = 0.0f;
        #pragma unroll
        for (int k = 0; k < NB; ++k) {
            float x = bas[a2][k];
            #pragma unroll
            for (int q = 0; q < 5; ++q) acc[q] = fmaf(x, Wt[0][k][j0 + q], acc[q]);
        }
        #pragma unroll
        for (int q = 0; q < 5; ++q) {
            int j = j0 + q;
            if (j < H) hA[a2 * 150 + j] = sp5(acc[q] + bs[j]);
        }
    }
    __syncthreads();   // hA ready; Wt/bs reads done

    // ---- L1 (hA->hB), L2 (hB->hA): 10 tiles of 15 rows, double-buffered ----
    for (int layer = 0; layer < 2; ++layer) {
        const float* W   = layer ? rW2 : rW1;
        const float* bb  = layer ? rb2 : rb1;
        const float* src = layer ? hBf : hA;
        float*       dst = layer ? hA  : hBf;
        for (int i = t; i < 15 * 160; i += 256) {
            int kr = (unsigned)i / 160, j = i - kr * 160;
            Wt[0][kr][j] = (j < H) ? W[(size_t)kr * H + j] : 0.0f;
        }
        if (t < 160) bs[t] = (t < H) ? bb[t] : 0.0f;
        __syncthreads();
        float acc[5];
        #pragma unroll
        for (int q = 0; q < 5; ++q) acc[q] = 0.0f;
        int buf = 0;
        for (int tile = 0; tile < 10; ++tile) {
            if (tile < 9) {      // prefetch next tile into the idle buffer
                int kk2 = (tile + 1) * 15;
                for (int i = t; i < 15 * 160; i += 256) {
                    int kr = (unsigned)i / 160, j = i - kr * 160;
                    Wt[buf ^ 1][kr][j] = (j < H) ? W[(size_t)(kk2 + kr) * H + j] : 0.0f;
                }
            }
            int kk = tile * 15;
            #pragma unroll 5
            for (int kr = 0; kr < 15; ++kr) {
                float x = src[a2 * 150 + kk + kr];
                #pragma unroll
                for (int q = 0; q < 5; ++q) acc[q] = fmaf(x, Wt[buf][kr][j0 + q], acc[q]);
            }
            __syncthreads();
            buf ^= 1;
        }
        #pragma unroll
        for (int q = 0; q < 5; ++q) {
            int j = j0 + q;
            if (j < H) dst[a2 * 150 + j] = sp5(acc[q] + bs[j]);
        }
        __syncthreads();
    }

    // ---- G: 36 segments (6 species x 6 chunks of 25 rows), double-buffered ----
    {
        float ac[3];
        #pragma unroll
        for (int q = 0; q < 3; ++q) ac[q] = 0.0f;
        for (int i = t; i < 25 * 72; i += 256) {         // stage seg 0 (z=0, rows 0..24)
            int kr = (unsigned)i / 72, lo = i - kr * 72;
            Wz[0][kr][lo] = Wpz[(size_t)kr * LOD + lo];
        }
        __syncthreads();
        int gbuf = 0;
        for (int s = 0; s < 36; ++s) {
            if (s < 35) {
                int s2 = s + 1, z2 = s2 / 6, base2 = (s2 - z2 * 6) * 25;
                for (int i = t; i < 25 * 72; i += 256) {
                    int kr = (unsigned)i / 72, lo = i - kr * 72;
                    Wz[gbuf ^ 1][kr][lo] =
                        Wpz[(size_t)z2 * (H * LOD) + (size_t)(base2 + kr) * LOD + lo];
                }
            }
            int z = s / 6, chunk = s - z * 6, base = chunk * 25;
            if (lo0 < LOD) {
                #pragma unroll 5
                for (int kr = 0; kr < 25; ++kr) {
                    float x = hA[a2 * 150 + base + kr];
                    #pragma unroll
                    for (int q = 0; q < 3; ++q) ac[q] = fmaf(x, Wz[gbuf][kr][lo0 + q], ac[q]);
                }
            }
            if (chunk == 5 && lo0 < LOD) {               // last chunk of this z
                float* gp = &G[((size_t)(row0 + a2) * NSP + z) * LOD + lo0];
                #pragma unroll
                for (int q = 0; q < 3; ++q) { gp[q] = ac[q] + pz[z * LOD + lo0 + q]; ac[q] = 0.0f; }
            }
            __syncthreads();
            gbuf ^= 1;
        }
    }
}

// fused per (b,a): pair mask + G-lerp -> ps[n][72] in LDS; Y-reduce; body23 concat; residual
__global__ void __launch_bounds__(256) k_red(const float* __restrict__ xyz,
                                             const int* __restrict__ Z,
                                             const float* __restrict__ body23,
                                             const float* __restrict__ G,
                                             const float* __restrict__ res_W,
                                             const float* __restrict__ res_b,
                                             float* __restrict__ feats) {
    int ba = blockIdx.x;
    int b = ba >> 6, a = ba & 63;
    int t = threadIdx.x;
    __shared__ float ym[64][12];
    __shared__ float ps[64][76];
    __shared__ float xr[CR];
    __shared__ int t0s[64];
    __shared__ float wls[64];
    __shared__ int zs[64];
    __shared__ int msks[64];
    if (t < 64) {
        int n = t;
        float ax = xyz[((size_t)b * cN + a) * 3 + 0];
        float ay = xyz[((size_t)b * cN + a) * 3 + 1];
        float az = xyz[((size_t)b * cN + a) * 3 + 2];
        float d0 = ax - xyz[((size_t)b * cN + n) * 3 + 0];
        float d1 = ay - xyz[((size_t)b * cN + n) * 3 + 1];
        float d2 = az - xyz[((size_t)b * cN + n) * 3 + 2];
        float s = d0 * d0 + d1 * d1 + d2 * d2;
        float r = sqrtf(s + 1e-12f);
        msks[n] = (r < RADIUS) && (r > 1e-6f);
        float u = r * ((float)(TBL - 1) / RADIUS);
        int t0 = (int)u;
        if (t0 > TBL - 2) t0 = TBL - 2;
        t0s[n] = t0;
        wls[n] = u - (float)t0;
        zs[n] = Z[b * cN + n];
        float inv = 1.0f / r;
        float x = d0 * inv, y = d1 * inv, z = d2 * inv;
        ym[n][0] = 0.28209479177387814f;
        ym[n][1] = 0.4886025119029199f * y;
        ym[n][2] = 0.4886025119029199f * z;
        ym[n][3] = 0.4886025119029199f * x;
        ym[n][4] = 1.0925484305920792f * x * y;
        ym[n][5] = 1.0925484305920792f * y * z;
        ym[n][6] = 0.31539156525252005f * (3.0f * z * z - 1.0f);
        ym[n][7] = 1.0925484305920792f * x * z;
        ym[n][8] = 0.5462742152960396f * (x * x - y * y);
    }
    __syncthreads();
    for (int i = t; i < 64 * LOD; i += 256) {
        int n = i / LOD, lo = i - n * LOD;
        float v = 0.0f;
        if (msks[n]) {
            const float* g = &G[((size_t)t0s[n] * NSP + zs[n]) * LOD + lo];
            float g0 = g[0], g1 = g[NSP * LOD];
            v = g0 + wls[n] * (g1 - g0);
        }
        ps[n][lo] = v;
    }
    __syncthreads();
    if (t < 216) {
        int lo, yi;
        if (t < 24) { lo = t; yi = 0; }
        else if (t < 96) { int q = t - 24; int o = q / 3; lo = 24 + o; yi = 1 + (q - o * 3); }
        else { int q = t - 96; int o = q / 5; lo = 48 + o; yi = 4 + (q - o * 5); }
        float acc = 0.0f;
        #pragma unroll 4
        for (int n = 0; n < cN; ++n)
            acc = fmaf(ps[n][lo], ym[n][yi], acc);
        xr[3 + t] = acc * 0.125f;
    } else if (t < 219) {
        xr[t - 216] = body23[(size_t)ba * 3 + (t - 216)];
    }
    __syncthreads();
    if (t < CR) {
        float xv = xr[t];
        feats[(size_t)ba * C2 + t] = xv;
        float racc = res_b[t];
        for (int k = 0; k < CR; ++k)
            racc = fmaf(xr[k], res_W[k * CR + t], racc);
        feats[(size_t)ba * C2 + CR + t] = xv + sp5(racc);
    }
}

__global__ void __launch_bounds__(448) k_pool(const float* __restrict__ feats,
                                              float* __restrict__ pooled) {
    int b = blockIdx.x;
    int t = threadIdx.x;
    if (t < C2) {
        float s = 0.0f;
        for (int a = 0; a < cN; ++a) {
            float v = feats[(size_t)(b * cN + a) * C2 + t];
            s = fmaf(v, v, s);
        }
        pooled[b * C2 + t] = sqrtf(s);
    }
}

__global__ void __launch_bounds__(256) k_head(const float* __restrict__ pooled,
                                              const float* __restrict__ c_W,
                                              const float* __restrict__ c_b,
                                              const float* __restrict__ bn_g,
                                              const float* __restrict__ bn_b,
                                              const float* __restrict__ o_W,
                                              const float* __restrict__ o_b,
                                              float* __restrict__ out) {
    __shared__ float psm[cB][C2];
    __shared__ float hh[cB][HD];
    __shared__ float hh2[cB][HD];
    int t = threadIdx.x;
    for (int i = t; i < cB * C2; i += 256) psm[(unsigned)i / C2][(unsigned)i % C2] = pooled[i];
    __syncthreads();
    for (int o = t; o < cB * HD; o += 256) {
        int b = o >> 7, j = o & 127;
        float s0 = 0, s1 = 0, s2 = 0, s3 = 0;
        for (int ch = 0; ch < 436; ch += 4) {
            s0 = fmaf(psm[b][ch + 0], c_W[(ch + 0) * HD + j], s0);
            s1 = fmaf(psm[b][ch + 1], c_W[(ch + 1) * HD + j], s1);
            s2 = fmaf(psm[b][ch + 2], c_W[(ch + 2) * HD + j], s2);
            s3 = fmaf(psm[b][ch + 3], c_W[(ch + 3) * HD + j], s3);
        }
        s0 = fmaf(psm[b][436], c_W[436 * HD + j], s0);
        s1 = fmaf(psm[b][437], c_W[437 * HD + j], s1);
        hh[b][j] = sp1(((s0 + s1) + (s2 + s3)) + c_b[j]);
    }
    __syncthreads();
    if (t < HD) {
        int j = t;
        float mu = 0.0f;
        for (int bb = 0; bb < cB; ++bb) mu += hh[bb][j];
        mu *= (1.0f / cB);
        float var = 0.0f;
        for (int bb = 0; bb < cB; ++bb) { float d = hh[bb][j] - mu; var = fmaf(d, d, var); }
        var *= (1.0f / cB);
        float sc = bn_g[j] / sqrtf(var + 1e-5f);
        float bnb = bn_b[j];
        for (int bb = 0; bb < cB; ++bb)
            hh2[bb][j] = sp1((hh[bb][j] - mu) * sc + bnb);
    }
    __syncthreads();
    if (t < cB) {
        float s = o_b[0];
        for (int j = 0; j < HD; ++j) s = fmaf(hh2[t][j], o_W[j], s);
        out[t] = 1.0f / (1.0f + expf(-s));
    }
}

extern "C" void kernel_launch(void* const* d_in, const int* in_sizes, int n_in,
                              void* d_out, int out_size, void* d_ws, size_t ws_size,
                              hipStream_t stream) {
    const float* xyz    = (const float*)d_in[0];
    const int*   Z      = (const int*)d_in[1];
    const float* body23 = (const float*)d_in[2];
    const float* emb_W  = (const float*)d_in[3];
    const float* rW0    = (const float*)d_in[4];
    const float* rb0    = (const float*)d_in[5];
    const float* rW1    = (const float*)d_in[6];
    const float* rb1    = (const float*)d_in[7];
    const float* rW2    = (const float*)d_in[8];
    const float* rb2    = (const float*)d_in[9];
    const float* rW3    = (const float*)d_in[10];
    const float* rb3    = (const float*)d_in[11];
    const float* res_W  = (const float*)d_in[12];
    const float* res_b  = (const float*)d_in[13];
    const float* c_W    = (const float*)d_in[14];
    const float* c_b    = (const float*)d_in[15];
    const float* bn_g   = (const float*)d_in[16];
    const float* bn_b   = (const float*)d_in[17];
    const float* o_W    = (const float*)d_in[18];
    const float* o_b    = (const float*)d_in[19];

    float* w      = (float*)d_ws;
    float* Wpz    = w;                        // 6*150*72   = 64800
    float* Pbz    = Wpz + 64800;              // 6*72       = 432
    float* G      = Pbz + 432;                // 8192*6*72  = 3538944
    float* feats  = G + 3538944;              // 1024*438   = 448512
    float* pooled = feats + 448512;           // 16*438
    (void)in_sizes; (void)n_in; (void)out_size; (void)ws_size;

    k_wz   <<<NSP, 256, 0, stream>>>(emb_W, rW3, rb3, Wpz, Pbz);
    k_chain<<<TBL / 8, 256, 0, stream>>>(rW0, rb0, rW1, rb1, rW2, rb2, Wpz, Pbz, G);
    k_red  <<<cB * cN, 256, 0, stream>>>(xyz, Z, body23, G, res_W, res_b, feats);
    k_pool <<<cB, 448, 0, stream>>>(feats, pooled);
    k_head <<<1, 256, 0, stream>>>(pooled, c_W, c_b, bn_g, bn_b, o_W, o_b, (float*)d_out);
}

// Round 11
// 288.129 us; speedup vs baseline: 2.1510x; 1.1494x over previous
//
#include <hip/hip_runtime.h>
#include <math.h>

constexpr int cB  = 16;
constexpr int cN  = 64;
constexpr int EMB = 32;
constexpr int NL  = 3;
constexpr int CDIM = 24;
constexpr int LOD = NL * CDIM;      // 72
constexpr int NB  = 10;
constexpr int H   = 150;
constexpr int CR  = 219;
constexpr int C2  = 438;
constexpr int HD  = 128;
constexpr int NSP = 6;              // species count
constexpr int TBL = 8192;
constexpr float RADIUS = 2.0f;

__device__ __forceinline__ float sp5(float x) {
    return fmaxf(x, 0.0f) + 0.2f * log1pf(expf(-5.0f * fabsf(x)));
}
__device__ __forceinline__ float sp1(float x) {
    return fmaxf(x, 0.0f) + log1pf(expf(-fabsf(x)));
}

// per species z: Wpz[z][h][lo] = sum_i rW3[h][lo*32+i]*emb[z][i]; Pbz[z][lo] from rb3
__global__ void __launch_bounds__(256) k_wz(const float* __restrict__ emb_W,
                                            const float* __restrict__ rW3,
                                            const float* __restrict__ rb3,
                                            float* __restrict__ Wpz,
                                            float* __restrict__ Pbz) {
    int z = blockIdx.x;
    __shared__ float e[EMB];
    int t = threadIdx.x;
    if (t < EMB) e[t] = emb_W[z * EMB + t];
    __syncthreads();
    for (int o = t; o < H * LOD; o += 256) {
        int h = o / LOD, lo = o - h * LOD;
        const float* wr = &rW3[(size_t)h * (LOD * EMB) + lo * EMB];
        float s = 0.0f;
        #pragma unroll
        for (int i = 0; i < EMB; ++i) s = fmaf(wr[i], e[i], s);
        Wpz[(size_t)z * (H * LOD) + o] = s;
    }
    if (t < LOD) {
        float s = 0.0f;
        #pragma unroll
        for (int i = 0; i < EMB; ++i) s = fmaf(rb3[t * EMB + i], e[i], s);
        Pbz[z * LOD + t] = s;
    }
}

// Fused table chain. 32 rows/block, 4 rows/thread, 256 blocks (1 blk/CU).
// W-reads are float4 from 152/72-padded LDS rows; x-reads are float2 broadcasts.
// One b128 W-read feeds 16 FMAs -> LDS-issue load drops ~6x vs scalar version.
__global__ void __launch_bounds__(256) k_chain(const float* __restrict__ rW0,
                                               const float* __restrict__ rb0,
                                               const float* __restrict__ rW1,
                                               const float* __restrict__ rb1,
                                               const float* __restrict__ rW2,
                                               const float* __restrict__ rb2,
                                               const float* __restrict__ Wpz,
                                               const float* __restrict__ Pbz,
                                               float* __restrict__ G) {
    const int row0 = blockIdx.x * 32;
    const int t = threadIdx.x;
    const int a2 = t >> 5;                   // 0..7 (base row)
    const int jt = t & 31;                   // col group
    const int j0 = jt * 4;                   // b128 cols [j0, j0+4)
    const int jx = (jt < 22) ? 128 + jt : 128;   // extra col 128..149
    const int lo0 = (jt < 18) ? jt * 4 : 0;  // G-phase cols (72 = 18*4)

    __shared__ __align__(16) float bas[32][10];
    __shared__ __align__(16) float hA[32 * 152];
    __shared__ __align__(16) float bs[152];
    __shared__ __align__(16) float pz[NSP * LOD];
    __shared__ __align__(16) float S[7904];  // hBf[4864] + WtL[2*1520]; G: Wz[2*3600]
    float* hBf = S;
    float* WtL = S + 4864;
    float* Wz  = S;

    // ---- prologue ----
    if (t < 32) {
        float r = (float)(row0 + t) * (RADIUS / (float)(TBL - 1));
        #pragma unroll
        for (int k = 0; k < NB; ++k) {
            float d = r * 4.5f - (float)k;
            float v = 0.0f;
            if (fabsf(d) < 1.0f) { float cc = cosf(1.57079632679489662f * d); v = cc * cc; }
            bas[t][k] = v;
        }
    }
    for (int i = t; i < NSP * LOD; i += 256) pz[i] = Pbz[i];
    for (int i = t; i < 10 * 75; i += 256) {             // rW0 -> WtL[0]
        int r = i / 75, c = i - r * 75;
        *(float2*)&WtL[r * 152 + 2 * c] = *(const float2*)&rW0[r * H + 2 * c];
    }
    if (t < 152) bs[t] = (t < H) ? rb0[t] : 0.0f;
    __syncthreads();

    // ---- L0 ----
    {
        float acc[4][4] = {{0}}; float accx[4] = {0};
        #pragma unroll
        for (int k = 0; k < NB; ++k) {
            float4 w = *(float4*)&WtL[k * 152 + j0];
            float wx = WtL[k * 152 + jx];
            #pragma unroll
            for (int rr = 0; rr < 4; ++rr) {
                float x = bas[a2 + 8 * rr][k];
                acc[rr][0] = fmaf(x, w.x, acc[rr][0]);
                acc[rr][1] = fmaf(x, w.y, acc[rr][1]);
                acc[rr][2] = fmaf(x, w.z, acc[rr][2]);
                acc[rr][3] = fmaf(x, w.w, acc[rr][3]);
                accx[rr]   = fmaf(x, wx,  accx[rr]);
            }
        }
        #pragma unroll
        for (int rr = 0; rr < 4; ++rr) {
            int row = a2 + 8 * rr;
            hA[row * 152 + j0 + 0] = sp5(acc[rr][0] + bs[j0 + 0]);
            hA[row * 152 + j0 + 1] = sp5(acc[rr][1] + bs[j0 + 1]);
            hA[row * 152 + j0 + 2] = sp5(acc[rr][2] + bs[j0 + 2]);
            hA[row * 152 + j0 + 3] = sp5(acc[rr][3] + bs[j0 + 3]);
            if (jt < 22) hA[row * 152 + 128 + jt] = sp5(accx[rr] + bs[128 + jt]);
        }
    }
    __syncthreads();

    // ---- L1 (hA->hBf), L2 (hBf->hA): 15 tiles of 10 K-rows, double-buffered ----
    for (int layer = 0; layer < 2; ++layer) {
        const float* W   = layer ? rW2 : rW1;
        const float* bb  = layer ? rb2 : rb1;
        const float* src = layer ? hBf : hA;
        float*       dst = layer ? hA  : hBf;
        for (int i = t; i < 750; i += 256) {
            int r = i / 75, c = i - r * 75;
            *(float2*)&WtL[r * 152 + 2 * c] = *(const float2*)&W[(size_t)r * H + 2 * c];
        }
        if (t < 152) bs[t] = (t < H) ? bb[t] : 0.0f;
        __syncthreads();
        float acc[4][4] = {{0}}; float accx[4] = {0};
        int buf = 0;
        for (int tile = 0; tile < 15; ++tile) {
            if (tile < 14) {
                const float* Wn = W + (size_t)(tile + 1) * 10 * H;
                float* dw = WtL + (buf ^ 1) * 1520;
                for (int i = t; i < 750; i += 256) {
                    int r = i / 75, c = i - r * 75;
                    *(float2*)&dw[r * 152 + 2 * c] = *(const float2*)&Wn[(size_t)r * H + 2 * c];
                }
            }
            const float* Wb = WtL + buf * 1520;
            int kk = tile * 10;
            #pragma unroll
            for (int k2 = 0; k2 < 5; ++k2) {
                float4 wA = *(float4*)&Wb[(2 * k2) * 152 + j0];
                float4 wB = *(float4*)&Wb[(2 * k2 + 1) * 152 + j0];
                float wxA = Wb[(2 * k2) * 152 + jx];
                float wxB = Wb[(2 * k2 + 1) * 152 + jx];
                #pragma unroll
                for (int rr = 0; rr < 4; ++rr) {
                    float2 x = *(float2*)&src[(a2 + 8 * rr) * 152 + kk + 2 * k2];
                    acc[rr][0] = fmaf(x.x, wA.x, acc[rr][0]);
                    acc[rr][1] = fmaf(x.x, wA.y, acc[rr][1]);
                    acc[rr][2] = fmaf(x.x, wA.z, acc[rr][2]);
                    acc[rr][3] = fmaf(x.x, wA.w, acc[rr][3]);
                    accx[rr]   = fmaf(x.x, wxA,  accx[rr]);
                    acc[rr][0] = fmaf(x.y, wB.x, acc[rr][0]);
                    acc[rr][1] = fmaf(x.y, wB.y, acc[rr][1]);
                    acc[rr][2] = fmaf(x.y, wB.z, acc[rr][2]);
                    acc[rr][3] = fmaf(x.y, wB.w, acc[rr][3]);
                    accx[rr]   = fmaf(x.y, wxB,  accx[rr]);
                }
            }
            __syncthreads();
            buf ^= 1;
        }
        #pragma unroll
        for (int rr = 0; rr < 4; ++rr) {
            int row = a2 + 8 * rr;
            dst[row * 152 + j0 + 0] = sp5(acc[rr][0] + bs[j0 + 0]);
            dst[row * 152 + j0 + 1] = sp5(acc[rr][1] + bs[j0 + 1]);
            dst[row * 152 + j0 + 2] = sp5(acc[rr][2] + bs[j0 + 2]);
            dst[row * 152 + j0 + 3] = sp5(acc[rr][3] + bs[j0 + 3]);
            if (jt < 22) dst[row * 152 + 128 + jt] = sp5(accx[rr] + bs[128 + jt]);
        }
        __syncthreads();
    }

    // ---- G: 18 segments (6 z x 3 chunks of 50 K-rows), double-buffered ----
    {
        float ac[4][4] = {{0}};
        for (int i = t; i < 1800; i += 256) {            // seg 0: z=0, rows 0..49
            int r = i / 36, c = i - r * 36;
            *(float2*)&Wz[r * 72 + 2 * c] = *(const float2*)&Wpz[(size_t)r * 72 + 2 * c];
        }
        __syncthreads();
        int gbuf = 0;
        for (int s = 0; s < 18; ++s) {
            if (s < 17) {
                int s2 = s + 1, z2 = s2 / 3, base2 = (s2 - z2 * 3) * 50;
                const float* Wn = Wpz + (size_t)z2 * (H * LOD) + (size_t)base2 * 72;
                float* dw = Wz + (gbuf ^ 1) * 3600;
                for (int i = t; i < 1800; i += 256) {
                    int r = i / 36, c = i - r * 36;
                    *(float2*)&dw[r * 72 + 2 * c] = *(const float2*)&Wn[(size_t)r * 72 + 2 * c];
                }
            }
            int z = s / 3, chunk = s - z * 3, base = chunk * 50;
            const float* Wb = Wz + gbuf * 3600;
            #pragma unroll 5
            for (int k2 = 0; k2 < 25; ++k2) {
                float4 wA = *(float4*)&Wb[(2 * k2) * 72 + lo0];
                float4 wB = *(float4*)&Wb[(2 * k2 + 1) * 72 + lo0];
                #pragma unroll
                for (int rr = 0; rr < 4; ++rr) {
                    float2 x = *(float2*)&hA[(a2 + 8 * rr) * 152 + base + 2 * k2];
                    ac[rr][0] = fmaf(x.x, wA.x, ac[rr][0]);
                    ac[rr][1] = fmaf(x.x, wA.y, ac[rr][1]);
                    ac[rr][2] = fmaf(x.x, wA.z, ac[rr][2]);
                    ac[rr][3] = fmaf(x.x, wA.w, ac[rr][3]);
                    ac[rr][0] = fmaf(x.y, wB.x, ac[rr][0]);
                    ac[rr][1] = fmaf(x.y, wB.y, ac[rr][1]);
                    ac[rr][2] = fmaf(x.y, wB.z, ac[rr][2]);
                    ac[rr][3] = fmaf(x.y, wB.w, ac[rr][3]);
                }
            }
            if (chunk == 2) {
                if (jt < 18) {
                    #pragma unroll
                    for (int rr = 0; rr < 4; ++rr) {
                        int row = row0 + a2 + 8 * rr;
                        float4 o;
                        o.x = ac[rr][0] + pz[z * LOD + lo0 + 0];
                        o.y = ac[rr][1] + pz[z * LOD + lo0 + 1];
                        o.z = ac[rr][2] + pz[z * LOD + lo0 + 2];
                        o.w = ac[rr][3] + pz[z * LOD + lo0 + 3];
                        *(float4*)&G[((size_t)row * NSP + z) * LOD + lo0] = o;
                    }
                }
                #pragma unroll
                for (int rr = 0; rr < 4; ++rr) {
                    ac[rr][0] = 0.0f; ac[rr][1] = 0.0f; ac[rr][2] = 0.0f; ac[rr][3] = 0.0f;
                }
            }
            __syncthreads();
            gbuf ^= 1;
        }
    }
}

// fused per (b,a): pair mask + G-lerp -> ps[n][72] in LDS; Y-reduce; body23 concat; residual
__global__ void __launch_bounds__(256) k_red(const float* __restrict__ xyz,
                                             const int* __restrict__ Z,
                                             const float* __restrict__ body23,
                                             const float* __restrict__ G,
                                             const float* __restrict__ res_W,
                                             const float* __restrict__ res_b,
                                             float* __restrict__ feats) {
    int ba = blockIdx.x;
    int b = ba >> 6, a = ba & 63;
    int t = threadIdx.x;
    __shared__ float ym[64][12];
    __shared__ float ps[64][76];
    __shared__ float xr[CR];
    __shared__ int t0s[64];
    __shared__ float wls[64];
    __shared__ int zs[64];
    __shared__ int msks[64];
    if (t < 64) {
        int n = t;
        float ax = xyz[((size_t)b * cN + a) * 3 + 0];
        float ay = xyz[((size_t)b * cN + a) * 3 + 1];
        float az = xyz[((size_t)b * cN + a) * 3 + 2];
        float d0 = ax - xyz[((size_t)b * cN + n) * 3 + 0];
        float d1 = ay - xyz[((size_t)b * cN + n) * 3 + 1];
        float d2 = az - xyz[((size_t)b * cN + n) * 3 + 2];
        float s = d0 * d0 + d1 * d1 + d2 * d2;
        float r = sqrtf(s + 1e-12f);
        msks[n] = (r < RADIUS) && (r > 1e-6f);
        float u = r * ((float)(TBL - 1) / RADIUS);
        int t0 = (int)u;
        if (t0 > TBL - 2) t0 = TBL - 2;
        t0s[n] = t0;
        wls[n] = u - (float)t0;
        zs[n] = Z[b * cN + n];
        float inv = 1.0f / r;
        float x = d0 * inv, y = d1 * inv, z = d2 * inv;
        ym[n][0] = 0.28209479177387814f;
        ym[n][1] = 0.4886025119029199f * y;
        ym[n][2] = 0.4886025119029199f * z;
        ym[n][3] = 0.4886025119029199f * x;
        ym[n][4] = 1.0925484305920792f * x * y;
        ym[n][5] = 1.0925484305920792f * y * z;
        ym[n][6] = 0.31539156525252005f * (3.0f * z * z - 1.0f);
        ym[n][7] = 1.0925484305920792f * x * z;
        ym[n][8] = 0.5462742152960396f * (x * x - y * y);
    }
    __syncthreads();
    for (int i = t; i < 64 * LOD; i += 256) {
        int n = i / LOD, lo = i - n * LOD;
        float v = 0.0f;
        if (msks[n]) {
            const float* g = &G[((size_t)t0s[n] * NSP + zs[n]) * LOD + lo];
            float g0 = g[0], g1 = g[NSP * LOD];
            v = g0 + wls[n] * (g1 - g0);
        }
        ps[n][lo] = v;
    }
    __syncthreads();
    if (t < 216) {
        int lo, yi;
        if (t < 24) { lo = t; yi = 0; }
        else if (t < 96) { int q = t - 24; int o = q / 3; lo = 24 + o; yi = 1 + (q - o * 3); }
        else { int q = t - 96; int o = q / 5; lo = 48 + o; yi = 4 + (q - o * 5); }
        float acc = 0.0f;
        #pragma unroll 4
        for (int n = 0; n < cN; ++n)
            acc = fmaf(ps[n][lo], ym[n][yi], acc);
        xr[3 + t] = acc * 0.125f;
    } else if (t < 219) {
        xr[t - 216] = body23[(size_t)ba * 3 + (t - 216)];
    }
    __syncthreads();
    if (t < CR) {
        float xv = xr[t];
        feats[(size_t)ba * C2 + t] = xv;
        float racc = res_b[t];
        for (int k = 0; k < CR; ++k)
            racc = fmaf(xr[k], res_W[k * CR + t], racc);
        feats[(size_t)ba * C2 + CR + t] = xv + sp5(racc);
    }
}

__global__ void __launch_bounds__(448) k_pool(const float* __restrict__ feats,
                                              float* __restrict__ pooled) {
    int b = blockIdx.x;
    int t = threadIdx.x;
    if (t < C2) {
        float s = 0.0f;
        for (int a = 0; a < cN; ++a) {
            float v = feats[(size_t)(b * cN + a) * C2 + t];
            s = fmaf(v, v, s);
        }
        pooled[b * C2 + t] = sqrtf(s);
    }
}

__global__ void __launch_bounds__(256) k_head(const float* __restrict__ pooled,
                                              const float* __restrict__ c_W,
                                              const float* __restrict__ c_b,
                                              const float* __restrict__ bn_g,
                                              const float* __restrict__ bn_b,
                                              const float* __restrict__ o_W,
                                              const float* __restrict__ o_b,
                                              float* __restrict__ out) {
    __shared__ float psm[cB][C2];
    __shared__ float hh[cB][HD];
    __shared__ float hh2[cB][HD];
    int t = threadIdx.x;
    for (int i = t; i < cB * C2; i += 256) psm[(unsigned)i / C2][(unsigned)i % C2] = pooled[i];
    __syncthreads();
    for (int o = t; o < cB * HD; o += 256) {
        int b = o >> 7, j = o & 127;
        float s0 = 0, s1 = 0, s2 = 0, s3 = 0;
        for (int ch = 0; ch < 436; ch += 4) {
            s0 = fmaf(psm[b][ch + 0], c_W[(ch + 0) * HD + j], s0);
            s1 = fmaf(psm[b][ch + 1], c_W[(ch + 1) * HD + j], s1);
            s2 = fmaf(psm[b][ch + 2], c_W[(ch + 2) * HD + j], s2);
            s3 = fmaf(psm[b][ch + 3], c_W[(ch + 3) * HD + j], s3);
        }
        s0 = fmaf(psm[b][436], c_W[436 * HD + j], s0);
        s1 = fmaf(psm[b][437], c_W[437 * HD + j], s1);
        hh[b][j] = sp1(((s0 + s1) + (s2 + s3)) + c_b[j]);
    }
    __syncthreads();
    if (t < HD) {
        int j = t;
        float mu = 0.0f;
        for (int bb = 0; bb < cB; ++bb) mu += hh[bb][j];
        mu *= (1.0f / cB);
        float var = 0.0f;
        for (int bb = 0; bb < cB; ++bb) { float d = hh[bb][j] - mu; var = fmaf(d, d, var); }
        var *= (1.0f / cB);
        float sc = bn_g[j] / sqrtf(var + 1e-5f);
        float bnb = bn_b[j];
        for (int bb = 0; bb < cB; ++bb)
            hh2[bb][j] = sp1((hh[bb][j] - mu) * sc + bnb);
    }
    __syncthreads();
    if (t < cB) {
        float s = o_b[0];
        for (int j = 0; j < HD; ++j) s = fmaf(hh2[t][j], o_W[j], s);
        out[t] = 1.0f / (1.0f + expf(-s));
    }
}

extern "C" void kernel_launch(void* const* d_in, const int* in_sizes, int n_in,
                              void* d_out, int out_size, void* d_ws, size_t ws_size,
                              hipStream_t stream) {
    const float* xyz    = (const float*)d_in[0];
    const int*   Z      = (const int*)d_in[1];
    const float* body23 = (const float*)d_in[2];
    const float* emb_W  = (const float*)d_in[3];
    const float* rW0    = (const float*)d_in[4];
    const float* rb0    = (const float*)d_in[5];
    const float* rW1    = (const float*)d_in[6];
    const float* rb1    = (const float*)d_in[7];
    const float* rW2    = (const float*)d_in[8];
    const float* rb2    = (const float*)d_in[9];
    const float* rW3    = (const float*)d_in[10];
    const float* rb3    = (const float*)d_in[11];
    const float* res_W  = (const float*)d_in[12];
    const float* res_b  = (const float*)d_in[13];
    const float* c_W    = (const float*)d_in[14];
    const float* c_b    = (const float*)d_in[15];
    const float* bn_g   = (const float*)d_in[16];
    const float* bn_b   = (const float*)d_in[17];
    const float* o_W    = (const float*)d_in[18];
    const float* o_b    = (const float*)d_in[19];

    float* w      = (float*)d_ws;
    float* Wpz    = w;                        // 6*150*72   = 64800
    float* Pbz    = Wpz + 64800;              // 6*72       = 432
    float* G      = Pbz + 432;                // 8192*6*72  = 3538944
    float* feats  = G + 3538944;              // 1024*438   = 448512
    float* pooled = feats + 448512;           // 16*438
    (void)in_sizes; (void)n_in; (void)out_size; (void)ws_size;

    k_wz   <<<NSP, 256, 0, stream>>>(emb_W, rW3, rb3, Wpz, Pbz);
    k_chain<<<TBL / 32, 256, 0, stream>>>(rW0, rb0, rW1, rb1, rW2, rb2, Wpz, Pbz, G);
    k_red  <<<cB * cN, 256, 0, stream>>>(xyz, Z, body23, G, res_W, res_b, feats);
    k_pool <<<cB, 448, 0, stream>>>(feats, pooled);
    k_head <<<1, 256, 0, stream>>>(pooled, c_W, c_b, bn_g, bn_b, o_W, o_b, (float*)d_out);
}

// Round 12
// 243.265 us; speedup vs baseline: 2.5477x; 1.1844x over previous
//
#include <hip/hip_runtime.h>
#include <math.h>

constexpr int cB  = 16;
constexpr int cN  = 64;
constexpr int EMB = 32;
constexpr int NL  = 3;
constexpr int CDIM = 24;
constexpr int LOD = NL * CDIM;      // 72
constexpr int NB  = 10;
constexpr int H   = 150;
constexpr int CR  = 219;
constexpr int C2  = 438;
constexpr int HD  = 128;
constexpr int NSP = 6;              // species count
constexpr int TBL = 2048;           // r-table resolution (err ~1e-4 << 7.2e-3 threshold)
constexpr float RADIUS = 2.0f;

__device__ __forceinline__ float sp5(float x) {
    return fmaxf(x, 0.0f) + 0.2f * log1pf(expf(-5.0f * fabsf(x)));
}
__device__ __forceinline__ float sp1(float x) {
    return fmaxf(x, 0.0f) + log1pf(expf(-fabsf(x)));
}

// per species z: Wpz[z][h][lo] = sum_i rW3[h][lo*32+i]*emb[z][i]; Pbz[z][lo] from rb3
__global__ void __launch_bounds__(256) k_wz(const float* __restrict__ emb_W,
                                            const float* __restrict__ rW3,
                                            const float* __restrict__ rb3,
                                            float* __restrict__ Wpz,
                                            float* __restrict__ Pbz) {
    int z = blockIdx.x;
    __shared__ float e[EMB];
    int t = threadIdx.x;
    if (t < EMB) e[t] = emb_W[z * EMB + t];
    __syncthreads();
    for (int o = t; o < H * LOD; o += 256) {
        int h = o / LOD, lo = o - h * LOD;
        const float* wr = &rW3[(size_t)h * (LOD * EMB) + lo * EMB];
        float s = 0.0f;
        #pragma unroll
        for (int i = 0; i < EMB; ++i) s = fmaf(wr[i], e[i], s);
        Wpz[(size_t)z * (H * LOD) + o] = s;
    }
    if (t < LOD) {
        float s = 0.0f;
        #pragma unroll
        for (int i = 0; i < EMB; ++i) s = fmaf(rb3[t * EMB + i], e[i], s);
        Pbz[z * LOD + t] = s;
    }
}

// Fused table chain. 8 rows/block, 1 row/thread, 256 blocks.
// Same 48-phase double-buffered schedule as the measured R11 kernel; per-block
// compute cut 4x via TBL 8192->2048.
__global__ void __launch_bounds__(256) k_chain(const float* __restrict__ rW0,
                                               const float* __restrict__ rb0,
                                               const float* __restrict__ rW1,
                                               const float* __restrict__ rb1,
                                               const float* __restrict__ rW2,
                                               const float* __restrict__ rb2,
                                               const float* __restrict__ Wpz,
                                               const float* __restrict__ Pbz,
                                               float* __restrict__ G) {
    const int row0 = blockIdx.x * 8;
    const int t = threadIdx.x;
    const int a2 = t >> 5;                   // 0..7 = local row
    const int jt = t & 31;                   // col group
    const int j0 = jt * 4;                   // b128 cols [j0, j0+4)
    const int jx = (jt < 22) ? 128 + jt : 128;   // extra col 128..149
    const int lo0 = (jt < 18) ? jt * 4 : 0;  // G-phase cols (72 = 18*4)

    __shared__ __align__(16) float bas[8][10];
    __shared__ __align__(16) float hA[8 * 152];
    __shared__ __align__(16) float bs[152];
    __shared__ __align__(16) float pz[NSP * LOD];
    __shared__ __align__(16) float S[7200];  // L: hBf[1216]+WtL[2*1520]; G: Wz[2*3600]
    float* hBf = S;
    float* WtL = S + 1216;
    float* Wz  = S;

    // ---- prologue ----
    if (t < 8) {
        float r = (float)(row0 + t) * (RADIUS / (float)(TBL - 1));
        #pragma unroll
        for (int k = 0; k < NB; ++k) {
            float d = r * 4.5f - (float)k;
            float v = 0.0f;
            if (fabsf(d) < 1.0f) { float cc = cosf(1.57079632679489662f * d); v = cc * cc; }
            bas[t][k] = v;
        }
    }
    for (int i = t; i < NSP * LOD; i += 256) pz[i] = Pbz[i];
    for (int i = t; i < 10 * 75; i += 256) {             // rW0 -> WtL[0]
        int r = i / 75, c = i - r * 75;
        *(float2*)&WtL[r * 152 + 2 * c] = *(const float2*)&rW0[r * H + 2 * c];
    }
    if (t < 152) bs[t] = (t < H) ? rb0[t] : 0.0f;
    __syncthreads();

    // ---- L0 ----
    {
        float acc[4] = {0, 0, 0, 0}; float accx = 0.0f;
        #pragma unroll
        for (int k = 0; k < NB; ++k) {
            float4 w = *(float4*)&WtL[k * 152 + j0];
            float wx = WtL[k * 152 + jx];
            float x = bas[a2][k];
            acc[0] = fmaf(x, w.x, acc[0]);
            acc[1] = fmaf(x, w.y, acc[1]);
            acc[2] = fmaf(x, w.z, acc[2]);
            acc[3] = fmaf(x, w.w, acc[3]);
            accx   = fmaf(x, wx,  accx);
        }
        hA[a2 * 152 + j0 + 0] = sp5(acc[0] + bs[j0 + 0]);
        hA[a2 * 152 + j0 + 1] = sp5(acc[1] + bs[j0 + 1]);
        hA[a2 * 152 + j0 + 2] = sp5(acc[2] + bs[j0 + 2]);
        hA[a2 * 152 + j0 + 3] = sp5(acc[3] + bs[j0 + 3]);
        if (jt < 22) hA[a2 * 152 + 128 + jt] = sp5(accx + bs[128 + jt]);
    }
    __syncthreads();

    // ---- L1 (hA->hBf), L2 (hBf->hA): 15 tiles of 10 K-rows, double-buffered ----
    for (int layer = 0; layer < 2; ++layer) {
        const float* W   = layer ? rW2 : rW1;
        const float* bb  = layer ? rb2 : rb1;
        const float* src = layer ? hBf : hA;
        float*       dst = layer ? hA  : hBf;
        for (int i = t; i < 750; i += 256) {
            int r = i / 75, c = i - r * 75;
            *(float2*)&WtL[r * 152 + 2 * c] = *(const float2*)&W[(size_t)r * H + 2 * c];
        }
        if (t < 152) bs[t] = (t < H) ? bb[t] : 0.0f;
        __syncthreads();
        float acc[4] = {0, 0, 0, 0}; float accx = 0.0f;
        int buf = 0;
        for (int tile = 0; tile < 15; ++tile) {
            if (tile < 14) {
                const float* Wn = W + (size_t)(tile + 1) * 10 * H;
                float* dw = WtL + (buf ^ 1) * 1520;
                for (int i = t; i < 750; i += 256) {
                    int r = i / 75, c = i - r * 75;
                    *(float2*)&dw[r * 152 + 2 * c] = *(const float2*)&Wn[(size_t)r * H + 2 * c];
                }
            }
            const float* Wb = WtL + buf * 1520;
            int kk = tile * 10;
            #pragma unroll
            for (int k2 = 0; k2 < 5; ++k2) {
                float4 wA = *(float4*)&Wb[(2 * k2) * 152 + j0];
                float4 wB = *(float4*)&Wb[(2 * k2 + 1) * 152 + j0];
                float wxA = Wb[(2 * k2) * 152 + jx];
                float wxB = Wb[(2 * k2 + 1) * 152 + jx];
                float2 x = *(float2*)&src[a2 * 152 + kk + 2 * k2];
                acc[0] = fmaf(x.x, wA.x, acc[0]);
                acc[1] = fmaf(x.x, wA.y, acc[1]);
                acc[2] = fmaf(x.x, wA.z, acc[2]);
                acc[3] = fmaf(x.x, wA.w, acc[3]);
                accx   = fmaf(x.x, wxA,  accx);
                acc[0] = fmaf(x.y, wB.x, acc[0]);
                acc[1] = fmaf(x.y, wB.y, acc[1]);
                acc[2] = fmaf(x.y, wB.z, acc[2]);
                acc[3] = fmaf(x.y, wB.w, acc[3]);
                accx   = fmaf(x.y, wxB,  accx);
            }
            __syncthreads();
            buf ^= 1;
        }
        dst[a2 * 152 + j0 + 0] = sp5(acc[0] + bs[j0 + 0]);
        dst[a2 * 152 + j0 + 1] = sp5(acc[1] + bs[j0 + 1]);
        dst[a2 * 152 + j0 + 2] = sp5(acc[2] + bs[j0 + 2]);
        dst[a2 * 152 + j0 + 3] = sp5(acc[3] + bs[j0 + 3]);
        if (jt < 22) dst[a2 * 152 + 128 + jt] = sp5(accx + bs[128 + jt]);
        __syncthreads();
    }

    // ---- G: 18 segments (6 z x 3 chunks of 50 K-rows), double-buffered ----
    {
        float ac[4] = {0, 0, 0, 0};
        for (int i = t; i < 1800; i += 256) {            // seg 0: z=0, rows 0..49
            int r = i / 36, c = i - r * 36;
            *(float2*)&Wz[r * 72 + 2 * c] = *(const float2*)&Wpz[(size_t)r * 72 + 2 * c];
        }
        __syncthreads();
        int gbuf = 0;
        for (int s = 0; s < 18; ++s) {
            if (s < 17) {
                int s2 = s + 1, z2 = s2 / 3, base2 = (s2 - z2 * 3) * 50;
                const float* Wn = Wpz + (size_t)z2 * (H * LOD) + (size_t)base2 * 72;
                float* dw = Wz + (gbuf ^ 1) * 3600;
                for (int i = t; i < 1800; i += 256) {
                    int r = i / 36, c = i - r * 36;
                    *(float2*)&dw[r * 72 + 2 * c] = *(const float2*)&Wn[(size_t)r * 72 + 2 * c];
                }
            }
            int z = s / 3, chunk = s - z * 3, base = chunk * 50;
            const float* Wb = Wz + gbuf * 3600;
            #pragma unroll 5
            for (int k2 = 0; k2 < 25; ++k2) {
                float4 wA = *(float4*)&Wb[(2 * k2) * 72 + lo0];
                float4 wB = *(float4*)&Wb[(2 * k2 + 1) * 72 + lo0];
                float2 x = *(float2*)&hA[a2 * 152 + base + 2 * k2];
                ac[0] = fmaf(x.x, wA.x, ac[0]);
                ac[1] = fmaf(x.x, wA.y, ac[1]);
                ac[2] = fmaf(x.x, wA.z, ac[2]);
                ac[3] = fmaf(x.x, wA.w, ac[3]);
                ac[0] = fmaf(x.y, wB.x, ac[0]);
                ac[1] = fmaf(x.y, wB.y, ac[1]);
                ac[2] = fmaf(x.y, wB.z, ac[2]);
                ac[3] = fmaf(x.y, wB.w, ac[3]);
            }
            if (chunk == 2) {
                if (jt < 18) {
                    int row = row0 + a2;
                    float4 o;
                    o.x = ac[0] + pz[z * LOD + lo0 + 0];
                    o.y = ac[1] + pz[z * LOD + lo0 + 1];
                    o.z = ac[2] + pz[z * LOD + lo0 + 2];
                    o.w = ac[3] + pz[z * LOD + lo0 + 3];
                    *(float4*)&G[((size_t)row * NSP + z) * LOD + lo0] = o;
                }
                ac[0] = 0.0f; ac[1] = 0.0f; ac[2] = 0.0f; ac[3] = 0.0f;
            }
            __syncthreads();
            gbuf ^= 1;
        }
    }
}

// fused per (b,a): pair mask + G-lerp -> ps[n][72] in LDS; Y-reduce; body23 concat; residual
__global__ void __launch_bounds__(256) k_red(const float* __restrict__ xyz,
                                             const int* __restrict__ Z,
                                             const float* __restrict__ body23,
                                             const float* __restrict__ G,
                                             const float* __restrict__ res_W,
                                             const float* __restrict__ res_b,
                                             float* __restrict__ feats) {
    int ba = blockIdx.x;
    int b = ba >> 6, a = ba & 63;
    int t = threadIdx.x;
    __shared__ float ym[64][12];
    __shared__ float ps[64][76];
    __shared__ float xr[CR];
    __shared__ int t0s[64];
    __shared__ float wls[64];
    __shared__ int zs[64];
    __shared__ int msks[64];
    if (t < 64) {
        int n = t;
        float ax = xyz[((size_t)b * cN + a) * 3 + 0];
        float ay = xyz[((size_t)b * cN + a) * 3 + 1];
        float az = xyz[((size_t)b * cN + a) * 3 + 2];
        float d0 = ax - xyz[((size_t)b * cN + n) * 3 + 0];
        float d1 = ay - xyz[((size_t)b * cN + n) * 3 + 1];
        float d2 = az - xyz[((size_t)b * cN + n) * 3 + 2];
        float s = d0 * d0 + d1 * d1 + d2 * d2;
        float r = sqrtf(s + 1e-12f);
        msks[n] = (r < RADIUS) && (r > 1e-6f);
        float u = r * ((float)(TBL - 1) / RADIUS);
        int t0 = (int)u;
        if (t0 > TBL - 2) t0 = TBL - 2;
        t0s[n] = t0;
        wls[n] = u - (float)t0;
        zs[n] = Z[b * cN + n];
        float inv = 1.0f / r;
        float x = d0 * inv, y = d1 * inv, z = d2 * inv;
        ym[n][0] = 0.28209479177387814f;
        ym[n][1] = 0.4886025119029199f * y;
        ym[n][2] = 0.4886025119029199f * z;
        ym[n][3] = 0.4886025119029199f * x;
        ym[n][4] = 1.0925484305920792f * x * y;
        ym[n][5] = 1.0925484305920792f * y * z;
        ym[n][6] = 0.31539156525252005f * (3.0f * z * z - 1.0f);
        ym[n][7] = 1.0925484305920792f * x * z;
        ym[n][8] = 0.5462742152960396f * (x * x - y * y);
    }
    __syncthreads();
    for (int i = t; i < 64 * LOD; i += 256) {
        int n = i / LOD, lo = i - n * LOD;
        float v = 0.0f;
        if (msks[n]) {
            const float* g = &G[((size_t)t0s[n] * NSP + zs[n]) * LOD + lo];
            float g0 = g[0], g1 = g[NSP * LOD];
            v = g0 + wls[n] * (g1 - g0);
        }
        ps[n][lo] = v;
    }
    __syncthreads();
    if (t < 216) {
        int lo, yi;
        if (t < 24) { lo = t; yi = 0; }
        else if (t < 96) { int q = t - 24; int o = q / 3; lo = 24 + o; yi = 1 + (q - o * 3); }
        else { int q = t - 96; int o = q / 5; lo = 48 + o; yi = 4 + (q - o * 5); }
        float acc = 0.0f;
        #pragma unroll 4
        for (int n = 0; n < cN; ++n)
            acc = fmaf(ps[n][lo], ym[n][yi], acc);
        xr[3 + t] = acc * 0.125f;
    } else if (t < 219) {
        xr[t - 216] = body23[(size_t)ba * 3 + (t - 216)];
    }
    __syncthreads();
    if (t < CR) {
        float xv = xr[t];
        feats[(size_t)ba * C2 + t] = xv;
        float racc = res_b[t];
        for (int k = 0; k < CR; ++k)
            racc = fmaf(xr[k], res_W[k * CR + t], racc);
        feats[(size_t)ba * C2 + CR + t] = xv + sp5(racc);
    }
}

__global__ void __launch_bounds__(448) k_pool(const float* __restrict__ feats,
                                              float* __restrict__ pooled) {
    int b = blockIdx.x;
    int t = threadIdx.x;
    if (t < C2) {
        float s = 0.0f;
        for (int a = 0; a < cN; ++a) {
            float v = feats[(size_t)(b * cN + a) * C2 + t];
            s = fmaf(v, v, s);
        }
        pooled[b * C2 + t] = sqrtf(s);
    }
}

__global__ void __launch_bounds__(256) k_head(const float* __restrict__ pooled,
                                              const float* __restrict__ c_W,
                                              const float* __restrict__ c_b,
                                              const float* __restrict__ bn_g,
                                              const float* __restrict__ bn_b,
                                              const float* __restrict__ o_W,
                                              const float* __restrict__ o_b,
                                              float* __restrict__ out) {
    __shared__ float psm[cB][C2];
    __shared__ float hh[cB][HD];
    __shared__ float hh2[cB][HD];
    int t = threadIdx.x;
    for (int i = t; i < cB * C2; i += 256) psm[(unsigned)i / C2][(unsigned)i % C2] = pooled[i];
    __syncthreads();
    for (int o = t; o < cB * HD; o += 256) {
        int b = o >> 7, j = o & 127;
        float s0 = 0, s1 = 0, s2 = 0, s3 = 0;
        for (int ch = 0; ch < 436; ch += 4) {
            s0 = fmaf(psm[b][ch + 0], c_W[(ch + 0) * HD + j], s0);
            s1 = fmaf(psm[b][ch + 1], c_W[(ch + 1) * HD + j], s1);
            s2 = fmaf(psm[b][ch + 2], c_W[(ch + 2) * HD + j], s2);
            s3 = fmaf(psm[b][ch + 3], c_W[(ch + 3) * HD + j], s3);
        }
        s0 = fmaf(psm[b][436], c_W[436 * HD + j], s0);
        s1 = fmaf(psm[b][437], c_W[437 * HD + j], s1);
        hh[b][j] = sp1(((s0 + s1) + (s2 + s3)) + c_b[j]);
    }
    __syncthreads();
    if (t < HD) {
        int j = t;
        float mu = 0.0f;
        for (int bb = 0; bb < cB; ++bb) mu += hh[bb][j];
        mu *= (1.0f / cB);
        float var = 0.0f;
        for (int bb = 0; bb < cB; ++bb) { float d = hh[bb][j] - mu; var = fmaf(d, d, var); }
        var *= (1.0f / cB);
        float sc = bn_g[j] / sqrtf(var + 1e-5f);
        float bnb = bn_b[j];
        for (int bb = 0; bb < cB; ++bb)
            hh2[bb][j] = sp1((hh[bb][j] - mu) * sc + bnb);
    }
    __syncthreads();
    if (t < cB) {
        float s = o_b[0];
        for (int j = 0; j < HD; ++j) s = fmaf(hh2[t][j], o_W[j], s);
        out[t] = 1.0f / (1.0f + expf(-s));
    }
}

extern "C" void kernel_launch(void* const* d_in, const int* in_sizes, int n_in,
                              void* d_out, int out_size, void* d_ws, size_t ws_size,
                              hipStream_t stream) {
    const float* xyz    = (const float*)d_in[0];
    const int*   Z      = (const int*)d_in[1];
    const float* body23 = (const float*)d_in[2];
    const float* emb_W  = (const float*)d_in[3];
    const float* rW0    = (const float*)d_in[4];
    const float* rb0    = (const float*)d_in[5];
    const float* rW1    = (const float*)d_in[6];
    const float* rb1    = (const float*)d_in[7];
    const float* rW2    = (const float*)d_in[8];
    const float* rb2    = (const float*)d_in[9];
    const float* rW3    = (const float*)d_in[10];
    const float* rb3    = (const float*)d_in[11];
    const float* res_W  = (const float*)d_in[12];
    const float* res_b  = (const float*)d_in[13];
    const float* c_W    = (const float*)d_in[14];
    const float* c_b    = (const float*)d_in[15];
    const float* bn_g   = (const float*)d_in[16];
    const float* bn_b   = (const float*)d_in[17];
    const float* o_W    = (const float*)d_in[18];
    const float* o_b    = (const float*)d_in[19];

    float* w      = (float*)d_ws;
    float* Wpz    = w;                        // 6*150*72   = 64800
    float* Pbz    = Wpz + 64800;              // 6*72       = 432
    float* G      = Pbz + 432;                // 2048*6*72  = 884736
    float* feats  = G + 884736;               // 1024*438   = 448512
    float* pooled = feats + 448512;           // 16*438
    (void)in_sizes; (void)n_in; (void)out_size; (void)ws_size;

    k_wz   <<<NSP, 256, 0, stream>>>(emb_W, rW3, rb3, Wpz, Pbz);
    k_chain<<<TBL / 8, 256, 0, stream>>>(rW0, rb0, rW1, rb1, rW2, rb2, Wpz, Pbz, G);
    k_red  <<<cB * cN, 256, 0, stream>>>(xyz, Z, body23, G, res_W, res_b, feats);
    k_pool <<<cB, 448, 0, stream>>>(feats, pooled);
    k_head <<<1, 256, 0, stream>>>(pooled, c_W, c_b, bn_g, bn_b, o_W, o_b, (float*)d_out);
}

// Round 13
// 202.867 us; speedup vs baseline: 3.0551x; 1.1991x over previous
//
#include <hip/hip_runtime.h>
#include <math.h>

constexpr int cB  = 16;
constexpr int cN  = 64;
constexpr int EMB = 32;
constexpr int NL  = 3;
constexpr int CDIM = 24;
constexpr int LOD = NL * CDIM;      // 72
constexpr int NB  = 10;
constexpr int H   = 150;
constexpr int CR  = 219;
constexpr int C2  = 438;
constexpr int HD  = 128;
constexpr int NSP = 6;              // species count
constexpr int TBL = 2048;           // r-table resolution (err ~1e-4 << 7.2e-3 threshold)
constexpr float RADIUS = 2.0f;

__device__ __forceinline__ float sp5(float x) {
    return fmaxf(x, 0.0f) + 0.2f * log1pf(expf(-5.0f * fabsf(x)));
}
__device__ __forceinline__ float sp1(float x) {
    return fmaxf(x, 0.0f) + log1pf(expf(-fabsf(x)));
}

// per (z, h-block): Wpz[z][h][lo] = sum_i rW3[h][lo*32+i]*emb[z][i]; Pbz from rb3
__global__ void __launch_bounds__(256) k_wz(const float* __restrict__ emb_W,
                                            const float* __restrict__ rW3,
                                            const float* __restrict__ rb3,
                                            float* __restrict__ Wpz,
                                            float* __restrict__ Pbz) {
    int z = blockIdx.x, hb = blockIdx.y;     // 6 x 15 blocks, 10 h-rows each
    __shared__ float e[EMB];
    int t = threadIdx.x;
    if (t < EMB) e[t] = emb_W[z * EMB + t];
    __syncthreads();
    for (int o = t; o < 10 * LOD; o += 256) {
        int h = hb * 10 + o / LOD, lo = o - (o / LOD) * LOD;
        const float* wr = &rW3[(size_t)h * (LOD * EMB) + lo * EMB];
        float s = 0.0f;
        #pragma unroll
        for (int i = 0; i < EMB; ++i) s = fmaf(wr[i], e[i], s);
        Wpz[(size_t)z * (H * LOD) + (size_t)h * LOD + lo] = s;
    }
    if (hb == 0 && t < LOD) {
        float s = 0.0f;
        #pragma unroll
        for (int i = 0; i < EMB; ++i) s = fmaf(rb3[t * EMB + i], e[i], s);
        Pbz[z * LOD + t] = s;
    }
}

// Fused table chain. 2 rows/block, 1024 blocks -> 4 blocks/CU; the 48-phase
// double-buffered schedule's latencies now overlap across resident blocks.
// Thread map: a2 = t>>7 (row), jt = t&127 (col); scalar W-reads (consecutive
// banks, conflict-free), broadcast x-reads.
__global__ void __launch_bounds__(256) k_chain(const float* __restrict__ rW0,
                                               const float* __restrict__ rb0,
                                               const float* __restrict__ rW1,
                                               const float* __restrict__ rb1,
                                               const float* __restrict__ rW2,
                                               const float* __restrict__ rb2,
                                               const float* __restrict__ Wpz,
                                               const float* __restrict__ Pbz,
                                               float* __restrict__ G) {
    const int row0 = blockIdx.x * 2;
    const int t = threadIdx.x;
    const int a2 = t >> 7;                   // 0..1 local row
    const int jt = t & 127;                  // col
    const int jx = (jt < 22) ? 128 + jt : 128;   // extra col 128..149 (guarded)

    __shared__ __align__(16) float bas[2][10];
    __shared__ __align__(16) float hA[2 * 152];
    __shared__ __align__(16) float bs[152];
    __shared__ __align__(16) float pz[NSP * LOD];
    __shared__ __align__(16) float S[7200];  // L: hBf[304]+WtL[2*1520]; G: Wz[2*3600]
    float* hBf = S;
    float* WtL = S + 304;
    float* Wz  = S;

    // ---- prologue ----
    if (t < 2) {
        float r = (float)(row0 + t) * (RADIUS / (float)(TBL - 1));
        #pragma unroll
        for (int k = 0; k < NB; ++k) {
            float d = r * 4.5f - (float)k;
            float v = 0.0f;
            if (fabsf(d) < 1.0f) { float cc = cosf(1.57079632679489662f * d); v = cc * cc; }
            bas[t][k] = v;
        }
    }
    for (int i = t; i < NSP * LOD; i += 256) pz[i] = Pbz[i];
    for (int i = t; i < 10 * 75; i += 256) {             // rW0 -> WtL (first buffer)
        int r = i / 75, c = i - r * 75;
        *(float2*)&WtL[r * 152 + 2 * c] = *(const float2*)&rW0[r * H + 2 * c];
    }
    if (t < 152) bs[t] = (t < H) ? rb0[t] : 0.0f;
    __syncthreads();

    // ---- L0 ----
    {
        float acc = 0.0f, accx = 0.0f;
        #pragma unroll
        for (int k = 0; k < NB; ++k) {
            float x = bas[a2][k];
            acc  = fmaf(x, WtL[k * 152 + jt], acc);
            accx = fmaf(x, WtL[k * 152 + jx], accx);
        }
        hA[a2 * 152 + jt] = sp5(acc + bs[jt]);
        if (jt < 22) hA[a2 * 152 + 128 + jt] = sp5(accx + bs[128 + jt]);
    }
    __syncthreads();

    // ---- L1 (hA->hBf), L2 (hBf->hA): 15 tiles of 10 K-rows, double-buffered ----
    for (int layer = 0; layer < 2; ++layer) {
        const float* W   = layer ? rW2 : rW1;
        const float* bb  = layer ? rb2 : rb1;
        const float* src = layer ? hBf : hA;
        float*       dst = layer ? hA  : hBf;
        for (int i = t; i < 750; i += 256) {
            int r = i / 75, c = i - r * 75;
            *(float2*)&WtL[r * 152 + 2 * c] = *(const float2*)&W[(size_t)r * H + 2 * c];
        }
        if (t < 152) bs[t] = (t < H) ? bb[t] : 0.0f;
        __syncthreads();
        float acc = 0.0f, accx = 0.0f;
        int buf = 0;
        for (int tile = 0; tile < 15; ++tile) {
            if (tile < 14) {
                const float* Wn = W + (size_t)(tile + 1) * 10 * H;
                float* dw = WtL + (buf ^ 1) * 1520;
                for (int i = t; i < 750; i += 256) {
                    int r = i / 75, c = i - r * 75;
                    *(float2*)&dw[r * 152 + 2 * c] = *(const float2*)&Wn[(size_t)r * H + 2 * c];
                }
            }
            const float* Wb = WtL + buf * 1520;
            int kk = tile * 10;
            #pragma unroll
            for (int k2 = 0; k2 < 5; ++k2) {
                float w0 = Wb[(2 * k2) * 152 + jt];
                float w1 = Wb[(2 * k2 + 1) * 152 + jt];
                float w0x = Wb[(2 * k2) * 152 + jx];
                float w1x = Wb[(2 * k2 + 1) * 152 + jx];
                float2 x = *(float2*)&src[a2 * 152 + kk + 2 * k2];
                acc  = fmaf(x.x, w0, acc);
                acc  = fmaf(x.y, w1, acc);
                accx = fmaf(x.x, w0x, accx);
                accx = fmaf(x.y, w1x, accx);
            }
            __syncthreads();
            buf ^= 1;
        }
        dst[a2 * 152 + jt] = sp5(acc + bs[jt]);
        if (jt < 22) dst[a2 * 152 + 128 + jt] = sp5(accx + bs[128 + jt]);
        __syncthreads();
    }

    // ---- G: 18 segments (6 z x 3 chunks of 50 K-rows), double-buffered ----
    {
        float ac = 0.0f;
        for (int i = t; i < 1800; i += 256) {            // seg 0: z=0, rows 0..49
            int r = i / 36, c = i - r * 36;
            *(float2*)&Wz[r * 72 + 2 * c] = *(const float2*)&Wpz[(size_t)r * 72 + 2 * c];
        }
        __syncthreads();
        int gbuf = 0;
        for (int s = 0; s < 18; ++s) {
            if (s < 17) {
                int s2 = s + 1, z2 = s2 / 3, base2 = (s2 - z2 * 3) * 50;
                const float* Wn = Wpz + (size_t)z2 * (H * LOD) + (size_t)base2 * 72;
                float* dw = Wz + (gbuf ^ 1) * 3600;
                for (int i = t; i < 1800; i += 256) {
                    int r = i / 36, c = i - r * 36;
                    *(float2*)&dw[r * 72 + 2 * c] = *(const float2*)&Wn[(size_t)r * 72 + 2 * c];
                }
            }
            int z = s / 3, chunk = s - z * 3, base = chunk * 50;
            const float* Wb = Wz + gbuf * 3600;
            if (jt < LOD) {
                #pragma unroll 5
                for (int k2 = 0; k2 < 25; ++k2) {
                    float2 x = *(float2*)&hA[a2 * 152 + base + 2 * k2];
                    ac = fmaf(x.x, Wb[(2 * k2) * 72 + jt], ac);
                    ac = fmaf(x.y, Wb[(2 * k2 + 1) * 72 + jt], ac);
                }
                if (chunk == 2) {
                    G[((size_t)(row0 + a2) * NSP + z) * LOD + jt] = ac + pz[z * LOD + jt];
                    ac = 0.0f;
                }
            }
            __syncthreads();
            gbuf ^= 1;
        }
    }
}

// fused per (b,a): pair mask + G-lerp -> ps[n][72] in LDS; Y-reduce; body23 concat; residual
__global__ void __launch_bounds__(256) k_red(const float* __restrict__ xyz,
                                             const int* __restrict__ Z,
                                             const float* __restrict__ body23,
                                             const float* __restrict__ G,
                                             const float* __restrict__ res_W,
                                             const float* __restrict__ res_b,
                                             float* __restrict__ feats) {
    int ba = blockIdx.x;
    int b = ba >> 6, a = ba & 63;
    int t = threadIdx.x;
    __shared__ float ym[64][12];
    __shared__ float ps[64][76];
    __shared__ float xr[CR];
    __shared__ int t0s[64];
    __shared__ float wls[64];
    __shared__ int zs[64];
    __shared__ int msks[64];
    if (t < 64) {
        int n = t;
        float ax = xyz[((size_t)b * cN + a) * 3 + 0];
        float ay = xyz[((size_t)b * cN + a) * 3 + 1];
        float az = xyz[((size_t)b * cN + a) * 3 + 2];
        float d0 = ax - xyz[((size_t)b * cN + n) * 3 + 0];
        float d1 = ay - xyz[((size_t)b * cN + n) * 3 + 1];
        float d2 = az - xyz[((size_t)b * cN + n) * 3 + 2];
        float s = d0 * d0 + d1 * d1 + d2 * d2;
        float r = sqrtf(s + 1e-12f);
        msks[n] = (r < RADIUS) && (r > 1e-6f);
        float u = r * ((float)(TBL - 1) / RADIUS);
        int t0 = (int)u;
        if (t0 > TBL - 2) t0 = TBL - 2;
        t0s[n] = t0;
        wls[n] = u - (float)t0;
        zs[n] = Z[b * cN + n];
        float inv = 1.0f / r;
        float x = d0 * inv, y = d1 * inv, z = d2 * inv;
        ym[n][0] = 0.28209479177387814f;
        ym[n][1] = 0.4886025119029199f * y;
        ym[n][2] = 0.4886025119029199f * z;
        ym[n][3] = 0.4886025119029199f * x;
        ym[n][4] = 1.0925484305920792f * x * y;
        ym[n][5] = 1.0925484305920792f * y * z;
        ym[n][6] = 0.31539156525252005f * (3.0f * z * z - 1.0f);
        ym[n][7] = 1.0925484305920792f * x * z;
        ym[n][8] = 0.5462742152960396f * (x * x - y * y);
    }
    __syncthreads();
    for (int i = t; i < 64 * LOD; i += 256) {
        int n = i / LOD, lo = i - n * LOD;
        float v = 0.0f;
        if (msks[n]) {
            const float* g = &G[((size_t)t0s[n] * NSP + zs[n]) * LOD + lo];
            float g0 = g[0], g1 = g[NSP * LOD];
            v = g0 + wls[n] * (g1 - g0);
        }
        ps[n][lo] = v;
    }
    __syncthreads();
    if (t < 216) {
        int lo, yi;
        if (t < 24) { lo = t; yi = 0; }
        else if (t < 96) { int q = t - 24; int o = q / 3; lo = 24 + o; yi = 1 + (q - o * 3); }
        else { int q = t - 96; int o = q / 5; lo = 48 + o; yi = 4 + (q - o * 5); }
        float acc = 0.0f;
        #pragma unroll 4
        for (int n = 0; n < cN; ++n)
            acc = fmaf(ps[n][lo], ym[n][yi], acc);
        xr[3 + t] = acc * 0.125f;
    } else if (t < 219) {
        xr[t - 216] = body23[(size_t)ba * 3 + (t - 216)];
    }
    __syncthreads();
    if (t < CR) {
        float xv = xr[t];
        feats[(size_t)ba * C2 + t] = xv;
        float racc = res_b[t];
        for (int k = 0; k < CR; ++k)
            racc = fmaf(xr[k], res_W[k * CR + t], racc);
        feats[(size_t)ba * C2 + CR + t] = xv + sp5(racc);
    }
}

__global__ void __launch_bounds__(448) k_pool(const float* __restrict__ feats,
                                              float* __restrict__ pooled) {
    int b = blockIdx.x;
    int t = threadIdx.x;
    if (t < C2) {
        float s = 0.0f;
        for (int a = 0; a < cN; ++a) {
            float v = feats[(size_t)(b * cN + a) * C2 + t];
            s = fmaf(v, v, s);
        }
        pooled[b * C2 + t] = sqrtf(s);
    }
}

__global__ void __launch_bounds__(256) k_head(const float* __restrict__ pooled,
                                              const float* __restrict__ c_W,
                                              const float* __restrict__ c_b,
                                              const float* __restrict__ bn_g,
                                              const float* __restrict__ bn_b,
                                              const float* __restrict__ o_W,
                                              const float* __restrict__ o_b,
                                              float* __restrict__ out) {
    __shared__ float psm[cB][C2];
    __shared__ float hh[cB][HD];
    __shared__ float hh2[cB][HD];
    int t = threadIdx.x;
    for (int i = t; i < cB * C2; i += 256) psm[(unsigned)i / C2][(unsigned)i % C2] = pooled[i];
    __syncthreads();
    for (int o = t; o < cB * HD; o += 256) {
        int b = o >> 7, j = o & 127;
        float s0 = 0, s1 = 0, s2 = 0, s3 = 0;
        for (int ch = 0; ch < 436; ch += 4) {
            s0 = fmaf(psm[b][ch + 0], c_W[(ch + 0) * HD + j], s0);
            s1 = fmaf(psm[b][ch + 1], c_W[(ch + 1) * HD + j], s1);
            s2 = fmaf(psm[b][ch + 2], c_W[(ch + 2) * HD + j], s2);
            s3 = fmaf(psm[b][ch + 3], c_W[(ch + 3) * HD + j], s3);
        }
        s0 = fmaf(psm[b][436], c_W[436 * HD + j], s0);
        s1 = fmaf(psm[b][437], c_W[437 * HD + j], s1);
        hh[b][j] = sp1(((s0 + s1) + (s2 + s3)) + c_b[j]);
    }
    __syncthreads();
    if (t < HD) {
        int j = t;
        float mu = 0.0f;
        for (int bb = 0; bb < cB; ++bb) mu += hh[bb][j];
        mu *= (1.0f / cB);
        float var = 0.0f;
        for (int bb = 0; bb < cB; ++bb) { float d = hh[bb][j] - mu; var = fmaf(d, d, var); }
        var *= (1.0f / cB);
        float sc = bn_g[j] / sqrtf(var + 1e-5f);
        float bnb = bn_b[j];
        for (int bb = 0; bb < cB; ++bb)
            hh2[bb][j] = sp1((hh[bb][j] - mu) * sc + bnb);
    }
    __syncthreads();
    if (t < cB) {
        float s = o_b[0];
        for (int j = 0; j < HD; ++j) s = fmaf(hh2[t][j], o_W[j], s);
        out[t] = 1.0f / (1.0f + expf(-s));
    }
}

extern "C" void kernel_launch(void* const* d_in, const int* in_sizes, int n_in,
                              void* d_out, int out_size, void* d_ws, size_t ws_size,
                              hipStream_t stream) {
    const float* xyz    = (const float*)d_in[0];
    const int*   Z      = (const int*)d_in[1];
    const float* body23 = (const float*)d_in[2];
    const float* emb_W  = (const float*)d_in[3];
    const float* rW0    = (const float*)d_in[4];
    const float* rb0    = (const float*)d_in[5];
    const float* rW1    = (const float*)d_in[6];
    const float* rb1    = (const float*)d_in[7];
    const float* rW2    = (const float*)d_in[8];
    const float* rb2    = (const float*)d_in[9];
    const float* rW3    = (const float*)d_in[10];
    const float* rb3    = (const float*)d_in[11];
    const float* res_W  = (const float*)d_in[12];
    const float* res_b  = (const float*)d_in[13];
    const float* c_W    = (const float*)d_in[14];
    const float* c_b    = (const float*)d_in[15];
    const float* bn_g   = (const float*)d_in[16];
    const float* bn_b   = (const float*)d_in[17];
    const float* o_W    = (const float*)d_in[18];
    const float* o_b    = (const float*)d_in[19];

    float* w      = (float*)d_ws;
    float* Wpz    = w;                        // 6*150*72   = 64800
    float* Pbz    = Wpz + 64800;              // 6*72       = 432
    float* G      = Pbz + 432;                // 2048*6*72  = 884736
    float* feats  = G + 884736;               // 1024*438   = 448512
    float* pooled = feats + 448512;           // 16*438
    (void)in_sizes; (void)n_in; (void)out_size; (void)ws_size;

    k_wz   <<<dim3(NSP, 15), 256, 0, stream>>>(emb_W, rW3, rb3, Wpz, Pbz);
    k_chain<<<TBL / 2, 256, 0, stream>>>(rW0, rb0, rW1, rb1, rW2, rb2, Wpz, Pbz, G);
    k_red  <<<cB * cN, 256, 0, stream>>>(xyz, Z, body23, G, res_W, res_b, feats);
    k_pool <<<cB, 448, 0, stream>>>(feats, pooled);
    k_head <<<1, 256, 0, stream>>>(pooled, c_W, c_b, bn_g, bn_b, o_W, o_b, (float*)d_out);
}

// Round 14
// 177.882 us; speedup vs baseline: 3.4842x; 1.1405x over previous
//
#include <hip/hip_runtime.h>
#include <math.h>

constexpr int cB  = 16;
constexpr int cN  = 64;
constexpr int EMB = 32;
constexpr int NL  = 3;
constexpr int CDIM = 24;
constexpr int LOD = NL * CDIM;      // 72
constexpr int NB  = 10;
constexpr int H   = 150;
constexpr int CR  = 219;
constexpr int C2  = 438;
constexpr int HD  = 128;
constexpr int NSP = 6;              // species count
constexpr int GC  = NSP * LOD;      // 432 G-columns
constexpr int GCP = 512;            // padded W2 row
constexpr int TBL = 2048;           // r-table resolution (err ~1e-4 << 7.2e-3 threshold)
constexpr float RADIUS = 2.0f;

__device__ __forceinline__ float sp5(float x) {
    return fmaxf(x, 0.0f) + 0.2f * log1pf(expf(-5.0f * fabsf(x)));
}
__device__ __forceinline__ float sp1(float x) {
    return fmaxf(x, 0.0f) + log1pf(expf(-fabsf(x)));
}

// pad rW0/rW1/rW2 into [.][152] row-padded copies (pad cols = 0)
__global__ void __launch_bounds__(256) k_pad(const float* __restrict__ rW0,
                                             const float* __restrict__ rW1,
                                             const float* __restrict__ rW2,
                                             float* __restrict__ rW0p,
                                             float* __restrict__ rW1p,
                                             float* __restrict__ rW2p) {
    int total = NB * 152 + 2 * H * 152;      // 1520 + 45600
    for (int i = blockIdx.x * 256 + threadIdx.x; i < total; i += gridDim.x * 256) {
        if (i < NB * 152) {
            int r = i / 152, c = i - r * 152;
            rW0p[i] = (c < H) ? rW0[r * H + c] : 0.0f;
        } else if (i < NB * 152 + H * 152) {
            int j = i - NB * 152; int r = j / 152, c = j - r * 152;
            rW1p[j] = (c < H) ? rW1[r * H + c] : 0.0f;
        } else {
            int j = i - NB * 152 - H * 152; int r = j / 152, c = j - r * 152;
            rW2p[j] = (c < H) ? rW2[r * H + c] : 0.0f;
        }
    }
}

// W2[k][z*72+lo] = sum_i rW3[k][lo*32+i]*emb[z][i]  (z-interleaved, 512-padded);
// Pbz flat [z*72+lo] from rb3.
__global__ void __launch_bounds__(256) k_wz(const float* __restrict__ emb_W,
                                            const float* __restrict__ rW3,
                                            const float* __restrict__ rb3,
                                            float* __restrict__ W2,
                                            float* __restrict__ Pbz) {
    int z = blockIdx.x, hb = blockIdx.y;     // 6 x 15 blocks, 10 k-rows each
    __shared__ float e[EMB];
    int t = threadIdx.x;
    if (t < EMB) e[t] = emb_W[z * EMB + t];
    __syncthreads();
    for (int o = t; o < 10 * LOD; o += 256) {
        int k = hb * 10 + o / LOD, lo = o % LOD;
        const float* wr = &rW3[(size_t)k * (LOD * EMB) + lo * EMB];
        float s = 0.0f;
        #pragma unroll
        for (int i = 0; i < EMB; ++i) s = fmaf(wr[i], e[i], s);
        W2[(size_t)k * GCP + z * LOD + lo] = s;
    }
    if (z == 0) {  // zero the pad cols 432..511
        for (int o = t; o < 10 * (GCP - GC); o += 256) {
            int k = hb * 10 + o / (GCP - GC), c = GC + o % (GCP - GC);
            W2[(size_t)k * GCP + c] = 0.0f;
        }
    }
    if (hb == 0 && t < LOD) {
        float s = 0.0f;
        #pragma unroll
        for (int i = 0; i < EMB; ++i) s = fmaf(rb3[t * EMB + i], e[i], s);
        Pbz[z * LOD + t] = s;
    }
}

// Fused table chain, NO weight staging: weights stream from L1/L2 via coalesced
// float4 loads (all blocks read the same ~470KB -> L2-resident, waves phase-locked
// by the 5 per-layer barriers so L1 absorbs redundancy). LDS holds only activations.
// 512 blocks x 128 thr x 4 rows; thread = (row a2 = t>>5, colgroup jt = t&31).
__global__ void __launch_bounds__(128) k_chain(const float* __restrict__ rW0p,
                                               const float* __restrict__ rb0,
                                               const float* __restrict__ rW1p,
                                               const float* __restrict__ rb1,
                                               const float* __restrict__ rW2p,
                                               const float* __restrict__ rb2,
                                               const float* __restrict__ W2,
                                               const float* __restrict__ Pbz,
                                               float* __restrict__ G) {
    const int row0 = blockIdx.x * 4;
    const int t = threadIdx.x;
    const int a2 = t >> 5;                   // 0..3 local row
    const int jt = t & 31;                   // col group
    const int j0 = 4 * jt;                   // f4 cols [j0, j0+4)
    const bool hasx = (jt < 22);
    const int jx = hasx ? 128 + jt : 128;    // extra col (idle lanes read col 128, discard)

    __shared__ __align__(16) float bas[4][10];
    __shared__ __align__(16) float hA[4 * 152];
    __shared__ __align__(16) float hB[4 * 152];

    if (t < 4) {
        float r = (float)(row0 + t) * (RADIUS / (float)(TBL - 1));
        #pragma unroll
        for (int k = 0; k < NB; ++k) {
            float d = r * 4.5f - (float)k;
            float v = 0.0f;
            if (fabsf(d) < 1.0f) { float cc = cosf(1.57079632679489662f * d); v = cc * cc; }
            bas[t][k] = v;
        }
    }
    __syncthreads();

    // ---- L0: K=10 ----
    {
        float a0 = 0, a1 = 0, a2v = 0, a3 = 0, ax = 0;
        #pragma unroll
        for (int k = 0; k < NB; ++k) {
            float x = bas[a2][k];
            float4 w = *(const float4*)&rW0p[k * 152 + j0];
            float wx = rW0p[k * 152 + jx];
            a0 = fmaf(x, w.x, a0); a1 = fmaf(x, w.y, a1);
            a2v = fmaf(x, w.z, a2v); a3 = fmaf(x, w.w, a3);
            ax = fmaf(x, wx, ax);
        }
        float4 b4 = *(const float4*)&rb0[j0];
        float4 o; o.x = sp5(a0 + b4.x); o.y = sp5(a1 + b4.y);
        o.z = sp5(a2v + b4.z); o.w = sp5(a3 + b4.w);
        *(float4*)&hA[a2 * 152 + j0] = o;
        if (hasx) hA[a2 * 152 + 128 + jt] = sp5(ax + rb0[128 + jt]);
    }
    __syncthreads();

    // ---- L1 (hA->hB), L2 (hB->hA): K=150, weights direct from L1/L2 ----
    for (int layer = 0; layer < 2; ++layer) {
        const float* W   = layer ? rW2p : rW1p;
        const float* bb  = layer ? rb2 : rb1;
        const float* src = layer ? hB : hA;
        float*       dst = layer ? hA : hB;
        float a0 = 0, a1 = 0, a2v = 0, a3 = 0, ax = 0;
        const float* xs = &src[a2 * 152];
        #pragma unroll 6
        for (int k = 0; k < H; ++k) {
            float x = xs[k];
            const float* wr = &W[k * 152];
            float4 w = *(const float4*)&wr[j0];
            float wx = wr[jx];
            a0 = fmaf(x, w.x, a0); a1 = fmaf(x, w.y, a1);
            a2v = fmaf(x, w.z, a2v); a3 = fmaf(x, w.w, a3);
            ax = fmaf(x, wx, ax);
        }
        float4 b4 = *(const float4*)&bb[j0];
        float4 o; o.x = sp5(a0 + b4.x); o.y = sp5(a1 + b4.y);
        o.z = sp5(a2v + b4.z); o.w = sp5(a3 + b4.w);
        *(float4*)&dst[a2 * 152 + j0] = o;
        if (hasx) dst[a2 * 152 + 128 + jt] = sp5(ax + bb[128 + jt]);
        __syncthreads();
    }

    // ---- G: out[row][c] = sum_k hA[row][k]*W2[k][c] + Pbz[c], c = 16jt..16jt+16 ----
    {
        const int g0r = 16 * jt;
        const int g0 = (g0r < GC) ? g0r : GC - 16;   // clamp idle lanes in-bounds
        float4 c0 = {0,0,0,0}, c1 = {0,0,0,0}, c2 = {0,0,0,0}, c3 = {0,0,0,0};
        const float* xs = &hA[a2 * 152];
        #pragma unroll 3
        for (int k = 0; k < H; ++k) {
            float x = xs[k];
            const float* wr = &W2[(size_t)k * GCP + g0];
            float4 w0 = *(const float4*)&wr[0];
            float4 w1 = *(const float4*)&wr[4];
            float4 w2 = *(const float4*)&wr[8];
            float4 w3 = *(const float4*)&wr[12];
            c0.x = fmaf(x, w0.x, c0.x); c0.y = fmaf(x, w0.y, c0.y);
            c0.z = fmaf(x, w0.z, c0.z); c0.w = fmaf(x, w0.w, c0.w);
            c1.x = fmaf(x, w1.x, c1.x); c1.y = fmaf(x, w1.y, c1.y);
            c1.z = fmaf(x, w1.z, c1.z); c1.w = fmaf(x, w1.w, c1.w);
            c2.x = fmaf(x, w2.x, c2.x); c2.y = fmaf(x, w2.y, c2.y);
            c2.z = fmaf(x, w2.z, c2.z); c2.w = fmaf(x, w2.w, c2.w);
            c3.x = fmaf(x, w3.x, c3.x); c3.y = fmaf(x, w3.y, c3.y);
            c3.z = fmaf(x, w3.z, c3.z); c3.w = fmaf(x, w3.w, c3.w);
        }
        if (g0r < GC) {
            int row = row0 + a2;
            float* gp = &G[(size_t)row * GC + g0];
            float4 p0 = *(const float4*)&Pbz[g0 + 0];
            float4 p1 = *(const float4*)&Pbz[g0 + 4];
            float4 p2 = *(const float4*)&Pbz[g0 + 8];
            float4 p3 = *(const float4*)&Pbz[g0 + 12];
            float4 o0, o1, o2, o3;
            o0.x = c0.x + p0.x; o0.y = c0.y + p0.y; o0.z = c0.z + p0.z; o0.w = c0.w + p0.w;
            o1.x = c1.x + p1.x; o1.y = c1.y + p1.y; o1.z = c1.z + p1.z; o1.w = c1.w + p1.w;
            o2.x = c2.x + p2.x; o2.y = c2.y + p2.y; o2.z = c2.z + p2.z; o2.w = c2.w + p2.w;
            o3.x = c3.x + p3.x; o3.y = c3.y + p3.y; o3.z = c3.z + p3.z; o3.w = c3.w + p3.w;
            *(float4*)&gp[0]  = o0;
            *(float4*)&gp[4]  = o1;
            *(float4*)&gp[8]  = o2;
            *(float4*)&gp[12] = o3;
        }
    }
}

// fused per (b,a): pair mask + G-lerp -> ps[n][72] in LDS; Y-reduce; body23 concat; residual
__global__ void __launch_bounds__(256) k_red(const float* __restrict__ xyz,
                                             const int* __restrict__ Z,
                                             const float* __restrict__ body23,
                                             const float* __restrict__ G,
                                             const float* __restrict__ res_W,
                                             const float* __restrict__ res_b,
                                             float* __restrict__ feats) {
    int ba = blockIdx.x;
    int b = ba >> 6, a = ba & 63;
    int t = threadIdx.x;
    __shared__ float ym[64][12];
    __shared__ float ps[64][76];
    __shared__ float xr[CR];
    __shared__ int t0s[64];
    __shared__ float wls[64];
    __shared__ int zs[64];
    __shared__ int msks[64];
    if (t < 64) {
        int n = t;
        float ax = xyz[((size_t)b * cN + a) * 3 + 0];
        float ay = xyz[((size_t)b * cN + a) * 3 + 1];
        float az = xyz[((size_t)b * cN + a) * 3 + 2];
        float d0 = ax - xyz[((size_t)b * cN + n) * 3 + 0];
        float d1 = ay - xyz[((size_t)b * cN + n) * 3 + 1];
        float d2 = az - xyz[((size_t)b * cN + n) * 3 + 2];
        float s = d0 * d0 + d1 * d1 + d2 * d2;
        float r = sqrtf(s + 1e-12f);
        msks[n] = (r < RADIUS) && (r > 1e-6f);
        float u = r * ((float)(TBL - 1) / RADIUS);
        int t0 = (int)u;
        if (t0 > TBL - 2) t0 = TBL - 2;
        t0s[n] = t0;
        wls[n] = u - (float)t0;
        zs[n] = Z[b * cN + n];
        float inv = 1.0f / r;
        float x = d0 * inv, y = d1 * inv, z = d2 * inv;
        ym[n][0] = 0.28209479177387814f;
        ym[n][1] = 0.4886025119029199f * y;
        ym[n][2] = 0.4886025119029199f * z;
        ym[n][3] = 0.4886025119029199f * x;
        ym[n][4] = 1.0925484305920792f * x * y;
        ym[n][5] = 1.0925484305920792f * y * z;
        ym[n][6] = 0.31539156525252005f * (3.0f * z * z - 1.0f);
        ym[n][7] = 1.0925484305920792f * x * z;
        ym[n][8] = 0.5462742152960396f * (x * x - y * y);
    }
    __syncthreads();
    for (int i = t; i < 64 * LOD; i += 256) {
        int n = i / LOD, lo = i - n * LOD;
        float v = 0.0f;
        if (msks[n]) {
            const float* g = &G[(size_t)t0s[n] * GC + zs[n] * LOD + lo];
            float g0 = g[0], g1 = g[GC];
            v = g0 + wls[n] * (g1 - g0);
        }
        ps[n][lo] = v;
    }
    __syncthreads();
    if (t < 216) {
        int lo, yi;
        if (t < 24) { lo = t; yi = 0; }
        else if (t < 96) { int q = t - 24; int o = q / 3; lo = 24 + o; yi = 1 + (q - o * 3); }
        else { int q = t - 96; int o = q / 5; lo = 48 + o; yi = 4 + (q - o * 5); }
        float acc = 0.0f;
        #pragma unroll 4
        for (int n = 0; n < cN; ++n)
            acc = fmaf(ps[n][lo], ym[n][yi], acc);
        xr[3 + t] = acc * 0.125f;
    } else if (t < 219) {
        xr[t - 216] = body23[(size_t)ba * 3 + (t - 216)];
    }
    __syncthreads();
    if (t < CR) {
        float xv = xr[t];
        feats[(size_t)ba * C2 + t] = xv;
        float racc = res_b[t];
        for (int k = 0; k < CR; ++k)
            racc = fmaf(xr[k], res_W[k * CR + t], racc);
        feats[(size_t)ba * C2 + CR + t] = xv + sp5(racc);
    }
}

__global__ void __launch_bounds__(448) k_pool(const float* __restrict__ feats,
                                              float* __restrict__ pooled) {
    int b = blockIdx.x;
    int t = threadIdx.x;
    if (t < C2) {
        float s = 0.0f;
        for (int a = 0; a < cN; ++a) {
            float v = feats[(size_t)(b * cN + a) * C2 + t];
            s = fmaf(v, v, s);
        }
        pooled[b * C2 + t] = sqrtf(s);
    }
}

__global__ void __launch_bounds__(256) k_head(const float* __restrict__ pooled,
                                              const float* __restrict__ c_W,
                                              const float* __restrict__ c_b,
                                              const float* __restrict__ bn_g,
                                              const float* __restrict__ bn_b,
                                              const float* __restrict__ o_W,
                                              const float* __restrict__ o_b,
                                              float* __restrict__ out) {
    __shared__ float psm[cB][C2];
    __shared__ float hh[cB][HD];
    __shared__ float hh2[cB][HD];
    int t = threadIdx.x;
    for (int i = t; i < cB * C2; i += 256) psm[(unsigned)i / C2][(unsigned)i % C2] = pooled[i];
    __syncthreads();
    for (int o = t; o < cB * HD; o += 256) {
        int b = o >> 7, j = o & 127;
        float s0 = 0, s1 = 0, s2 = 0, s3 = 0;
        for (int ch = 0; ch < 436; ch += 4) {
            s0 = fmaf(psm[b][ch + 0], c_W[(ch + 0) * HD + j], s0);
            s1 = fmaf(psm[b][ch + 1], c_W[(ch + 1) * HD + j], s1);
            s2 = fmaf(psm[b][ch + 2], c_W[(ch + 2) * HD + j], s2);
            s3 = fmaf(psm[b][ch + 3], c_W[(ch + 3) * HD + j], s3);
        }
        s0 = fmaf(psm[b][436], c_W[436 * HD + j], s0);
        s1 = fmaf(psm[b][437], c_W[437 * HD + j], s1);
        hh[b][j] = sp1(((s0 + s1) + (s2 + s3)) + c_b[j]);
    }
    __syncthreads();
    if (t < HD) {
        int j = t;
        float mu = 0.0f;
        for (int bb = 0; bb < cB; ++bb) mu += hh[bb][j];
        mu *= (1.0f / cB);
        float var = 0.0f;
        for (int bb = 0; bb < cB; ++bb) { float d = hh[bb][j] - mu; var = fmaf(d, d, var); }
        var *= (1.0f / cB);
        float sc = bn_g[j] / sqrtf(var + 1e-5f);
        float bnb = bn_b[j];
        for (int bb = 0; bb < cB; ++bb)
            hh2[bb][j] = sp1((hh[bb][j] - mu) * sc + bnb);
    }
    __syncthreads();
    if (t < cB) {
        float s = o_b[0];
        for (int j = 0; j < HD; ++j) s = fmaf(hh2[t][j], o_W[j], s);
        out[t] = 1.0f / (1.0f + expf(-s));
    }
}

extern "C" void kernel_launch(void* const* d_in, const int* in_sizes, int n_in,
                              void* d_out, int out_size, void* d_ws, size_t ws_size,
                              hipStream_t stream) {
    const float* xyz    = (const float*)d_in[0];
    const int*   Z      = (const int*)d_in[1];
    const float* body23 = (const float*)d_in[2];
    const float* emb_W  = (const float*)d_in[3];
    const float* rW0    = (const float*)d_in[4];
    const float* rb0    = (const float*)d_in[5];
    const float* rW1    = (const float*)d_in[6];
    const float* rb1    = (const float*)d_in[7];
    const float* rW2    = (const float*)d_in[8];
    const float* rb2    = (const float*)d_in[9];
    const float* rW3    = (const float*)d_in[10];
    const float* rb3    = (const float*)d_in[11];
    const float* res_W  = (const float*)d_in[12];
    const float* res_b  = (const float*)d_in[13];
    const float* c_W    = (const float*)d_in[14];
    const float* c_b    = (const float*)d_in[15];
    const float* bn_g   = (const float*)d_in[16];
    const float* bn_b   = (const float*)d_in[17];
    const float* o_W    = (const float*)d_in[18];
    const float* o_b    = (const float*)d_in[19];

    float* w      = (float*)d_ws;
    float* W2     = w;                        // 150*512    = 76800
    float* Pbz    = W2 + 76800;               // 432
    float* rW0p   = Pbz + 432;                // 10*152     = 1520
    float* rW1p   = rW0p + 1520;              // 150*152    = 22800
    float* rW2p   = rW1p + 22800;             // 22800
    float* G      = rW2p + 22800;             // 2048*432   = 884736
    float* feats  = G + 884736;               // 1024*438   = 448512
    float* pooled = feats + 448512;           // 16*438
    (void)in_sizes; (void)n_in; (void)out_size; (void)ws_size;

    k_pad  <<<184, 256, 0, stream>>>(rW0, rW1, rW2, rW0p, rW1p, rW2p);
    k_wz   <<<dim3(NSP, 15), 256, 0, stream>>>(emb_W, rW3, rb3, W2, Pbz);
    k_chain<<<TBL / 4, 128, 0, stream>>>(rW0p, rb0, rW1p, rb1, rW2p, rb2, W2, Pbz, G);
    k_red  <<<cB * cN, 256, 0, stream>>>(xyz, Z, body23, G, res_W, res_b, feats);
    k_pool <<<cB, 448, 0, stream>>>(feats, pooled);
    k_head <<<1, 256, 0, stream>>>(pooled, c_W, c_b, bn_g, bn_b, o_W, o_b, (float*)d_out);
}

// Round 15
// 120.108 us; speedup vs baseline: 5.1601x; 1.4810x over previous
//
#include <hip/hip_runtime.h>
#include <math.h>

constexpr int cB  = 16;
constexpr int cN  = 64;
constexpr int EMB = 32;
constexpr int NL  = 3;
constexpr int CDIM = 24;
constexpr int LOD = NL * CDIM;      // 72
constexpr int NB  = 10;
constexpr int H   = 150;
constexpr int CR  = 219;
constexpr int C2  = 438;
constexpr int HD  = 128;
constexpr int NSP = 6;              // species count
constexpr int GC  = NSP * LOD;      // 432 G-columns
constexpr int GCP = 512;            // padded W2 row
constexpr int TBL = 2048;           // r-table resolution (err ~1e-4 << 7.2e-3 threshold)
constexpr float RADIUS = 2.0f;

__device__ __forceinline__ float sp5(float x) {
    return fmaxf(x, 0.0f) + 0.2f * log1pf(expf(-5.0f * fabsf(x)));
}
__device__ __forceinline__ float sp1(float x) {
    return fmaxf(x, 0.0f) + log1pf(expf(-fabsf(x)));
}

// pad rW0/rW1/rW2 into [.][152] copies; transpose c_W -> c_Wt[128][440]
__global__ void __launch_bounds__(256) k_pad(const float* __restrict__ rW0,
                                             const float* __restrict__ rW1,
                                             const float* __restrict__ rW2,
                                             const float* __restrict__ c_W,
                                             float* __restrict__ rW0p,
                                             float* __restrict__ rW1p,
                                             float* __restrict__ rW2p,
                                             float* __restrict__ c_Wt) {
    int total = NB * 152 + 2 * H * 152 + HD * 440;   // 1520+45600+56320
    for (int i = blockIdx.x * 256 + threadIdx.x; i < total; i += gridDim.x * 256) {
        if (i < NB * 152) {
            int r = i / 152, c = i - r * 152;
            rW0p[i] = (c < H) ? rW0[r * H + c] : 0.0f;
        } else if (i < NB * 152 + H * 152) {
            int j = i - NB * 152; int r = j / 152, c = j - r * 152;
            rW1p[j] = (c < H) ? rW1[r * H + c] : 0.0f;
        } else if (i < NB * 152 + 2 * H * 152) {
            int j = i - NB * 152 - H * 152; int r = j / 152, c = j - r * 152;
            rW2p[j] = (c < H) ? rW2[r * H + c] : 0.0f;
        } else {
            int j = i - NB * 152 - 2 * H * 152;
            int jj = j / 440, ch = j - jj * 440;
            c_Wt[j] = (ch < C2) ? c_W[ch * HD + jj] : 0.0f;
        }
    }
}

// W2[k][z*72+lo] = sum_i rW3[k][lo*32+i]*emb[z][i]  (z-interleaved, 512-padded);
// Pbz flat [z*72+lo] from rb3.
__global__ void __launch_bounds__(256) k_wz(const float* __restrict__ emb_W,
                                            const float* __restrict__ rW3,
                                            const float* __restrict__ rb3,
                                            float* __restrict__ W2,
                                            float* __restrict__ Pbz) {
    int z = blockIdx.x, hb = blockIdx.y;     // 6 x 15 blocks, 10 k-rows each
    __shared__ float e[EMB];
    int t = threadIdx.x;
    if (t < EMB) e[t] = emb_W[z * EMB + t];
    __syncthreads();
    for (int o = t; o < 10 * LOD; o += 256) {
        int k = hb * 10 + o / LOD, lo = o % LOD;
        const float* wr = &rW3[(size_t)k * (LOD * EMB) + lo * EMB];
        float s = 0.0f;
        #pragma unroll
        for (int i = 0; i < EMB; ++i) s = fmaf(wr[i], e[i], s);
        W2[(size_t)k * GCP + z * LOD + lo] = s;
    }
    if (z == 0) {  // zero the pad cols 432..511
        for (int o = t; o < 10 * (GCP - GC); o += 256) {
            int k = hb * 10 + o / (GCP - GC), c = GC + o % (GCP - GC);
            W2[(size_t)k * GCP + c] = 0.0f;
        }
    }
    if (hb == 0 && t < LOD) {
        float s = 0.0f;
        #pragma unroll
        for (int i = 0; i < EMB; ++i) s = fmaf(rb3[t * EMB + i], e[i], s);
        Pbz[z * LOD + t] = s;
    }
}

// Fused table chain, NO weight staging: weights stream from L1/L2 via coalesced
// float4 loads. LDS holds only activations. 512 blocks x 128 thr x 4 rows.
__global__ void __launch_bounds__(128) k_chain(const float* __restrict__ rW0p,
                                               const float* __restrict__ rb0,
                                               const float* __restrict__ rW1p,
                                               const float* __restrict__ rb1,
                                               const float* __restrict__ rW2p,
                                               const float* __restrict__ rb2,
                                               const float* __restrict__ W2,
                                               const float* __restrict__ Pbz,
                                               float* __restrict__ G) {
    const int row0 = blockIdx.x * 4;
    const int t = threadIdx.x;
    const int a2 = t >> 5;                   // 0..3 local row
    const int jt = t & 31;                   // col group
    const int j0 = 4 * jt;                   // f4 cols [j0, j0+4)
    const bool hasx = (jt < 22);
    const int jx = hasx ? 128 + jt : 128;    // extra col (idle lanes read col 128, discard)

    __shared__ __align__(16) float bas[4][10];
    __shared__ __align__(16) float hA[4 * 152];
    __shared__ __align__(16) float hB[4 * 152];

    if (t < 4) {
        float r = (float)(row0 + t) * (RADIUS / (float)(TBL - 1));
        #pragma unroll
        for (int k = 0; k < NB; ++k) {
            float d = r * 4.5f - (float)k;
            float v = 0.0f;
            if (fabsf(d) < 1.0f) { float cc = cosf(1.57079632679489662f * d); v = cc * cc; }
            bas[t][k] = v;
        }
    }
    __syncthreads();

    // ---- L0: K=10 ----
    {
        float a0 = 0, a1 = 0, a2v = 0, a3 = 0, ax = 0;
        #pragma unroll
        for (int k = 0; k < NB; ++k) {
            float x = bas[a2][k];
            float4 w = *(const float4*)&rW0p[k * 152 + j0];
            float wx = rW0p[k * 152 + jx];
            a0 = fmaf(x, w.x, a0); a1 = fmaf(x, w.y, a1);
            a2v = fmaf(x, w.z, a2v); a3 = fmaf(x, w.w, a3);
            ax = fmaf(x, wx, ax);
        }
        float4 b4 = *(const float4*)&rb0[j0];
        float4 o; o.x = sp5(a0 + b4.x); o.y = sp5(a1 + b4.y);
        o.z = sp5(a2v + b4.z); o.w = sp5(a3 + b4.w);
        *(float4*)&hA[a2 * 152 + j0] = o;
        if (hasx) hA[a2 * 152 + 128 + jt] = sp5(ax + rb0[128 + jt]);
    }
    __syncthreads();

    // ---- L1 (hA->hB), L2 (hB->hA): K=150, weights direct from L1/L2 ----
    for (int layer = 0; layer < 2; ++layer) {
        const float* W   = layer ? rW2p : rW1p;
        const float* bb  = layer ? rb2 : rb1;
        const float* src = layer ? hB : hA;
        float*       dst = layer ? hA : hB;
        float a0 = 0, a1 = 0, a2v = 0, a3 = 0, ax = 0;
        const float* xs = &src[a2 * 152];
        #pragma unroll 6
        for (int k = 0; k < H; ++k) {
            float x = xs[k];
            const float* wr = &W[k * 152];
            float4 w = *(const float4*)&wr[j0];
            float wx = wr[jx];
            a0 = fmaf(x, w.x, a0); a1 = fmaf(x, w.y, a1);
            a2v = fmaf(x, w.z, a2v); a3 = fmaf(x, w.w, a3);
            ax = fmaf(x, wx, ax);
        }
        float4 b4 = *(const float4*)&bb[j0];
        float4 o; o.x = sp5(a0 + b4.x); o.y = sp5(a1 + b4.y);
        o.z = sp5(a2v + b4.z); o.w = sp5(a3 + b4.w);
        *(float4*)&dst[a2 * 152 + j0] = o;
        if (hasx) dst[a2 * 152 + 128 + jt] = sp5(ax + bb[128 + jt]);
        __syncthreads();
    }

    // ---- G: out[row][c] = sum_k hA[row][k]*W2[k][c] + Pbz[c], c = 16jt..16jt+16 ----
    {
        const int g0r = 16 * jt;
        const int g0 = (g0r < GC) ? g0r : GC - 16;   // clamp idle lanes in-bounds
        float4 c0 = {0,0,0,0}, c1 = {0,0,0,0}, c2 = {0,0,0,0}, c3 = {0,0,0,0};
        const float* xs = &hA[a2 * 152];
        #pragma unroll 3
        for (int k = 0; k < H; ++k) {
            float x = xs[k];
            const float* wr = &W2[(size_t)k * GCP + g0];
            float4 w0 = *(const float4*)&wr[0];
            float4 w1 = *(const float4*)&wr[4];
            float4 w2 = *(const float4*)&wr[8];
            float4 w3 = *(const float4*)&wr[12];
            c0.x = fmaf(x, w0.x, c0.x); c0.y = fmaf(x, w0.y, c0.y);
            c0.z = fmaf(x, w0.z, c0.z); c0.w = fmaf(x, w0.w, c0.w);
            c1.x = fmaf(x, w1.x, c1.x); c1.y = fmaf(x, w1.y, c1.y);
            c1.z = fmaf(x, w1.z, c1.z); c1.w = fmaf(x, w1.w, c1.w);
            c2.x = fmaf(x, w2.x, c2.x); c2.y = fmaf(x, w2.y, c2.y);
            c2.z = fmaf(x, w2.z, c2.z); c2.w = fmaf(x, w2.w, c2.w);
            c3.x = fmaf(x, w3.x, c3.x); c3.y = fmaf(x, w3.y, c3.y);
            c3.z = fmaf(x, w3.z, c3.z); c3.w = fmaf(x, w3.w, c3.w);
        }
        if (g0r < GC) {
            int row = row0 + a2;
            float* gp = &G[(size_t)row * GC + g0];
            float4 p0 = *(const float4*)&Pbz[g0 + 0];
            float4 p1 = *(const float4*)&Pbz[g0 + 4];
            float4 p2 = *(const float4*)&Pbz[g0 + 8];
            float4 p3 = *(const float4*)&Pbz[g0 + 12];
            float4 o0, o1, o2, o3;
            o0.x = c0.x + p0.x; o0.y = c0.y + p0.y; o0.z = c0.z + p0.z; o0.w = c0.w + p0.w;
            o1.x = c1.x + p1.x; o1.y = c1.y + p1.y; o1.z = c1.z + p1.z; o1.w = c1.w + p1.w;
            o2.x = c2.x + p2.x; o2.y = c2.y + p2.y; o2.z = c2.z + p2.z; o2.w = c2.w + p2.w;
            o3.x = c3.x + p3.x; o3.y = c3.y + p3.y; o3.z = c3.z + p3.z; o3.w = c3.w + p3.w;
            *(float4*)&gp[0]  = o0;
            *(float4*)&gp[4]  = o1;
            *(float4*)&gp[8]  = o2;
            *(float4*)&gp[12] = o3;
        }
    }
}

// fused per (b,a): pair mask + G-lerp -> ps[n][72] in LDS; Y-reduce; body23 concat; residual
__global__ void __launch_bounds__(256) k_red(const float* __restrict__ xyz,
                                             const int* __restrict__ Z,
                                             const float* __restrict__ body23,
                                             const float* __restrict__ G,
                                             const float* __restrict__ res_W,
                                             const float* __restrict__ res_b,
                                             float* __restrict__ feats) {
    int ba = blockIdx.x;
    int b = ba >> 6, a = ba & 63;
    int t = threadIdx.x;
    __shared__ float ym[64][12];
    __shared__ float ps[64][76];
    __shared__ float xr[CR];
    __shared__ int t0s[64];
    __shared__ float wls[64];
    __shared__ int zs[64];
    __shared__ int msks[64];
    if (t < 64) {
        int n = t;
        float ax = xyz[((size_t)b * cN + a) * 3 + 0];
        float ay = xyz[((size_t)b * cN + a) * 3 + 1];
        float az = xyz[((size_t)b * cN + a) * 3 + 2];
        float d0 = ax - xyz[((size_t)b * cN + n) * 3 + 0];
        float d1 = ay - xyz[((size_t)b * cN + n) * 3 + 1];
        float d2 = az - xyz[((size_t)b * cN + n) * 3 + 2];
        float s = d0 * d0 + d1 * d1 + d2 * d2;
        float r = sqrtf(s + 1e-12f);
        msks[n] = (r < RADIUS) && (r > 1e-6f);
        float u = r * ((float)(TBL - 1) / RADIUS);
        int t0 = (int)u;
        if (t0 > TBL - 2) t0 = TBL - 2;
        t0s[n] = t0;
        wls[n] = u - (float)t0;
        zs[n] = Z[b * cN + n];
        float inv = 1.0f / r;
        float x = d0 * inv, y = d1 * inv, z = d2 * inv;
        ym[n][0] = 0.28209479177387814f;
        ym[n][1] = 0.4886025119029199f * y;
        ym[n][2] = 0.4886025119029199f * z;
        ym[n][3] = 0.4886025119029199f * x;
        ym[n][4] = 1.0925484305920792f * x * y;
        ym[n][5] = 1.0925484305920792f * y * z;
        ym[n][6] = 0.31539156525252005f * (3.0f * z * z - 1.0f);
        ym[n][7] = 1.0925484305920792f * x * z;
        ym[n][8] = 0.5462742152960396f * (x * x - y * y);
    }
    __syncthreads();
    for (int i = t; i < 64 * LOD; i += 256) {
        int n = i / LOD, lo = i - n * LOD;
        float v = 0.0f;
        if (msks[n]) {
            const float* g = &G[(size_t)t0s[n] * GC + zs[n] * LOD + lo];
            float g0 = g[0], g1 = g[GC];
            v = g0 + wls[n] * (g1 - g0);
        }
        ps[n][lo] = v;
    }
    __syncthreads();
    if (t < 216) {
        int lo, yi;
        if (t < 24) { lo = t; yi = 0; }
        else if (t < 96) { int q = t - 24; int o = q / 3; lo = 24 + o; yi = 1 + (q - o * 3); }
        else { int q = t - 96; int o = q / 5; lo = 48 + o; yi = 4 + (q - o * 5); }
        float acc = 0.0f;
        #pragma unroll 4
        for (int n = 0; n < cN; ++n)
            acc = fmaf(ps[n][lo], ym[n][yi], acc);
        xr[3 + t] = acc * 0.125f;
    } else if (t < 219) {
        xr[t - 216] = body23[(size_t)ba * 3 + (t - 216)];
    }
    __syncthreads();
    if (t < CR) {
        float xv = xr[t];
        feats[(size_t)ba * C2 + t] = xv;
        float racc = res_b[t];
        for (int k = 0; k < CR; ++k)
            racc = fmaf(xr[k], res_W[k * CR + t], racc);
        feats[(size_t)ba * C2 + CR + t] = xv + sp5(racc);
    }
}

__global__ void __launch_bounds__(448) k_pool(const float* __restrict__ feats,
                                              float* __restrict__ pooled) {
    int b = blockIdx.x;
    int t = threadIdx.x;
    if (t < C2) {
        float s = 0.0f;
        for (int a = 0; a < cN; ++a) {
            float v = feats[(size_t)(b * cN + a) * C2 + t];
            s = fmaf(v, v, s);
        }
        pooled[b * C2 + t] = sqrtf(s);
    }
}

// hh[b][j] = sp1(pooled[b] . c_Wt[j] + c_b[j]); one block per column j, 64 lanes
__global__ void __launch_bounds__(64) k_head1(const float* __restrict__ pooled,
                                              const float* __restrict__ c_Wt,
                                              const float* __restrict__ c_b,
                                              float* __restrict__ hh) {
    int j = blockIdx.x;
    int l = threadIdx.x;
    float acc[cB];
    #pragma unroll
    for (int b = 0; b < cB; ++b) acc[b] = 0.0f;
    const float* wr = &c_Wt[j * 440];
    for (int ch = l; ch < C2; ch += 64) {
        float wv = wr[ch];
        #pragma unroll
        for (int b = 0; b < cB; ++b)
            acc[b] = fmaf(pooled[b * C2 + ch], wv, acc[b]);
    }
    #pragma unroll
    for (int off = 32; off >= 1; off >>= 1) {
        #pragma unroll
        for (int b = 0; b < cB; ++b) acc[b] += __shfl_xor(acc[b], off, 64);
    }
    if (l == 0) {
        float cb = c_b[j];
        #pragma unroll
        for (int b = 0; b < cB; ++b) hh[b * HD + j] = sp1(acc[b] + cb);
    }
}

// BN (training batch stats) + softplus + output linear + sigmoid; single small block
__global__ void __launch_bounds__(128) k_head2(const float* __restrict__ hh,
                                               const float* __restrict__ bn_g,
                                               const float* __restrict__ bn_b,
                                               const float* __restrict__ o_W,
                                               const float* __restrict__ o_b,
                                               float* __restrict__ out) {
    __shared__ float hh2[cB][HD];
    int t = threadIdx.x;                     // = column j
    float v[cB];
    float mu = 0.0f;
    #pragma unroll
    for (int b = 0; b < cB; ++b) { v[b] = hh[b * HD + t]; mu += v[b]; }
    mu *= (1.0f / cB);
    float var = 0.0f;
    #pragma unroll
    for (int b = 0; b < cB; ++b) { float d = v[b] - mu; var = fmaf(d, d, var); }
    var *= (1.0f / cB);
    float sc = bn_g[t] / sqrtf(var + 1e-5f);
    float bnb = bn_b[t];
    #pragma unroll
    for (int b = 0; b < cB; ++b) hh2[b][t] = sp1((v[b] - mu) * sc + bnb);
    __syncthreads();
    if (t < cB) {
        float s = o_b[0];
        for (int j = 0; j < HD; ++j) s = fmaf(hh2[t][j], o_W[j], s);
        out[t] = 1.0f / (1.0f + expf(-s));
    }
}

extern "C" void kernel_launch(void* const* d_in, const int* in_sizes, int n_in,
                              void* d_out, int out_size, void* d_ws, size_t ws_size,
                              hipStream_t stream) {
    const float* xyz    = (const float*)d_in[0];
    const int*   Z      = (const int*)d_in[1];
    const float* body23 = (const float*)d_in[2];
    const float* emb_W  = (const float*)d_in[3];
    const float* rW0    = (const float*)d_in[4];
    const float* rb0    = (const float*)d_in[5];
    const float* rW1    = (const float*)d_in[6];
    const float* rb1    = (const float*)d_in[7];
    const float* rW2    = (const float*)d_in[8];
    const float* rb2    = (const float*)d_in[9];
    const float* rW3    = (const float*)d_in[10];
    const float* rb3    = (const float*)d_in[11];
    const float* res_W  = (const float*)d_in[12];
    const float* res_b  = (const float*)d_in[13];
    const float* c_W    = (const float*)d_in[14];
    const float* c_b    = (const float*)d_in[15];
    const float* bn_g   = (const float*)d_in[16];
    const float* bn_b   = (const float*)d_in[17];
    const float* o_W    = (const float*)d_in[18];
    const float* o_b    = (const float*)d_in[19];

    float* w      = (float*)d_ws;
    float* W2     = w;                        // 150*512    = 76800
    float* Pbz    = W2 + 76800;               // 432
    float* rW0p   = Pbz + 432;                // 10*152     = 1520
    float* rW1p   = rW0p + 1520;              // 150*152    = 22800
    float* rW2p   = rW1p + 22800;             // 22800
    float* c_Wt   = rW2p + 22800;             // 128*440    = 56320
    float* G      = c_Wt + 56320;             // 2048*432   = 884736
    float* feats  = G + 884736;               // 1024*438   = 448512
    float* pooled = feats + 448512;           // 16*438     = 7008
    float* hh     = pooled + 7008;            // 16*128     = 2048
    (void)in_sizes; (void)n_in; (void)out_size; (void)ws_size;

    k_pad  <<<256, 256, 0, stream>>>(rW0, rW1, rW2, c_W, rW0p, rW1p, rW2p, c_Wt);
    k_wz   <<<dim3(NSP, 15), 256, 0, stream>>>(emb_W, rW3, rb3, W2, Pbz);
    k_chain<<<TBL / 4, 128, 0, stream>>>(rW0p, rb0, rW1p, rb1, rW2p, rb2, W2, Pbz, G);
    k_red  <<<cB * cN, 256, 0, stream>>>(xyz, Z, body23, G, res_W, res_b, feats);
    k_pool <<<cB, 448, 0, stream>>>(feats, pooled);
    k_head1<<<HD, 64, 0, stream>>>(pooled, c_Wt, c_b, hh);
    k_head2<<<1, 128, 0, stream>>>(hh, bn_g, bn_b, o_W, o_b, (float*)d_out);
}

// Round 16
// 107.735 us; speedup vs baseline: 5.7528x; 1.1148x over previous
//
#include <hip/hip_runtime.h>
#include <math.h>

constexpr int cB  = 16;
constexpr int cN  = 64;
constexpr int EMB = 32;
constexpr int NL  = 3;
constexpr int CDIM = 24;
constexpr int LOD = NL * CDIM;      // 72
constexpr int NB  = 10;
constexpr int H   = 150;
constexpr int CR  = 219;
constexpr int C2  = 438;
constexpr int HD  = 128;
constexpr int NSP = 6;              // species count
constexpr int GC  = NSP * LOD;      // 432 G-columns
constexpr int GCP = 512;            // padded W2 row
constexpr int TBL = 2048;           // r-table resolution (err ~1e-4 << 7.2e-3 threshold)
constexpr float RADIUS = 2.0f;

__device__ __forceinline__ float sp5(float x) {
    return fmaxf(x, 0.0f) + 0.2f * log1pf(expf(-5.0f * fabsf(x)));
}
__device__ __forceinline__ float sp1(float x) {
    return fmaxf(x, 0.0f) + log1pf(expf(-fabsf(x)));
}

// pad rW0/rW1/rW2 into [.][152] copies; transpose c_W -> c_Wt[128][440]
__global__ void __launch_bounds__(256) k_pad(const float* __restrict__ rW0,
                                             const float* __restrict__ rW1,
                                             const float* __restrict__ rW2,
                                             const float* __restrict__ c_W,
                                             float* __restrict__ rW0p,
                                             float* __restrict__ rW1p,
                                             float* __restrict__ rW2p,
                                             float* __restrict__ c_Wt) {
    int total = NB * 152 + 2 * H * 152 + HD * 440;   // 1520+45600+56320
    for (int i = blockIdx.x * 256 + threadIdx.x; i < total; i += gridDim.x * 256) {
        if (i < NB * 152) {
            int r = i / 152, c = i - r * 152;
            rW0p[i] = (c < H) ? rW0[r * H + c] : 0.0f;
        } else if (i < NB * 152 + H * 152) {
            int j = i - NB * 152; int r = j / 152, c = j - r * 152;
            rW1p[j] = (c < H) ? rW1[r * H + c] : 0.0f;
        } else if (i < NB * 152 + 2 * H * 152) {
            int j = i - NB * 152 - H * 152; int r = j / 152, c = j - r * 152;
            rW2p[j] = (c < H) ? rW2[r * H + c] : 0.0f;
        } else {
            int j = i - NB * 152 - 2 * H * 152;
            int jj = j / 440, ch = j - jj * 440;
            c_Wt[j] = (ch < C2) ? c_W[ch * HD + jj] : 0.0f;
        }
    }
}

// W2[k][z*72+lo] = sum_i rW3[k][lo*32+i]*emb[z][i]  (z-interleaved, 512-padded);
// Pbz flat [z*72+lo] from rb3.
__global__ void __launch_bounds__(256) k_wz(const float* __restrict__ emb_W,
                                            const float* __restrict__ rW3,
                                            const float* __restrict__ rb3,
                                            float* __restrict__ W2,
                                            float* __restrict__ Pbz) {
    int z = blockIdx.x, hb = blockIdx.y;     // 6 x 15 blocks, 10 k-rows each
    __shared__ float e[EMB];
    int t = threadIdx.x;
    if (t < EMB) e[t] = emb_W[z * EMB + t];
    __syncthreads();
    for (int o = t; o < 10 * LOD; o += 256) {
        int k = hb * 10 + o / LOD, lo = o % LOD;
        const float* wr = &rW3[(size_t)k * (LOD * EMB) + lo * EMB];
        float s = 0.0f;
        #pragma unroll
        for (int i = 0; i < EMB; ++i) s = fmaf(wr[i], e[i], s);
        W2[(size_t)k * GCP + z * LOD + lo] = s;
    }
    if (z == 0) {  // zero the pad cols 432..511
        for (int o = t; o < 10 * (GCP - GC); o += 256) {
            int k = hb * 10 + o / (GCP - GC), c = GC + o % (GCP - GC);
            W2[(size_t)k * GCP + c] = 0.0f;
        }
    }
    if (hb == 0 && t < LOD) {
        float s = 0.0f;
        #pragma unroll
        for (int i = 0; i < EMB; ++i) s = fmaf(rb3[t * EMB + i], e[i], s);
        Pbz[z * LOD + t] = s;
    }
}

// Fused table chain, no weight staging (weights stream L1/L2, coalesced).
// 2 rows/block x 256 thr, 1024 blocks -> 4096 waves = 4 waves/SIMD for latency hiding.
// Thread map: a2 = t>>7 (row), jt = t&127 (col).
__global__ void __launch_bounds__(256) k_chain(const float* __restrict__ rW0p,
                                               const float* __restrict__ rb0,
                                               const float* __restrict__ rW1p,
                                               const float* __restrict__ rb1,
                                               const float* __restrict__ rW2p,
                                               const float* __restrict__ rb2,
                                               const float* __restrict__ W2,
                                               const float* __restrict__ Pbz,
                                               float* __restrict__ G) {
    const int row0 = blockIdx.x * 2;
    const int t = threadIdx.x;
    const int a2 = t >> 7;                   // 0..1 local row
    const int jt = t & 127;                  // col
    const bool hasx = (jt < 22);
    const int jx = hasx ? 128 + jt : 128;    // extra col (idle lanes read col 128, discard)

    __shared__ __align__(16) float bas[2][10];
    __shared__ __align__(16) float hA[2 * 152];
    __shared__ __align__(16) float hB[2 * 152];

    if (t < 2) {
        float r = (float)(row0 + t) * (RADIUS / (float)(TBL - 1));
        #pragma unroll
        for (int k = 0; k < NB; ++k) {
            float d = r * 4.5f - (float)k;
            float v = 0.0f;
            if (fabsf(d) < 1.0f) { float cc = cosf(1.57079632679489662f * d); v = cc * cc; }
            bas[t][k] = v;
        }
    }
    __syncthreads();

    // ---- L0: K=10 ----
    {
        float a0 = 0, ax = 0;
        #pragma unroll
        for (int k = 0; k < NB; ++k) {
            float x = bas[a2][k];
            a0 = fmaf(x, rW0p[k * 152 + jt], a0);
            ax = fmaf(x, rW0p[k * 152 + jx], ax);
        }
        hA[a2 * 152 + jt] = sp5(a0 + rb0[jt]);
        if (hasx) hA[a2 * 152 + 128 + jt] = sp5(ax + rb0[128 + jt]);
    }
    __syncthreads();

    // ---- L1 (hA->hB), L2 (hB->hA): K=150, weights direct from L1/L2 ----
    for (int layer = 0; layer < 2; ++layer) {
        const float* W   = layer ? rW2p : rW1p;
        const float* bb  = layer ? rb2 : rb1;
        const float* src = layer ? hB : hA;
        float*       dst = layer ? hA : hB;
        float a0 = 0, ax = 0;
        const float* xs = &src[a2 * 152];
        #pragma unroll 10
        for (int k = 0; k < H; ++k) {
            float x = xs[k];
            const float* wr = &W[k * 152];
            a0 = fmaf(x, wr[jt], a0);
            ax = fmaf(x, wr[jx], ax);
        }
        dst[a2 * 152 + jt] = sp5(a0 + bb[jt]);
        if (hasx) dst[a2 * 152 + 128 + jt] = sp5(ax + bb[128 + jt]);
        __syncthreads();
    }

    // ---- G: out[row][c] = sum_k hA[row][k]*W2[k][c] + Pbz[c], c = 4jt..4jt+4 ----
    if (jt < 108) {
        const int g0 = 4 * jt;
        float4 c0 = {0, 0, 0, 0};
        const float* xs = &hA[a2 * 152];
        #pragma unroll 10
        for (int k = 0; k < H; ++k) {
            float x = xs[k];
            float4 w = *(const float4*)&W2[(size_t)k * GCP + g0];
            c0.x = fmaf(x, w.x, c0.x); c0.y = fmaf(x, w.y, c0.y);
            c0.z = fmaf(x, w.z, c0.z); c0.w = fmaf(x, w.w, c0.w);
        }
        int row = row0 + a2;
        float4 p = *(const float4*)&Pbz[g0];
        float4 o;
        o.x = c0.x + p.x; o.y = c0.y + p.y; o.z = c0.z + p.z; o.w = c0.w + p.w;
        *(float4*)&G[(size_t)row * GC + g0] = o;
    }
}

// fused per (b,a): pair mask + G-lerp -> ps[n][72] in LDS; Y-reduce; body23 concat; residual
__global__ void __launch_bounds__(256) k_red(const float* __restrict__ xyz,
                                             const int* __restrict__ Z,
                                             const float* __restrict__ body23,
                                             const float* __restrict__ G,
                                             const float* __restrict__ res_W,
                                             const float* __restrict__ res_b,
                                             float* __restrict__ feats) {
    int ba = blockIdx.x;
    int b = ba >> 6, a = ba & 63;
    int t = threadIdx.x;
    __shared__ float ym[64][12];
    __shared__ float ps[64][76];
    __shared__ float xr[CR];
    __shared__ int t0s[64];
    __shared__ float wls[64];
    __shared__ int zs[64];
    __shared__ int msks[64];
    if (t < 64) {
        int n = t;
        float ax = xyz[((size_t)b * cN + a) * 3 + 0];
        float ay = xyz[((size_t)b * cN + a) * 3 + 1];
        float az = xyz[((size_t)b * cN + a) * 3 + 2];
        float d0 = ax - xyz[((size_t)b * cN + n) * 3 + 0];
        float d1 = ay - xyz[((size_t)b * cN + n) * 3 + 1];
        float d2 = az - xyz[((size_t)b * cN + n) * 3 + 2];
        float s = d0 * d0 + d1 * d1 + d2 * d2;
        float r = sqrtf(s + 1e-12f);
        msks[n] = (r < RADIUS) && (r > 1e-6f);
        float u = r * ((float)(TBL - 1) / RADIUS);
        int t0 = (int)u;
        if (t0 > TBL - 2) t0 = TBL - 2;
        t0s[n] = t0;
        wls[n] = u - (float)t0;
        zs[n] = Z[b * cN + n];
        float inv = 1.0f / r;
        float x = d0 * inv, y = d1 * inv, z = d2 * inv;
        ym[n][0] = 0.28209479177387814f;
        ym[n][1] = 0.4886025119029199f * y;
        ym[n][2] = 0.4886025119029199f * z;
        ym[n][3] = 0.4886025119029199f * x;
        ym[n][4] = 1.0925484305920792f * x * y;
        ym[n][5] = 1.0925484305920792f * y * z;
        ym[n][6] = 0.31539156525252005f * (3.0f * z * z - 1.0f);
        ym[n][7] = 1.0925484305920792f * x * z;
        ym[n][8] = 0.5462742152960396f * (x * x - y * y);
    }
    __syncthreads();
    for (int i = t; i < 64 * LOD; i += 256) {
        int n = i / LOD, lo = i - n * LOD;
        float v = 0.0f;
        if (msks[n]) {
            const float* g = &G[(size_t)t0s[n] * GC + zs[n] * LOD + lo];
            float g0 = g[0], g1 = g[GC];
            v = g0 + wls[n] * (g1 - g0);
        }
        ps[n][lo] = v;
    }
    __syncthreads();
    if (t < 216) {
        int lo, yi;
        if (t < 24) { lo = t; yi = 0; }
        else if (t < 96) { int q = t - 24; int o = q / 3; lo = 24 + o; yi = 1 + (q - o * 3); }
        else { int q = t - 96; int o = q / 5; lo = 48 + o; yi = 4 + (q - o * 5); }
        float acc = 0.0f;
        #pragma unroll 4
        for (int n = 0; n < cN; ++n)
            acc = fmaf(ps[n][lo], ym[n][yi], acc);
        xr[3 + t] = acc * 0.125f;
    } else if (t < 219) {
        xr[t - 216] = body23[(size_t)ba * 3 + (t - 216)];
    }
    __syncthreads();
    if (t < CR) {
        float xv = xr[t];
        feats[(size_t)ba * C2 + t] = xv;
        float racc = res_b[t];
        for (int k = 0; k < CR; ++k)
            racc = fmaf(xr[k], res_W[k * CR + t], racc);
        feats[(size_t)ba * C2 + CR + t] = xv + sp5(racc);
    }
}

__global__ void __launch_bounds__(448) k_pool(const float* __restrict__ feats,
                                              float* __restrict__ pooled) {
    int b = blockIdx.x;
    int t = threadIdx.x;
    if (t < C2) {
        float s = 0.0f;
        for (int a = 0; a < cN; ++a) {
            float v = feats[(size_t)(b * cN + a) * C2 + t];
            s = fmaf(v, v, s);
        }
        pooled[b * C2 + t] = sqrtf(s);
    }
}

// hh[b][j] = sp1(pooled[b] . c_Wt[j] + c_b[j]); one block per column j, 64 lanes
__global__ void __launch_bounds__(64) k_head1(const float* __restrict__ pooled,
                                              const float* __restrict__ c_Wt,
                                              const float* __restrict__ c_b,
                                              float* __restrict__ hh) {
    int j = blockIdx.x;
    int l = threadIdx.x;
    float acc[cB];
    #pragma unroll
    for (int b = 0; b < cB; ++b) acc[b] = 0.0f;
    const float* wr = &c_Wt[j * 440];
    for (int ch = l; ch < C2; ch += 64) {
        float wv = wr[ch];
        #pragma unroll
        for (int b = 0; b < cB; ++b)
            acc[b] = fmaf(pooled[b * C2 + ch], wv, acc[b]);
    }
    #pragma unroll
    for (int off = 32; off >= 1; off >>= 1) {
        #pragma unroll
        for (int b = 0; b < cB; ++b) acc[b] += __shfl_xor(acc[b], off, 64);
    }
    if (l == 0) {
        float cb = c_b[j];
        #pragma unroll
        for (int b = 0; b < cB; ++b) hh[b * HD + j] = sp1(acc[b] + cb);
    }
}

// BN (training batch stats) + softplus + output linear + sigmoid; single small block
__global__ void __launch_bounds__(128) k_head2(const float* __restrict__ hh,
                                               const float* __restrict__ bn_g,
                                               const float* __restrict__ bn_b,
                                               const float* __restrict__ o_W,
                                               const float* __restrict__ o_b,
                                               float* __restrict__ out) {
    __shared__ float hh2[cB][HD];
    int t = threadIdx.x;                     // = column j
    float v[cB];
    float mu = 0.0f;
    #pragma unroll
    for (int b = 0; b < cB; ++b) { v[b] = hh[b * HD + t]; mu += v[b]; }
    mu *= (1.0f / cB);
    float var = 0.0f;
    #pragma unroll
    for (int b = 0; b < cB; ++b) { float d = v[b] - mu; var = fmaf(d, d, var); }
    var *= (1.0f / cB);
    float sc = bn_g[t] / sqrtf(var + 1e-5f);
    float bnb = bn_b[t];
    #pragma unroll
    for (int b = 0; b < cB; ++b) hh2[b][t] = sp1((v[b] - mu) * sc + bnb);
    __syncthreads();
    if (t < cB) {
        float s = o_b[0];
        for (int j = 0; j < HD; ++j) s = fmaf(hh2[t][j], o_W[j], s);
        out[t] = 1.0f / (1.0f + expf(-s));
    }
}

extern "C" void kernel_launch(void* const* d_in, const int* in_sizes, int n_in,
                              void* d_out, int out_size, void* d_ws, size_t ws_size,
                              hipStream_t stream) {
    const float* xyz    = (const float*)d_in[0];
    const int*   Z      = (const int*)d_in[1];
    const float* body23 = (const float*)d_in[2];
    const float* emb_W  = (const float*)d_in[3];
    const float* rW0    = (const float*)d_in[4];
    const float* rb0    = (const float*)d_in[5];
    const float* rW1    = (const float*)d_in[6];
    const float* rb1    = (const float*)d_in[7];
    const float* rW2    = (const float*)d_in[8];
    const float* rb2    = (const float*)d_in[9];
    const float* rW3    = (const float*)d_in[10];
    const float* rb3    = (const float*)d_in[11];
    const float* res_W  = (const float*)d_in[12];
    const float* res_b  = (const float*)d_in[13];
    const float* c_W    = (const float*)d_in[14];
    const float* c_b    = (const float*)d_in[15];
    const float* bn_g   = (const float*)d_in[16];
    const float* bn_b   = (const float*)d_in[17];
    const float* o_W    = (const float*)d_in[18];
    const float* o_b    = (const float*)d_in[19];

    float* w      = (float*)d_ws;
    float* W2     = w;                        // 150*512    = 76800
    float* Pbz    = W2 + 76800;               // 432
    float* rW0p   = Pbz + 432;                // 10*152     = 1520
    float* rW1p   = rW0p + 1520;              // 150*152    = 22800
    float* rW2p   = rW1p + 22800;             // 22800
    float* c_Wt   = rW2p + 22800;             // 128*440    = 56320
    float* G      = c_Wt + 56320;             // 2048*432   = 884736
    float* feats  = G + 884736;               // 1024*438   = 448512
    float* pooled = feats + 448512;           // 16*438     = 7008
    float* hh     = pooled + 7008;            // 16*128     = 2048
    (void)in_sizes; (void)n_in; (void)out_size; (void)ws_size;

    k_pad  <<<256, 256, 0, stream>>>(rW0, rW1, rW2, c_W, rW0p, rW1p, rW2p, c_Wt);
    k_wz   <<<dim3(NSP, 15), 256, 0, stream>>>(emb_W, rW3, rb3, W2, Pbz);
    k_chain<<<TBL / 2, 256, 0, stream>>>(rW0p, rb0, rW1p, rb1, rW2p, rb2, W2, Pbz, G);
    k_red  <<<cB * cN, 256, 0, stream>>>(xyz, Z, body23, G, res_W, res_b, feats);
    k_pool <<<cB, 448, 0, stream>>>(feats, pooled);
    k_head1<<<HD, 64, 0, stream>>>(pooled, c_Wt, c_b, hh);
    k_head2<<<1, 128, 0, stream>>>(hh, bn_g, bn_b, o_W, o_b, (float*)d_out);
}

// Round 18
// 82.540 us; speedup vs baseline: 7.5087x; 1.3052x over previous
//
#include <hip/hip_runtime.h>
#include <math.h>

constexpr int cB  = 16;
constexpr int cN  = 64;
constexpr int EMB = 32;
constexpr int NL  = 3;
constexpr int CDIM = 24;
constexpr int LOD = NL * CDIM;      // 72
constexpr int NB  = 10;
constexpr int H   = 150;
constexpr int CR  = 219;
constexpr int C2  = 438;
constexpr int HD  = 128;
constexpr int NSP = 6;              // species count
constexpr int GC  = NSP * LOD;      // 432 G-columns
constexpr int GCP = 512;            // padded W2 row
constexpr int TBL = 1024;           // r-table resolution (err ~4e-4 << 7.2e-3 threshold)
constexpr float RADIUS = 2.0f;

__device__ __forceinline__ float sp5(float x) {
    return fmaxf(x, 0.0f) + 0.2f * log1pf(expf(-5.0f * fabsf(x)));
}
__device__ __forceinline__ float sp1(float x) {
    return fmaxf(x, 0.0f) + log1pf(expf(-fabsf(x)));
}

// pad rW0/rW1/rW2 into [.][152] copies; transpose c_W -> c_Wt[128][440]
__global__ void __launch_bounds__(256) k_pad(const float* __restrict__ rW0,
                                             const float* __restrict__ rW1,
                                             const float* __restrict__ rW2,
                                             const float* __restrict__ c_W,
                                             float* __restrict__ rW0p,
                                             float* __restrict__ rW1p,
                                             float* __restrict__ rW2p,
                                             float* __restrict__ c_Wt) {
    int total = NB * 152 + 2 * H * 152 + HD * 440;   // 1520+45600+56320
    for (int i = blockIdx.x * 256 + threadIdx.x; i < total; i += gridDim.x * 256) {
        if (i < NB * 152) {
            int r = i / 152, c = i - r * 152;
            rW0p[i] = (c < H) ? rW0[r * H + c] : 0.0f;
        } else if (i < NB * 152 + H * 152) {
            int j = i - NB * 152; int r = j / 152, c = j - r * 152;
            rW1p[j] = (c < H) ? rW1[r * H + c] : 0.0f;
        } else if (i < NB * 152 + 2 * H * 152) {
            int j = i - NB * 152 - H * 152; int r = j / 152, c = j - r * 152;
            rW2p[j] = (c < H) ? rW2[r * H + c] : 0.0f;
        } else {
            int j = i - NB * 152 - 2 * H * 152;
            int jj = j / 440, ch = j - jj * 440;
            c_Wt[j] = (ch < C2) ? c_W[ch * HD + jj] : 0.0f;
        }
    }
}

// W2[k][z*72+lo] = sum_i rW3[k][lo*32+i]*emb[z][i]  (z-interleaved, 512-padded);
// Pbz flat [z*72+lo] from rb3.
__global__ void __launch_bounds__(256) k_wz(const float* __restrict__ emb_W,
                                            const float* __restrict__ rW3,
                                            const float* __restrict__ rb3,
                                            float* __restrict__ W2,
                                            float* __restrict__ Pbz) {
    int z = blockIdx.x, hb = blockIdx.y;     // 6 x 15 blocks, 10 k-rows each
    __shared__ float e[EMB];
    int t = threadIdx.x;
    if (t < EMB) e[t] = emb_W[z * EMB + t];
    __syncthreads();
    for (int o = t; o < 10 * LOD; o += 256) {
        int k = hb * 10 + o / LOD, lo = o % LOD;
        const float* wr = &rW3[(size_t)k * (LOD * EMB) + lo * EMB];
        float s = 0.0f;
        #pragma unroll
        for (int i = 0; i < EMB; ++i) s = fmaf(wr[i], e[i], s);
        W2[(size_t)k * GCP + z * LOD + lo] = s;
    }
    if (z == 0) {  // zero the pad cols 432..511
        for (int o = t; o < 10 * (GCP - GC); o += 256) {
            int k = hb * 10 + o / (GCP - GC), c = GC + o % (GCP - GC);
            W2[(size_t)k * GCP + c] = 0.0f;
        }
    }
    if (hb == 0 && t < LOD) {
        float s = 0.0f;
        #pragma unroll
        for (int i = 0; i < EMB; ++i) s = fmaf(rb3[t * EMB + i], e[i], s);
        Pbz[z * LOD + t] = s;
    }
}

// Fused table chain, no weight staging (weights stream L1/L2, coalesced).
// 2 rows/block x 256 thr; thread map: a2 = t>>7 (row), jt = t&127 (col).
__global__ void __launch_bounds__(256) k_chain(const float* __restrict__ rW0p,
                                               const float* __restrict__ rb0,
                                               const float* __restrict__ rW1p,
                                               const float* __restrict__ rb1,
                                               const float* __restrict__ rW2p,
                                               const float* __restrict__ rb2,
                                               const float* __restrict__ W2,
                                               const float* __restrict__ Pbz,
                                               float* __restrict__ G) {
    const int row0 = blockIdx.x * 2;
    const int t = threadIdx.x;
    const int a2 = t >> 7;                   // 0..1 local row
    const int jt = t & 127;                  // col
    const bool hasx = (jt < 22);
    const int jx = hasx ? 128 + jt : 128;    // extra col (idle lanes read col 128, discard)

    __shared__ __align__(16) float bas[2][10];
    __shared__ __align__(16) float hA[2 * 152];
    __shared__ __align__(16) float hB[2 * 152];

    if (t < 2) {
        float r = (float)(row0 + t) * (RADIUS / (float)(TBL - 1));
        #pragma unroll
        for (int k = 0; k < NB; ++k) {
            float d = r * 4.5f - (float)k;
            float v = 0.0f;
            if (fabsf(d) < 1.0f) { float cc = cosf(1.57079632679489662f * d); v = cc * cc; }
            bas[t][k] = v;
        }
    }
    __syncthreads();

    // ---- L0: K=10 ----
    {
        float a0 = 0, ax = 0;
        #pragma unroll
        for (int k = 0; k < NB; ++k) {
            float x = bas[a2][k];
            a0 = fmaf(x, rW0p[k * 152 + jt], a0);
            ax = fmaf(x, rW0p[k * 152 + jx], ax);
        }
        hA[a2 * 152 + jt] = sp5(a0 + rb0[jt]);
        if (hasx) hA[a2 * 152 + 128 + jt] = sp5(ax + rb0[128 + jt]);
    }
    __syncthreads();

    // ---- L1 (hA->hB), L2 (hB->hA): K=150, weights direct from L1/L2 ----
    for (int layer = 0; layer < 2; ++layer) {
        const float* W   = layer ? rW2p : rW1p;
        const float* bb  = layer ? rb2 : rb1;
        const float* src = layer ? hB : hA;
        float*       dst = layer ? hA : hB;
        float a0 = 0, ax = 0;
        const float* xs = &src[a2 * 152];
        #pragma unroll 10
        for (int k = 0; k < H; ++k) {
            float x = xs[k];
            const float* wr = &W[k * 152];
            a0 = fmaf(x, wr[jt], a0);
            ax = fmaf(x, wr[jx], ax);
        }
        dst[a2 * 152 + jt] = sp5(a0 + bb[jt]);
        if (hasx) dst[a2 * 152 + 128 + jt] = sp5(ax + bb[128 + jt]);
        __syncthreads();
    }

    // ---- G: out[row][c] = sum_k hA[row][k]*W2[k][c] + Pbz[c], c = 4jt..4jt+4 ----
    if (jt < 108) {
        const int g0 = 4 * jt;
        float4 c0 = {0, 0, 0, 0};
        const float* xs = &hA[a2 * 152];
        #pragma unroll 10
        for (int k = 0; k < H; ++k) {
            float x = xs[k];
            float4 w = *(const float4*)&W2[(size_t)k * GCP + g0];
            c0.x = fmaf(x, w.x, c0.x); c0.y = fmaf(x, w.y, c0.y);
            c0.z = fmaf(x, w.z, c0.z); c0.w = fmaf(x, w.w, c0.w);
        }
        int row = row0 + a2;
        float4 p = *(const float4*)&Pbz[g0];
        float4 o;
        o.x = c0.x + p.x; o.y = c0.y + p.y; o.z = c0.z + p.z; o.w = c0.w + p.w;
        *(float4*)&G[(size_t)row * GC + g0] = o;
    }
}

// fused per (b,a): pair mask + G-lerp -> ps[n][72] in LDS; Y-reduce; body23 concat; residual
__global__ void __launch_bounds__(256) k_red(const float* __restrict__ xyz,
                                             const int* __restrict__ Z,
                                             const float* __restrict__ body23,
                                             const float* __restrict__ G,
                                             const float* __restrict__ res_W,
                                             const float* __restrict__ res_b,
                                             float* __restrict__ feats) {
    int ba = blockIdx.x;
    int b = ba >> 6, a = ba & 63;
    int t = threadIdx.x;
    __shared__ float ym[64][12];
    __shared__ float ps[64][76];
    __shared__ float xr[CR];
    __shared__ int t0s[64];
    __shared__ float wls[64];
    __shared__ int zs[64];
    __shared__ int msks[64];
    if (t < 64) {
        int n = t;
        float ax = xyz[((size_t)b * cN + a) * 3 + 0];
        float ay = xyz[((size_t)b * cN + a) * 3 + 1];
        float az = xyz[((size_t)b * cN + a) * 3 + 2];
        float d0 = ax - xyz[((size_t)b * cN + n) * 3 + 0];
        float d1 = ay - xyz[((size_t)b * cN + n) * 3 + 1];
        float d2 = az - xyz[((size_t)b * cN + n) * 3 + 2];
        float s = d0 * d0 + d1 * d1 + d2 * d2;
        float r = sqrtf(s + 1e-12f);
        msks[n] = (r < RADIUS) && (r > 1e-6f);
        float u = r * ((float)(TBL - 1) / RADIUS);
        int t0 = (int)u;
        if (t0 > TBL - 2) t0 = TBL - 2;
        t0s[n] = t0;
        wls[n] = u - (float)t0;
        zs[n] = Z[b * cN + n];
        float inv = 1.0f / r;
        float x = d0 * inv, y = d1 * inv, z = d2 * inv;
        ym[n][0] = 0.28209479177387814f;
        ym[n][1] = 0.4886025119029199f * y;
        ym[n][2] = 0.4886025119029199f * z;
        ym[n][3] = 0.4886025119029199f * x;
        ym[n][4] = 1.0925484305920792f * x * y;
        ym[n][5] = 1.0925484305920792f * y * z;
        ym[n][6] = 0.31539156525252005f * (3.0f * z * z - 1.0f);
        ym[n][7] = 1.0925484305920792f * x * z;
        ym[n][8] = 0.5462742152960396f * (x * x - y * y);
    }
    __syncthreads();
    for (int i = t; i < 64 * LOD; i += 256) {
        int n = i / LOD, lo = i - n * LOD;
        float v = 0.0f;
        if (msks[n]) {
            const float* g = &G[(size_t)t0s[n] * GC + zs[n] * LOD + lo];
            float g0 = g[0], g1 = g[GC];
            v = g0 + wls[n] * (g1 - g0);
        }
        ps[n][lo] = v;
    }
    __syncthreads();
    if (t < 216) {
        int lo, yi;
        if (t < 24) { lo = t; yi = 0; }
        else if (t < 96) { int q = t - 24; int o = q / 3; lo = 24 + o; yi = 1 + (q - o * 3); }
        else { int q = t - 96; int o = q / 5; lo = 48 + o; yi = 4 + (q - o * 5); }
        float acc = 0.0f;
        #pragma unroll 4
        for (int n = 0; n < cN; ++n)
            acc = fmaf(ps[n][lo], ym[n][yi], acc);
        xr[3 + t] = acc * 0.125f;
    } else if (t < 219) {
        xr[t - 216] = body23[(size_t)ba * 3 + (t - 216)];
    }
    __syncthreads();
    if (t < CR) {
        float xv = xr[t];
        feats[(size_t)ba * C2 + t] = xv;
        float racc = res_b[t];
        for (int k = 0; k < CR; ++k)
            racc = fmaf(xr[k], res_W[k * CR + t], racc);
        feats[(size_t)ba * C2 + CR + t] = xv + sp5(racc);
    }
}

__global__ void __launch_bounds__(448) k_pool(const float* __restrict__ feats,
                                              float* __restrict__ pooled) {
    int b = blockIdx.x;
    int t = threadIdx.x;
    if (t < C2) {
        float s = 0.0f;
        for (int a = 0; a < cN; ++a) {
            float v = feats[(size_t)(b * cN + a) * C2 + t];
            s = fmaf(v, v, s);
        }
        pooled[b * C2 + t] = sqrtf(s);
    }
}

// hh[b][j] = sp1(pooled[b] . c_Wt[j] + c_b[j]); one block per column j, 64 lanes
__global__ void __launch_bounds__(64) k_head1(const float* __restrict__ pooled,
                                              const float* __restrict__ c_Wt,
                                              const float* __restrict__ c_b,
                                              float* __restrict__ hh) {
    int j = blockIdx.x;
    int l = threadIdx.x;
    float acc[cB];
    #pragma unroll
    for (int b = 0; b < cB; ++b) acc[b] = 0.0f;
    const float* wr = &c_Wt[j * 440];
    for (int ch = l; ch < C2; ch += 64) {
        float wv = wr[ch];
        #pragma unroll
        for (int b = 0; b < cB; ++b)
            acc[b] = fmaf(pooled[b * C2 + ch], wv, acc[b]);
    }
    #pragma unroll
    for (int off = 32; off >= 1; off >>= 1) {
        #pragma unroll
        for (int b = 0; b < cB; ++b) acc[b] += __shfl_xor(acc[b], off, 64);
    }
    if (l == 0) {
        float cb = c_b[j];
        #pragma unroll
        for (int b = 0; b < cB; ++b) hh[b * HD + j] = sp1(acc[b] + cb);
    }
}

// BN (training batch stats) + softplus + output linear + sigmoid; single small block
__global__ void __launch_bounds__(128) k_head2(const float* __restrict__ hh,
                                               const float* __restrict__ bn_g,
                                               const float* __restrict__ bn_b,
                                               const float* __restrict__ o_W,
                                               const float* __restrict__ o_b,
                                               float* __restrict__ out) {
    __shared__ float hh2[cB][HD];
    int t = threadIdx.x;                     // = column j
    float v[cB];
    float mu = 0.0f;
    #pragma unroll
    for (int b = 0; b < cB; ++b) { v[b] = hh[b * HD + t]; mu += v[b]; }
    mu *= (1.0f / cB);
    float var = 0.0f;
    #pragma unroll
    for (int b = 0; b < cB; ++b) { float d = v[b] - mu; var = fmaf(d, d, var); }
    var *= (1.0f / cB);
    float sc = bn_g[t] / sqrtf(var + 1e-5f);
    float bnb = bn_b[t];
    #pragma unroll
    for (int b = 0; b < cB; ++b) hh2[b][t] = sp1((v[b] - mu) * sc + bnb);
    __syncthreads();
    if (t < cB) {
        float s = o_b[0];
        for (int j = 0; j < HD; ++j) s = fmaf(hh2[t][j], o_W[j], s);
        out[t] = 1.0f / (1.0f + expf(-s));
    }
}

extern "C" void kernel_launch(void* const* d_in, const int* in_sizes, int n_in,
                              void* d_out, int out_size, void* d_ws, size_t ws_size,
                              hipStream_t stream) {
    const float* xyz    = (const float*)d_in[0];
    const int*   Z      = (const int*)d_in[1];
    const float* body23 = (const float*)d_in[2];
    const float* emb_W  = (const float*)d_in[3];
    const float* rW0    = (const float*)d_in[4];
    const float* rb0    = (const float*)d_in[5];
    const float* rW1    = (const float*)d_in[6];
    const float* rb1    = (const float*)d_in[7];
    const float* rW2    = (const float*)d_in[8];
    const float* rb2    = (const float*)d_in[9];
    const float* rW3    = (const float*)d_in[10];
    const float* rb3    = (const float*)d_in[11];
    const float* res_W  = (const float*)d_in[12];
    const float* res_b  = (const float*)d_in[13];
    const float* c_W    = (const float*)d_in[14];
    const float* c_b    = (const float*)d_in[15];
    const float* bn_g   = (const float*)d_in[16];
    const float* bn_b   = (const float*)d_in[17];
    const float* o_W    = (const float*)d_in[18];
    const float* o_b    = (const float*)d_in[19];

    float* w      = (float*)d_ws;
    float* W2     = w;                        // 150*512    = 76800
    float* Pbz    = W2 + 76800;               // 432
    float* rW0p   = Pbz + 432;                // 10*152     = 1520
    float* rW1p   = rW0p + 1520;              // 150*152    = 22800
    float* rW2p   = rW1p + 22800;             // 22800
    float* c_Wt   = rW2p + 22800;             // 128*440    = 56320
    float* G      = c_Wt + 56320;             // 1024*432   = 442368
    float* feats  = G + 442368;               // 1024*438   = 448512
    float* pooled = feats + 448512;           // 16*438     = 7008
    float* hh     = pooled + 7008;            // 16*128     = 2048
    (void)in_sizes; (void)n_in; (void)out_size; (void)ws_size;

    k_pad  <<<256, 256, 0, stream>>>(rW0, rW1, rW2, c_W, rW0p, rW1p, rW2p, c_Wt);
    k_wz   <<<dim3(NSP, 15), 256, 0, stream>>>(emb_W, rW3, rb3, W2, Pbz);
    k_chain<<<TBL / 2, 256, 0, stream>>>(rW0p, rb0, rW1p, rb1, rW2p, rb2, W2, Pbz, G);
    k_red  <<<cB * cN, 256, 0, stream>>>(xyz, Z, body23, G, res_W, res_b, feats);
    k_pool <<<cB, 448, 0, stream>>>(feats, pooled);
    k_head1<<<HD, 64, 0, stream>>>(pooled, c_Wt, c_b, hh);
    k_head2<<<1, 128, 0, stream>>>(hh, bn_g, bn_b, o_W, o_b, (float*)d_out);
}

// Round 19
// 73.816 us; speedup vs baseline: 8.3962x; 1.1182x over previous
//
#include <hip/hip_runtime.h>
#include <math.h>

constexpr int cB  = 16;
constexpr int cN  = 64;
constexpr int EMB = 32;
constexpr int NL  = 3;
constexpr int CDIM = 24;
constexpr int LOD = NL * CDIM;      // 72
constexpr int NB  = 10;
constexpr int H   = 150;
constexpr int CR  = 219;
constexpr int C2  = 438;
constexpr int HD  = 128;
constexpr int NSP = 6;              // species count
constexpr int GC  = NSP * LOD;      // 432 G-columns
constexpr int GCP = 512;            // padded W2 row
constexpr int TBL = 512;            // r-table resolution (err ~1.6e-3 < 7.2e-3 thr; measured 0.0 at 1024/2048)
constexpr float RADIUS = 2.0f;

__device__ __forceinline__ float sp5(float x) {
    return fmaxf(x, 0.0f) + 0.2f * log1pf(expf(-5.0f * fabsf(x)));
}
__device__ __forceinline__ float sp1(float x) {
    return fmaxf(x, 0.0f) + log1pf(expf(-fabsf(x)));
}

// Merged prologue kernel.
// blocks 0..89: W2[k][z*72+lo] = sum_i rW3[k][lo*32+i]*emb[z][i] (z-interleaved, 512-padded) + Pbz
// blocks 90..345: pad rW0/rW1/rW2 into [.][152] copies; transpose c_W -> c_Wt[128][440]
__global__ void __launch_bounds__(256) k_prep(const float* __restrict__ emb_W,
                                              const float* __restrict__ rW3,
                                              const float* __restrict__ rb3,
                                              const float* __restrict__ rW0,
                                              const float* __restrict__ rW1,
                                              const float* __restrict__ rW2,
                                              const float* __restrict__ c_W,
                                              float* __restrict__ W2,
                                              float* __restrict__ Pbz,
                                              float* __restrict__ rW0p,
                                              float* __restrict__ rW1p,
                                              float* __restrict__ rW2p,
                                              float* __restrict__ c_Wt) {
    int bx = blockIdx.x;
    int t = threadIdx.x;
    __shared__ float e[EMB];
    if (bx < 90) {
        int z = bx / 15, hb = bx - (bx / 15) * 15;   // 6 x 15, 10 k-rows each
        if (t < EMB) e[t] = emb_W[z * EMB + t];
        __syncthreads();
        for (int o = t; o < 10 * LOD; o += 256) {
            int k = hb * 10 + o / LOD, lo = o % LOD;
            const float* wr = &rW3[(size_t)k * (LOD * EMB) + lo * EMB];
            float s = 0.0f;
            #pragma unroll
            for (int i = 0; i < EMB; ++i) s = fmaf(wr[i], e[i], s);
            W2[(size_t)k * GCP + z * LOD + lo] = s;
        }
        if (z == 0) {  // zero the pad cols 432..511
            for (int o = t; o < 10 * (GCP - GC); o += 256) {
                int k = hb * 10 + o / (GCP - GC), c = GC + o % (GCP - GC);
                W2[(size_t)k * GCP + c] = 0.0f;
            }
        }
        if (hb == 0 && t < LOD) {
            float s = 0.0f;
            #pragma unroll
            for (int i = 0; i < EMB; ++i) s = fmaf(rb3[t * EMB + i], e[i], s);
            Pbz[z * LOD + t] = s;
        }
    } else {
        int pb = bx - 90;                            // 256 pad blocks
        int total = NB * 152 + 2 * H * 152 + HD * 440;
        for (int i = pb * 256 + t; i < total; i += 256 * 256) {
            if (i < NB * 152) {
                int r = i / 152, c = i - r * 152;
                rW0p[i] = (c < H) ? rW0[r * H + c] : 0.0f;
            } else if (i < NB * 152 + H * 152) {
                int j = i - NB * 152; int r = j / 152, c = j - r * 152;
                rW1p[j] = (c < H) ? rW1[r * H + c] : 0.0f;
            } else if (i < NB * 152 + 2 * H * 152) {
                int j = i - NB * 152 - H * 152; int r = j / 152, c = j - r * 152;
                rW2p[j] = (c < H) ? rW2[r * H + c] : 0.0f;
            } else {
                int j = i - NB * 152 - 2 * H * 152;
                int jj = j / 440, ch = j - jj * 440;
                c_Wt[j] = (ch < C2) ? c_W[ch * HD + jj] : 0.0f;
            }
        }
    }
}

// Fused table chain, no weight staging (weights stream L1/L2, coalesced).
// 2 rows/block x 256 thr; thread map: a2 = t>>7 (row), jt = t&127 (col).
__global__ void __launch_bounds__(256) k_chain(const float* __restrict__ rW0p,
                                               const float* __restrict__ rb0,
                                               const float* __restrict__ rW1p,
                                               const float* __restrict__ rb1,
                                               const float* __restrict__ rW2p,
                                               const float* __restrict__ rb2,
                                               const float* __restrict__ W2,
                                               const float* __restrict__ Pbz,
                                               float* __restrict__ G) {
    const int row0 = blockIdx.x * 2;
    const int t = threadIdx.x;
    const int a2 = t >> 7;                   // 0..1 local row
    const int jt = t & 127;                  // col
    const bool hasx = (jt < 22);
    const int jx = hasx ? 128 + jt : 128;    // extra col (idle lanes read col 128, discard)

    __shared__ __align__(16) float bas[2][10];
    __shared__ __align__(16) float hA[2 * 152];
    __shared__ __align__(16) float hB[2 * 152];

    if (t < 2) {
        float r = (float)(row0 + t) * (RADIUS / (float)(TBL - 1));
        #pragma unroll
        for (int k = 0; k < NB; ++k) {
            float d = r * 4.5f - (float)k;
            float v = 0.0f;
            if (fabsf(d) < 1.0f) { float cc = cosf(1.57079632679489662f * d); v = cc * cc; }
            bas[t][k] = v;
        }
    }
    __syncthreads();

    // ---- L0: K=10 ----
    {
        float a0 = 0, ax = 0;
        #pragma unroll
        for (int k = 0; k < NB; ++k) {
            float x = bas[a2][k];
            a0 = fmaf(x, rW0p[k * 152 + jt], a0);
            ax = fmaf(x, rW0p[k * 152 + jx], ax);
        }
        hA[a2 * 152 + jt] = sp5(a0 + rb0[jt]);
        if (hasx) hA[a2 * 152 + 128 + jt] = sp5(ax + rb0[128 + jt]);
    }
    __syncthreads();

    // ---- L1 (hA->hB), L2 (hB->hA): K=150, weights direct from L1/L2 ----
    for (int layer = 0; layer < 2; ++layer) {
        const float* W   = layer ? rW2p : rW1p;
        const float* bb  = layer ? rb2 : rb1;
        const float* src = layer ? hB : hA;
        float*       dst = layer ? hA : hB;
        float a0 = 0, ax = 0;
        const float* xs = &src[a2 * 152];
        #pragma unroll 10
        for (int k = 0; k < H; ++k) {
            float x = xs[k];
            const float* wr = &W[k * 152];
            a0 = fmaf(x, wr[jt], a0);
            ax = fmaf(x, wr[jx], ax);
        }
        dst[a2 * 152 + jt] = sp5(a0 + bb[jt]);
        if (hasx) dst[a2 * 152 + 128 + jt] = sp5(ax + bb[128 + jt]);
        __syncthreads();
    }

    // ---- G: out[row][c] = sum_k hA[row][k]*W2[k][c] + Pbz[c], c = 4jt..4jt+4 ----
    if (jt < 108) {
        const int g0 = 4 * jt;
        float4 c0 = {0, 0, 0, 0};
        const float* xs = &hA[a2 * 152];
        #pragma unroll 10
        for (int k = 0; k < H; ++k) {
            float x = xs[k];
            float4 w = *(const float4*)&W2[(size_t)k * GCP + g0];
            c0.x = fmaf(x, w.x, c0.x); c0.y = fmaf(x, w.y, c0.y);
            c0.z = fmaf(x, w.z, c0.z); c0.w = fmaf(x, w.w, c0.w);
        }
        int row = row0 + a2;
        float4 p = *(const float4*)&Pbz[g0];
        float4 o;
        o.x = c0.x + p.x; o.y = c0.y + p.y; o.z = c0.z + p.z; o.w = c0.w + p.w;
        *(float4*)&G[(size_t)row * GC + g0] = o;
    }
}

// fused per (b,a): pair mask + G-lerp -> ps[n][72] in LDS; Y-reduce; body23 concat; residual
__global__ void __launch_bounds__(256) k_red(const float* __restrict__ xyz,
                                             const int* __restrict__ Z,
                                             const float* __restrict__ body23,
                                             const float* __restrict__ G,
                                             const float* __restrict__ res_W,
                                             const float* __restrict__ res_b,
                                             float* __restrict__ feats) {
    int ba = blockIdx.x;
    int b = ba >> 6, a = ba & 63;
    int t = threadIdx.x;
    __shared__ float ym[64][12];
    __shared__ float ps[64][76];
    __shared__ float xr[CR];
    __shared__ int t0s[64];
    __shared__ float wls[64];
    __shared__ int zs[64];
    __shared__ int msks[64];
    if (t < 64) {
        int n = t;
        float ax = xyz[((size_t)b * cN + a) * 3 + 0];
        float ay = xyz[((size_t)b * cN + a) * 3 + 1];
        float az = xyz[((size_t)b * cN + a) * 3 + 2];
        float d0 = ax - xyz[((size_t)b * cN + n) * 3 + 0];
        float d1 = ay - xyz[((size_t)b * cN + n) * 3 + 1];
        float d2 = az - xyz[((size_t)b * cN + n) * 3 + 2];
        float s = d0 * d0 + d1 * d1 + d2 * d2;
        float r = sqrtf(s + 1e-12f);
        msks[n] = (r < RADIUS) && (r > 1e-6f);
        float u = r * ((float)(TBL - 1) / RADIUS);
        int t0 = (int)u;
        if (t0 > TBL - 2) t0 = TBL - 2;
        t0s[n] = t0;
        wls[n] = u - (float)t0;
        zs[n] = Z[b * cN + n];
        float inv = 1.0f / r;
        float x = d0 * inv, y = d1 * inv, z = d2 * inv;
        ym[n][0] = 0.28209479177387814f;
        ym[n][1] = 0.4886025119029199f * y;
        ym[n][2] = 0.4886025119029199f * z;
        ym[n][3] = 0.4886025119029199f * x;
        ym[n][4] = 1.0925484305920792f * x * y;
        ym[n][5] = 1.0925484305920792f * y * z;
        ym[n][6] = 0.31539156525252005f * (3.0f * z * z - 1.0f);
        ym[n][7] = 1.0925484305920792f * x * z;
        ym[n][8] = 0.5462742152960396f * (x * x - y * y);
    }
    __syncthreads();
    for (int i = t; i < 64 * LOD; i += 256) {
        int n = i / LOD, lo = i - n * LOD;
        float v = 0.0f;
        if (msks[n]) {
            const float* g = &G[(size_t)t0s[n] * GC + zs[n] * LOD + lo];
            float g0 = g[0], g1 = g[GC];
            v = g0 + wls[n] * (g1 - g0);
        }
        ps[n][lo] = v;
    }
    __syncthreads();
    if (t < 216) {
        int lo, yi;
        if (t < 24) { lo = t; yi = 0; }
        else if (t < 96) { int q = t - 24; int o = q / 3; lo = 24 + o; yi = 1 + (q - o * 3); }
        else { int q = t - 96; int o = q / 5; lo = 48 + o; yi = 4 + (q - o * 5); }
        float acc = 0.0f;
        #pragma unroll 4
        for (int n = 0; n < cN; ++n)
            acc = fmaf(ps[n][lo], ym[n][yi], acc);
        xr[3 + t] = acc * 0.125f;
    } else if (t < 219) {
        xr[t - 216] = body23[(size_t)ba * 3 + (t - 216)];
    }
    __syncthreads();
    if (t < CR) {
        float xv = xr[t];
        feats[(size_t)ba * C2 + t] = xv;
        float r0 = 0.0f, r1 = 0.0f, r2 = 0.0f;
        #pragma unroll 3
        for (int k = 0; k < CR; k += 3) {     // 219 = 3*73
            r0 = fmaf(xr[k + 0], res_W[(k + 0) * CR + t], r0);
            r1 = fmaf(xr[k + 1], res_W[(k + 1) * CR + t], r1);
            r2 = fmaf(xr[k + 2], res_W[(k + 2) * CR + t], r2);
        }
        float racc = res_b[t] + ((r0 + r1) + r2);
        feats[(size_t)ba * C2 + CR + t] = xv + sp5(racc);
    }
}

// pooled[b][ch] = sqrt(sum_a feats^2); grid (cB x 7), 64 thr, coalesced rows
__global__ void __launch_bounds__(64) k_pool(const float* __restrict__ feats,
                                             float* __restrict__ pooled) {
    int b = blockIdx.x;
    int ch = blockIdx.y * 64 + threadIdx.x;
    if (ch < C2) {
        float s = 0.0f;
        #pragma unroll 4
        for (int a = 0; a < cN; ++a) {
            float v = feats[(size_t)(b * cN + a) * C2 + ch];
            s = fmaf(v, v, s);
        }
        pooled[b * C2 + ch] = sqrtf(s);
    }
}

// hh[b][j] = sp1(pooled[b] . c_Wt[j] + c_b[j]); one block per column j, 64 lanes
__global__ void __launch_bounds__(64) k_head1(const float* __restrict__ pooled,
                                              const float* __restrict__ c_Wt,
                                              const float* __restrict__ c_b,
                                              float* __restrict__ hh) {
    int j = blockIdx.x;
    int l = threadIdx.x;
    float acc[cB];
    #pragma unroll
    for (int b = 0; b < cB; ++b) acc[b] = 0.0f;
    const float* wr = &c_Wt[j * 440];
    for (int ch = l; ch < C2; ch += 64) {
        float wv = wr[ch];
        #pragma unroll
        for (int b = 0; b < cB; ++b)
            acc[b] = fmaf(pooled[b * C2 + ch], wv, acc[b]);
    }
    #pragma unroll
    for (int off = 32; off >= 1; off >>= 1) {
        #pragma unroll
        for (int b = 0; b < cB; ++b) acc[b] += __shfl_xor(acc[b], off, 64);
    }
    if (l == 0) {
        float cb = c_b[j];
        #pragma unroll
        for (int b = 0; b < cB; ++b) hh[b * HD + j] = sp1(acc[b] + cb);
    }
}

// BN (training batch stats) + softplus + output linear + sigmoid; single small block
__global__ void __launch_bounds__(128) k_head2(const float* __restrict__ hh,
                                               const float* __restrict__ bn_g,
                                               const float* __restrict__ bn_b,
                                               const float* __restrict__ o_W,
                                               const float* __restrict__ o_b,
                                               float* __restrict__ out) {
    __shared__ float hh2[cB][HD];
    int t = threadIdx.x;                     // = column j
    float v[cB];
    float mu = 0.0f;
    #pragma unroll
    for (int b = 0; b < cB; ++b) { v[b] = hh[b * HD + t]; mu += v[b]; }
    mu *= (1.0f / cB);
    float var = 0.0f;
    #pragma unroll
    for (int b = 0; b < cB; ++b) { float d = v[b] - mu; var = fmaf(d, d, var); }
    var *= (1.0f / cB);
    float sc = bn_g[t] / sqrtf(var + 1e-5f);
    float bnb = bn_b[t];
    #pragma unroll
    for (int b = 0; b < cB; ++b) hh2[b][t] = sp1((v[b] - mu) * sc + bnb);
    __syncthreads();
    if (t < cB) {
        float s = o_b[0];
        for (int j = 0; j < HD; ++j) s = fmaf(hh2[t][j], o_W[j], s);
        out[t] = 1.0f / (1.0f + expf(-s));
    }
}

extern "C" void kernel_launch(void* const* d_in, const int* in_sizes, int n_in,
                              void* d_out, int out_size, void* d_ws, size_t ws_size,
                              hipStream_t stream) {
    const float* xyz    = (const float*)d_in[0];
    const int*   Z      = (const int*)d_in[1];
    const float* body23 = (const float*)d_in[2];
    const float* emb_W  = (const float*)d_in[3];
    const float* rW0    = (const float*)d_in[4];
    const float* rb0    = (const float*)d_in[5];
    const float* rW1    = (const float*)d_in[6];
    const float* rb1    = (const float*)d_in[7];
    const float* rW2    = (const float*)d_in[8];
    const float* rb2    = (const float*)d_in[9];
    const float* rW3    = (const float*)d_in[10];
    const float* rb3    = (const float*)d_in[11];
    const float* res_W  = (const float*)d_in[12];
    const float* res_b  = (const float*)d_in[13];
    const float* c_W    = (const float*)d_in[14];
    const float* c_b    = (const float*)d_in[15];
    const float* bn_g   = (const float*)d_in[16];
    const float* bn_b   = (const float*)d_in[17];
    const float* o_W    = (const float*)d_in[18];
    const float* o_b    = (const float*)d_in[19];

    float* w      = (float*)d_ws;
    float* W2     = w;                        // 150*512    = 76800
    float* Pbz    = W2 + 76800;               // 432
    float* rW0p   = Pbz + 432;                // 10*152     = 1520
    float* rW1p   = rW0p + 1520;              // 150*152    = 22800
    float* rW2p   = rW1p + 22800;             // 22800
    float* c_Wt   = rW2p + 22800;             // 128*440    = 56320
    float* G      = c_Wt + 56320;             // 512*432    = 221184
    float* feats  = G + 221184;               // 1024*438   = 448512
    float* pooled = feats + 448512;           // 16*438     = 7008
    float* hh     = pooled + 7008;            // 16*128     = 2048
    (void)in_sizes; (void)n_in; (void)out_size; (void)ws_size;

    k_prep <<<346, 256, 0, stream>>>(emb_W, rW3, rb3, rW0, rW1, rW2, c_W,
                                     W2, Pbz, rW0p, rW1p, rW2p, c_Wt);
    k_chain<<<TBL / 2, 256, 0, stream>>>(rW0p, rb0, rW1p, rb1, rW2p, rb2, W2, Pbz, G);
    k_red  <<<cB * cN, 256, 0, stream>>>(xyz, Z, body23, G, res_W, res_b, feats);
    k_pool <<<dim3(cB, 7), 64, 0, stream>>>(feats, pooled);
    k_head1<<<HD, 64, 0, stream>>>(pooled, c_Wt, c_b, hh);
    k_head2<<<1, 128, 0, stream>>>(hh, bn_g, bn_b, o_W, o_b, (float*)d_out);
}